// Round 1
// baseline (7968.093 us; speedup 1.0000x reference)
//
#include <hip/hip_runtime.h>
#include <cstdint>
#include <cstddef>

#define BNODES 2048
#define NT 20
#define HDIM 128
#define NROWS (NT * BNODES)      // 40960
#define CAP 64

// ---------------- mask expansion (dtype auto-detect) ----------------
__global__ void expand_mask_kernel(const void* __restrict__ ego, float* __restrict__ maskf) {
  int gid = blockIdx.x * blockDim.x + threadIdx.x;
  if (gid >= 8 * NT * 256) return;
  // first 256 elements of ego_mask are guaranteed True -> word0 identifies dtype
  unsigned int w0 = ((const unsigned int*)ego)[0];
  int val;
  if (w0 == 1u)                 val = ((const int*)ego)[gid] != 0;             // int32
  else if (w0 == 0x3F800000u)   val = ((const float*)ego)[gid] != 0.0f;        // f32
  else if (w0 == 0x3F803F80u)   val = ((const unsigned short*)ego)[gid] != 0;  // bf16
  else                          val = ((const unsigned char*)ego)[gid] != 0;   // byte/bool
  int b = gid / (NT * 256);
  int t = (gid / 256) % NT;
  int n = gid % 256;
  maskf[t * BNODES + b * 256 + n] = val ? 1.0f : 0.0f;
}

// ---------------- degree + sparse column build ----------------
// column i of A_t: edges j->i. store j where A[t,j,i]!=0 && m[j]!=0.
// deg[i] = m[i]*(cnt+1); dinv = m[i] ? rsqrt(deg) : 0
__global__ void deg_fill_kernel(const float* __restrict__ adj, const float* __restrict__ maskf,
                                float* __restrict__ dinv, int* __restrict__ colcnt,
                                int* __restrict__ colidx) {
  int gid = blockIdx.x * blockDim.x + threadIdx.x;  // t*BNODES + i
  if (gid >= NROWS) return;
  int t = gid / BNODES, i = gid % BNODES;
  const float* Acol = adj + (size_t)t * BNODES * BNODES + i;
  const float* mrow = maskf + t * BNODES;
  int* out = colidx + (size_t)gid * CAP;
  int cnt = 0;
  for (int j = 0; j < BNODES; ++j) {
    float a = Acol[(size_t)j * BNODES];
    if (a != 0.0f && mrow[j] != 0.0f) {
      if (cnt < CAP) out[cnt] = j;
      cnt++;
    }
  }
  float m = mrow[i];
  dinv[gid] = (m != 0.0f) ? rsqrtf((float)cnt + 1.0f) : 0.0f;
  colcnt[gid] = cnt < CAP ? cnt : CAP;
}

// ---------------- first GCN linear: [NROWS,2] @ [2,128] ----------------
__global__ void lin0_kernel(const float* __restrict__ x, const float* __restrict__ w,
                            float* __restrict__ out) {
  int gid = blockIdx.x * blockDim.x + threadIdx.x;
  if (gid >= NROWS * HDIM) return;
  int r = gid >> 7, c = gid & 127;
  out[gid] = x[r * 2] * w[c] + x[r * 2 + 1] * w[HDIM + c];
}

// ---------------- SpMM: out = S @ Y using sparse columns ----------------
// out[i,c] = dinv[i] * ( sum_j dinv[j]*Y[j,c] + dinv[i]*Y[i,c] )
__global__ __launch_bounds__(HDIM) void spmm_kernel(const float* __restrict__ Y,
                                                    const float* __restrict__ dinv,
                                                    const int* __restrict__ colcnt,
                                                    const int* __restrict__ colidx,
                                                    float* __restrict__ out) {
  int r = blockIdx.x;
  int c = threadIdx.x;
  int t = r / BNODES;
  float di = dinv[r];
  float* orow = out + (size_t)r * HDIM;
  if (di == 0.0f) { orow[c] = 0.0f; return; }
  float acc = di * Y[(size_t)r * HDIM + c];
  int cnt = colcnt[r];
  const int* cols = colidx + (size_t)r * CAP;
  const float* dt = dinv + t * BNODES;
  const float* Yt = Y + (size_t)t * BNODES * HDIM;
  for (int k = 0; k < cnt; ++k) {
    int j = cols[k];
    acc += dt[j] * Yt[(size_t)j * HDIM + c];
  }
  orow[c] = di * acc;
}

// ---------------- fused LayerNorm (+bias pre, +residual pre/post, +relu) ----------------
__global__ __launch_bounds__(HDIM) void ln_kernel(const float* __restrict__ src,
                                                  const float* __restrict__ bias,
                                                  const float* __restrict__ pre,
                                                  const float* __restrict__ gamma,
                                                  const float* __restrict__ beta,
                                                  const float* __restrict__ post,
                                                  int relu, float* __restrict__ dst) {
  int r = blockIdx.x, c = threadIdx.x;
  size_t idx = (size_t)r * HDIM + c;
  float v = src[idx];
  if (bias) v += bias[c];
  if (pre) v += pre[idx];
  float s = v, q = v * v;
  #pragma unroll
  for (int off = 32; off > 0; off >>= 1) {
    s += __shfl_down(s, off, 64);
    q += __shfl_down(q, off, 64);
  }
  __shared__ float ls[2], lq[2];
  int wid = c >> 6, lane = c & 63;
  if (lane == 0) { ls[wid] = s; lq[wid] = q; }
  __syncthreads();
  float mu = (ls[0] + ls[1]) * (1.0f / HDIM);
  float var = (lq[0] + lq[1]) * (1.0f / HDIM) - mu * mu;
  var = fmaxf(var, 0.0f);
  float rs = rsqrtf(var + 1e-5f);
  float o = (v - mu) * rs * gamma[c] + beta[c];
  if (post) o += post[idx];
  if (relu) o = fmaxf(o, 0.0f);
  dst[idx] = o;
}

// ---------------- GEMM: C[M,N] = A[M,K] @ B[K,N] (+bias) (+relu) ----------------
// A rows read via wave-uniform addresses (scalar loads); B streamed coalesced.
__global__ __launch_bounds__(128) void gemm_kernel(const float* __restrict__ A,
                                                   const float* __restrict__ B,
                                                   const float* __restrict__ bias,
                                                   float* __restrict__ C,
                                                   int K, int N, int relu) {
  const int TM = 16;
  int c = blockIdx.x * 128 + threadIdx.x;
  int row0 = blockIdx.y * TM;
  float acc[TM];
  float binit = bias ? bias[c] : 0.0f;
  #pragma unroll
  for (int m = 0; m < TM; ++m) acc[m] = binit;
  int K4 = K >> 2;
  for (int k4 = 0; k4 < K4; ++k4) {
    float b0 = B[(size_t)(4 * k4 + 0) * N + c];
    float b1 = B[(size_t)(4 * k4 + 1) * N + c];
    float b2 = B[(size_t)(4 * k4 + 2) * N + c];
    float b3 = B[(size_t)(4 * k4 + 3) * N + c];
    #pragma unroll
    for (int m = 0; m < TM; ++m) {
      float4 av = *reinterpret_cast<const float4*>(A + (size_t)(row0 + m) * K + 4 * k4);
      acc[m] = fmaf(av.x, b0, acc[m]);
      acc[m] = fmaf(av.y, b1, acc[m]);
      acc[m] = fmaf(av.z, b2, acc[m]);
      acc[m] = fmaf(av.w, b3, acc[m]);
    }
  }
  #pragma unroll
  for (int m = 0; m < TM; ++m) {
    float v = acc[m];
    if (relu) v = fmaxf(v, 0.0f);
    C[(size_t)(row0 + m) * N + c] = v;
  }
}

// ---------------- batched transpose: L mats of [R,C] -> [C,R] ----------------
__global__ void transpose_kernel(const float* __restrict__ src, float* __restrict__ dst,
                                 int R, int C, int n) {
  int gid = blockIdx.x * blockDim.x + threadIdx.x;
  if (gid >= n) return;
  int rc = R * C;
  int l = gid / rc, rem = gid % rc;
  int r = rem / C, cc = rem % C;
  dst[(size_t)l * rc + (size_t)cc * R + r] = src[gid];
}

// ---------------- GCN output -> transformer input layout ----------------
__global__ void to_x_kernel(const float* __restrict__ h, const float* __restrict__ maskf,
                            const float* __restrict__ pos, float* __restrict__ xbuf) {
  int gid = blockIdx.x * blockDim.x + threadIdx.x;
  if (gid >= NROWS * HDIM) return;
  int r = gid >> 7, c = gid & 127;
  int t = r / BNODES, bn = r % BNODES;
  xbuf[((size_t)bn * NT + t) * HDIM + c] = h[gid] * maskf[r] + pos[t * HDIM + c];
}

// ---------------- attention: one block per sequence bn ----------------
__global__ __launch_bounds__(256) void attn_kernel(const float* __restrict__ qkv,
                                                   const float* __restrict__ maskf,
                                                   float* __restrict__ o) {
  int bn = blockIdx.x;
  __shared__ float q[NT][HDIM], kk[NT][HDIM], vv[NT][HDIM];
  __shared__ float sc[8][NT][NT];
  int tid = threadIdx.x;
  for (int idx = tid; idx < NT * 384; idx += 256) {
    int t = idx / 384, col = idx % 384;
    float val = qkv[((size_t)bn * NT + t) * 384 + col];
    if (col < 128) q[t][col] = val;
    else if (col < 256) kk[t][col - 128] = val;
    else vv[t][col - 256] = val;
  }
  __syncthreads();
  for (int idx = tid; idx < 8 * NT * NT; idx += 256) {
    int h = idx / (NT * NT), rr = idx % (NT * NT);
    int tq = rr / NT, tk = rr % NT;
    float s = 0.0f;
    #pragma unroll
    for (int d = 0; d < 16; ++d) s += q[tq][h * 16 + d] * kk[tk][h * 16 + d];
    s *= 0.25f;  // 1/sqrt(16)
    if (maskf[tk * BNODES + bn] == 0.0f) s = -1e30f;
    sc[h][tq][tk] = s;
  }
  __syncthreads();
  if (tid < 8 * NT) {
    int h = tid / NT, tq = tid % NT;
    float mx = -1e30f;
    for (int tk = 0; tk < NT; ++tk) mx = fmaxf(mx, sc[h][tq][tk]);
    float sum = 0.0f;
    for (int tk = 0; tk < NT; ++tk) { float e = __expf(sc[h][tq][tk] - mx); sc[h][tq][tk] = e; sum += e; }
    float inv = 1.0f / sum;
    for (int tk = 0; tk < NT; ++tk) sc[h][tq][tk] *= inv;
  }
  __syncthreads();
  for (int idx = tid; idx < NT * HDIM; idx += 256) {
    int tq = idx / HDIM, col = idx % HDIM;
    int h = col >> 4;
    float s = 0.0f;
    #pragma unroll
    for (int tk = 0; tk < NT; ++tk) s += sc[h][tq][tk] * vv[tk][col];
    o[((size_t)bn * NT + tq) * HDIM + col] = s;
  }
}

extern "C" void kernel_launch(void* const* d_in, const int* in_sizes, int n_in,
                              void* d_out, int out_size, void* d_ws, size_t ws_size,
                              hipStream_t stream) {
  const void*  ego   = d_in[0];
  const float* xraw  = (const float*)d_in[1];
  const float* adj   = (const float*)d_in[2];
  const float* gcn1w = (const float*)d_in[3];
  const float* gcnws = (const float*)d_in[4];
  const float* gcnbs = (const float*)d_in[5];
  const float* lng   = (const float*)d_in[6];
  const float* lnb   = (const float*)d_in[7];
  const float* pos   = (const float*)d_in[8];
  const float* twqkv = (const float*)d_in[9];
  const float* tbqkv = (const float*)d_in[10];
  const float* two   = (const float*)d_in[11];
  const float* tbo   = (const float*)d_in[12];
  const float* tln1g = (const float*)d_in[13];
  const float* tln1b = (const float*)d_in[14];
  const float* tw1   = (const float*)d_in[15];
  const float* tb1   = (const float*)d_in[16];
  const float* tw2   = (const float*)d_in[17];
  const float* tb2   = (const float*)d_in[18];
  const float* tln2g = (const float*)d_in[19];
  const float* tln2b = (const float*)d_in[20];

  char* base = (char*)d_ws;
  size_t off = 0;
  auto alloc = [&](size_t bytes) -> void* {
    void* p = base + off;
    off = (off + bytes + 255) & ~(size_t)255;
    return p;
  };
  float* maskf  = (float*)alloc((size_t)NROWS * 4);
  float* dinv   = (float*)alloc((size_t)NROWS * 4);
  int*   colcnt = (int*)  alloc((size_t)NROWS * 4);
  int*   colidx = (int*)  alloc((size_t)NROWS * CAP * 4);
  float* wT     = (float*)alloc((size_t)983040 * 4);
  float* t1     = (float*)alloc((size_t)NROWS * HDIM * 4);
  float* t2     = (float*)alloc((size_t)NROWS * HDIM * 4);
  float* hbuf   = (float*)alloc((size_t)NROWS * HDIM * 4);
  float* xbuf   = (float*)alloc((size_t)NROWS * HDIM * 4);
  float* big    = (float*)alloc((size_t)NROWS * 512 * 4);   // qkv (x384) / ff hidden (x512)

  // transposed transformer weights layout inside wT:
  float* wTqkv = wT;              // 5 * 128*384
  float* wTo   = wT + 245760;     // 5 * 128*128
  float* wTw1  = wT + 327680;     // 5 * 128*512
  float* wTw2  = wT + 655360;     // 5 * 512*128

  // ---- setup ----
  expand_mask_kernel<<<160, 256, 0, stream>>>(ego, maskf);
  transpose_kernel<<<960, 256, 0, stream>>>(twqkv, wTqkv, 384, 128, 245760);
  transpose_kernel<<<320, 256, 0, stream>>>(two, wTo, 128, 128, 81920);
  transpose_kernel<<<1280, 256, 0, stream>>>(tw1, wTw1, 512, 128, 327680);
  transpose_kernel<<<1280, 256, 0, stream>>>(tw2, wTw2, 128, 512, 327680);
  deg_fill_kernel<<<160, 256, 0, stream>>>(adj, maskf, dinv, colcnt, colidx);

  // ---- GCN ----
  lin0_kernel<<<NROWS * HDIM / 256, 256, 0, stream>>>(xraw, gcn1w, t1);
  spmm_kernel<<<NROWS, HDIM, 0, stream>>>(t1, dinv, colcnt, colidx, t2);
  ln_kernel<<<NROWS, HDIM, 0, stream>>>(t2, gcnbs, nullptr, lng, lnb, nullptr, 1, hbuf);
  for (int i = 0; i < 5; ++i) {
    gemm_kernel<<<dim3(1, NROWS / 16), 128, 0, stream>>>(hbuf, gcnws + (size_t)i * 16384,
                                                         nullptr, t1, 128, 128, 0);
    spmm_kernel<<<NROWS, HDIM, 0, stream>>>(t1, dinv, colcnt, colidx, t2);
    ln_kernel<<<NROWS, HDIM, 0, stream>>>(t2, gcnbs + (i + 1) * 128, nullptr,
                                          lng + (i + 1) * 128, lnb + (i + 1) * 128,
                                          hbuf, 1, hbuf);
  }
  to_x_kernel<<<NROWS * HDIM / 256, 256, 0, stream>>>(hbuf, maskf, pos, xbuf);

  // ---- transformer ----
  for (int l = 0; l < 5; ++l) {
    gemm_kernel<<<dim3(3, NROWS / 16), 128, 0, stream>>>(xbuf, wTqkv + (size_t)l * 49152,
                                                         tbqkv + l * 384, big, 128, 384, 0);
    attn_kernel<<<BNODES, 256, 0, stream>>>(big, maskf, t1);
    gemm_kernel<<<dim3(1, NROWS / 16), 128, 0, stream>>>(t1, wTo + (size_t)l * 16384,
                                                         tbo + l * 128, t2, 128, 128, 0);
    ln_kernel<<<NROWS, HDIM, 0, stream>>>(t2, nullptr, xbuf, tln1g + l * 128,
                                          tln1b + l * 128, nullptr, 0, xbuf);
    gemm_kernel<<<dim3(4, NROWS / 16), 128, 0, stream>>>(xbuf, wTw1 + (size_t)l * 65536,
                                                         tb1 + l * 512, big, 128, 512, 1);
    gemm_kernel<<<dim3(1, NROWS / 16), 128, 0, stream>>>(big, wTw2 + (size_t)l * 65536,
                                                         tb2 + l * 128, t2, 512, 128, 0);
    ln_kernel<<<NROWS, HDIM, 0, stream>>>(t2, nullptr, xbuf, tln2g + l * 128,
                                          tln2b + l * 128, nullptr, 0, xbuf);
  }

  // x [BN,T,H] is exactly out [B,N,T,H]
  hipMemcpyAsync(d_out, xbuf, (size_t)NROWS * HDIM * 4, hipMemcpyDeviceToDevice, stream);
}

// Round 2
// 7001.808 us; speedup vs baseline: 1.1380x; 1.1380x over previous
//
#include <hip/hip_runtime.h>
#include <cstdint>
#include <cstddef>

#define BNODES 2048
#define NT 20
#define HDIM 128
#define NROWS (NT * BNODES)      // 40960
#define CAP 64

// ---------------- mask expansion (dtype auto-detect) ----------------
__global__ void expand_mask_kernel(const void* __restrict__ ego, float* __restrict__ maskf) {
  int gid = blockIdx.x * blockDim.x + threadIdx.x;
  if (gid >= 8 * NT * 256) return;
  // first 256 elements of ego_mask are guaranteed True -> word0 identifies dtype
  unsigned int w0 = ((const unsigned int*)ego)[0];
  int val;
  if (w0 == 1u)                 val = ((const int*)ego)[gid] != 0;             // int32
  else if (w0 == 0x3F800000u)   val = ((const float*)ego)[gid] != 0.0f;        // f32
  else if (w0 == 0x3F803F80u)   val = ((const unsigned short*)ego)[gid] != 0;  // bf16
  else                          val = ((const unsigned char*)ego)[gid] != 0;   // byte/bool
  int b = gid / (NT * 256);
  int t = (gid / 256) % NT;
  int n = gid % 256;
  maskf[t * BNODES + b * 256 + n] = val ? 1.0f : 0.0f;
}

// ---------------- edge-list build: streaming scatter ----------------
__global__ void zero_cnt_kernel(int* __restrict__ colcnt) {
  int gid = blockIdx.x * blockDim.x + threadIdx.x;
  if (gid < NROWS) colcnt[gid] = 0;
}

// one thread per float4 of adj: coalesced full-BW stream + atomic append.
// edge j->i stored into column list of (t,i) when A[t,j,i]!=0 && m[t,j]!=0.
__global__ __launch_bounds__(256) void build_edges_kernel(const float* __restrict__ adj,
                                                          const float* __restrict__ maskf,
                                                          int* __restrict__ colcnt,
                                                          int* __restrict__ colidx) {
  size_t e4 = (size_t)blockIdx.x * 256 + threadIdx.x;   // 81920 blocks x 256 = exactly NROWS*BNODES/4
  const float4 a = ((const float4*)adj)[e4];
  if (a.x == 0.0f && a.y == 0.0f && a.z == 0.0f && a.w == 0.0f) return;
  size_t e = e4 * 4;
  int i0 = (int)(e & (BNODES - 1));        // target column
  size_t row = e >> 11;                     // t*BNODES + j  (source row)
  if (maskf[row] == 0.0f) return;           // m[j]
  int t = (int)(row >> 11);
  int j = (int)(row & (BNODES - 1));
  int base = t * BNODES;
  if (a.x != 0.0f) { int p = atomicAdd(&colcnt[base + i0 + 0], 1); if (p < CAP) colidx[(size_t)(base + i0 + 0) * CAP + p] = j; }
  if (a.y != 0.0f) { int p = atomicAdd(&colcnt[base + i0 + 1], 1); if (p < CAP) colidx[(size_t)(base + i0 + 1) * CAP + p] = j; }
  if (a.z != 0.0f) { int p = atomicAdd(&colcnt[base + i0 + 2], 1); if (p < CAP) colidx[(size_t)(base + i0 + 2) * CAP + p] = j; }
  if (a.w != 0.0f) { int p = atomicAdd(&colcnt[base + i0 + 3], 1); if (p < CAP) colidx[(size_t)(base + i0 + 3) * CAP + p] = j; }
}

// dinv from UNCAPPED count (matches reference degree), then clamp stored count.
__global__ void finalize_deg_kernel(const float* __restrict__ maskf, int* __restrict__ colcnt,
                                    float* __restrict__ dinv) {
  int gid = blockIdx.x * blockDim.x + threadIdx.x;
  if (gid >= NROWS) return;
  int cnt = colcnt[gid];
  dinv[gid] = (maskf[gid] != 0.0f) ? rsqrtf((float)cnt + 1.0f) : 0.0f;
  colcnt[gid] = cnt < CAP ? cnt : CAP;
}

// ---------------- first GCN linear: [NROWS,2] @ [2,128] ----------------
__global__ void lin0_kernel(const float* __restrict__ x, const float* __restrict__ w,
                            float* __restrict__ out) {
  int gid = blockIdx.x * blockDim.x + threadIdx.x;
  if (gid >= NROWS * HDIM) return;
  int r = gid >> 7, c = gid & 127;
  out[gid] = x[r * 2] * w[c] + x[r * 2 + 1] * w[HDIM + c];
}

// ---------------- SpMM: out = S @ Y using sparse columns ----------------
// out[i,c] = dinv[i] * ( sum_j dinv[j]*Y[j,c] + dinv[i]*Y[i,c] )
__global__ __launch_bounds__(HDIM) void spmm_kernel(const float* __restrict__ Y,
                                                    const float* __restrict__ dinv,
                                                    const int* __restrict__ colcnt,
                                                    const int* __restrict__ colidx,
                                                    float* __restrict__ out) {
  int r = blockIdx.x;
  int c = threadIdx.x;
  int t = r / BNODES;
  float di = dinv[r];
  float* orow = out + (size_t)r * HDIM;
  if (di == 0.0f) { orow[c] = 0.0f; return; }
  float acc = di * Y[(size_t)r * HDIM + c];
  int cnt = colcnt[r];
  const int* cols = colidx + (size_t)r * CAP;
  const float* dt = dinv + t * BNODES;
  const float* Yt = Y + (size_t)t * BNODES * HDIM;
  for (int k = 0; k < cnt; ++k) {
    int j = cols[k];
    acc += dt[j] * Yt[(size_t)j * HDIM + c];
  }
  orow[c] = di * acc;
}

// ---------------- fused LayerNorm (+bias pre, +residual pre/post, +relu) ----------------
__global__ __launch_bounds__(HDIM) void ln_kernel(const float* __restrict__ src,
                                                  const float* __restrict__ bias,
                                                  const float* __restrict__ pre,
                                                  const float* __restrict__ gamma,
                                                  const float* __restrict__ beta,
                                                  const float* __restrict__ post,
                                                  int relu, float* __restrict__ dst) {
  int r = blockIdx.x, c = threadIdx.x;
  size_t idx = (size_t)r * HDIM + c;
  float v = src[idx];
  if (bias) v += bias[c];
  if (pre) v += pre[idx];
  float s = v, q = v * v;
  #pragma unroll
  for (int off = 32; off > 0; off >>= 1) {
    s += __shfl_down(s, off, 64);
    q += __shfl_down(q, off, 64);
  }
  __shared__ float ls[2], lq[2];
  int wid = c >> 6, lane = c & 63;
  if (lane == 0) { ls[wid] = s; lq[wid] = q; }
  __syncthreads();
  float mu = (ls[0] + ls[1]) * (1.0f / HDIM);
  float var = (lq[0] + lq[1]) * (1.0f / HDIM) - mu * mu;
  var = fmaxf(var, 0.0f);
  float rs = rsqrtf(var + 1e-5f);
  float o = (v - mu) * rs * gamma[c] + beta[c];
  if (post) o += post[idx];
  if (relu) o = fmaxf(o, 0.0f);
  dst[idx] = o;
}

// ---------------- GEMM: C[M,N] = A[M,K] @ B[K,N] (+bias) (+relu) ----------------
// A rows read via wave-uniform addresses (scalar loads); B streamed coalesced.
__global__ __launch_bounds__(128) void gemm_kernel(const float* __restrict__ A,
                                                   const float* __restrict__ B,
                                                   const float* __restrict__ bias,
                                                   float* __restrict__ C,
                                                   int K, int N, int relu) {
  const int TM = 16;
  int c = blockIdx.x * 128 + threadIdx.x;
  int row0 = blockIdx.y * TM;
  float acc[TM];
  float binit = bias ? bias[c] : 0.0f;
  #pragma unroll
  for (int m = 0; m < TM; ++m) acc[m] = binit;
  int K4 = K >> 2;
  for (int k4 = 0; k4 < K4; ++k4) {
    float b0 = B[(size_t)(4 * k4 + 0) * N + c];
    float b1 = B[(size_t)(4 * k4 + 1) * N + c];
    float b2 = B[(size_t)(4 * k4 + 2) * N + c];
    float b3 = B[(size_t)(4 * k4 + 3) * N + c];
    #pragma unroll
    for (int m = 0; m < TM; ++m) {
      float4 av = *reinterpret_cast<const float4*>(A + (size_t)(row0 + m) * K + 4 * k4);
      acc[m] = fmaf(av.x, b0, acc[m]);
      acc[m] = fmaf(av.y, b1, acc[m]);
      acc[m] = fmaf(av.z, b2, acc[m]);
      acc[m] = fmaf(av.w, b3, acc[m]);
    }
  }
  #pragma unroll
  for (int m = 0; m < TM; ++m) {
    float v = acc[m];
    if (relu) v = fmaxf(v, 0.0f);
    C[(size_t)(row0 + m) * N + c] = v;
  }
}

// ---------------- batched transpose: L mats of [R,C] -> [C,R] ----------------
__global__ void transpose_kernel(const float* __restrict__ src, float* __restrict__ dst,
                                 int R, int C, int n) {
  int gid = blockIdx.x * blockDim.x + threadIdx.x;
  if (gid >= n) return;
  int rc = R * C;
  int l = gid / rc, rem = gid % rc;
  int r = rem / C, cc = rem % C;
  dst[(size_t)l * rc + (size_t)cc * R + r] = src[gid];
}

// ---------------- GCN output -> transformer input layout ----------------
__global__ void to_x_kernel(const float* __restrict__ h, const float* __restrict__ maskf,
                            const float* __restrict__ pos, float* __restrict__ xbuf) {
  int gid = blockIdx.x * blockDim.x + threadIdx.x;
  if (gid >= NROWS * HDIM) return;
  int r = gid >> 7, c = gid & 127;
  int t = r / BNODES, bn = r % BNODES;
  xbuf[((size_t)bn * NT + t) * HDIM + c] = h[gid] * maskf[r] + pos[t * HDIM + c];
}

// ---------------- attention: one block per sequence bn ----------------
__global__ __launch_bounds__(256) void attn_kernel(const float* __restrict__ qkv,
                                                   const float* __restrict__ maskf,
                                                   float* __restrict__ o) {
  int bn = blockIdx.x;
  __shared__ float q[NT][HDIM], kk[NT][HDIM], vv[NT][HDIM];
  __shared__ float sc[8][NT][NT];
  int tid = threadIdx.x;
  for (int idx = tid; idx < NT * 384; idx += 256) {
    int t = idx / 384, col = idx % 384;
    float val = qkv[((size_t)bn * NT + t) * 384 + col];
    if (col < 128) q[t][col] = val;
    else if (col < 256) kk[t][col - 128] = val;
    else vv[t][col - 256] = val;
  }
  __syncthreads();
  for (int idx = tid; idx < 8 * NT * NT; idx += 256) {
    int h = idx / (NT * NT), rr = idx % (NT * NT);
    int tq = rr / NT, tk = rr % NT;
    float s = 0.0f;
    #pragma unroll
    for (int d = 0; d < 16; ++d) s += q[tq][h * 16 + d] * kk[tk][h * 16 + d];
    s *= 0.25f;  // 1/sqrt(16)
    if (maskf[tk * BNODES + bn] == 0.0f) s = -1e30f;
    sc[h][tq][tk] = s;
  }
  __syncthreads();
  if (tid < 8 * NT) {
    int h = tid / NT, tq = tid % NT;
    float mx = -1e30f;
    for (int tk = 0; tk < NT; ++tk) mx = fmaxf(mx, sc[h][tq][tk]);
    float sum = 0.0f;
    for (int tk = 0; tk < NT; ++tk) { float e = __expf(sc[h][tq][tk] - mx); sc[h][tq][tk] = e; sum += e; }
    float inv = 1.0f / sum;
    for (int tk = 0; tk < NT; ++tk) sc[h][tq][tk] *= inv;
  }
  __syncthreads();
  for (int idx = tid; idx < NT * HDIM; idx += 256) {
    int tq = idx / HDIM, col = idx % HDIM;
    int h = col >> 4;
    float s = 0.0f;
    #pragma unroll
    for (int tk = 0; tk < NT; ++tk) s += sc[h][tq][tk] * vv[tk][col];
    o[((size_t)bn * NT + tq) * HDIM + col] = s;
  }
}

extern "C" void kernel_launch(void* const* d_in, const int* in_sizes, int n_in,
                              void* d_out, int out_size, void* d_ws, size_t ws_size,
                              hipStream_t stream) {
  const void*  ego   = d_in[0];
  const float* xraw  = (const float*)d_in[1];
  const float* adj   = (const float*)d_in[2];
  const float* gcn1w = (const float*)d_in[3];
  const float* gcnws = (const float*)d_in[4];
  const float* gcnbs = (const float*)d_in[5];
  const float* lng   = (const float*)d_in[6];
  const float* lnb   = (const float*)d_in[7];
  const float* pos   = (const float*)d_in[8];
  const float* twqkv = (const float*)d_in[9];
  const float* tbqkv = (const float*)d_in[10];
  const float* two   = (const float*)d_in[11];
  const float* tbo   = (const float*)d_in[12];
  const float* tln1g = (const float*)d_in[13];
  const float* tln1b = (const float*)d_in[14];
  const float* tw1   = (const float*)d_in[15];
  const float* tb1   = (const float*)d_in[16];
  const float* tw2   = (const float*)d_in[17];
  const float* tb2   = (const float*)d_in[18];
  const float* tln2g = (const float*)d_in[19];
  const float* tln2b = (const float*)d_in[20];

  char* base = (char*)d_ws;
  size_t off = 0;
  auto alloc = [&](size_t bytes) -> void* {
    void* p = base + off;
    off = (off + bytes + 255) & ~(size_t)255;
    return p;
  };
  float* maskf  = (float*)alloc((size_t)NROWS * 4);
  float* dinv   = (float*)alloc((size_t)NROWS * 4);
  int*   colcnt = (int*)  alloc((size_t)NROWS * 4);
  int*   colidx = (int*)  alloc((size_t)NROWS * CAP * 4);
  float* wT     = (float*)alloc((size_t)983040 * 4);
  float* t1     = (float*)alloc((size_t)NROWS * HDIM * 4);
  float* t2     = (float*)alloc((size_t)NROWS * HDIM * 4);
  float* hbuf   = (float*)alloc((size_t)NROWS * HDIM * 4);
  float* xbuf   = (float*)alloc((size_t)NROWS * HDIM * 4);
  float* big    = (float*)alloc((size_t)NROWS * 512 * 4);   // qkv (x384) / ff hidden (x512)

  // transposed transformer weights layout inside wT:
  float* wTqkv = wT;              // 5 * 128*384
  float* wTo   = wT + 245760;     // 5 * 128*128
  float* wTw1  = wT + 327680;     // 5 * 128*512
  float* wTw2  = wT + 655360;     // 5 * 512*128

  // ---- setup ----
  expand_mask_kernel<<<160, 256, 0, stream>>>(ego, maskf);
  transpose_kernel<<<960, 256, 0, stream>>>(twqkv, wTqkv, 384, 128, 245760);
  transpose_kernel<<<320, 256, 0, stream>>>(two, wTo, 128, 128, 81920);
  transpose_kernel<<<1280, 256, 0, stream>>>(tw1, wTw1, 512, 128, 327680);
  transpose_kernel<<<1280, 256, 0, stream>>>(tw2, wTw2, 128, 512, 327680);
  zero_cnt_kernel<<<160, 256, 0, stream>>>(colcnt);
  build_edges_kernel<<<81920, 256, 0, stream>>>(adj, maskf, colcnt, colidx);
  finalize_deg_kernel<<<160, 256, 0, stream>>>(maskf, colcnt, dinv);

  // ---- GCN ----
  lin0_kernel<<<NROWS * HDIM / 256, 256, 0, stream>>>(xraw, gcn1w, t1);
  spmm_kernel<<<NROWS, HDIM, 0, stream>>>(t1, dinv, colcnt, colidx, t2);
  ln_kernel<<<NROWS, HDIM, 0, stream>>>(t2, gcnbs, nullptr, lng, lnb, nullptr, 1, hbuf);
  for (int i = 0; i < 5; ++i) {
    gemm_kernel<<<dim3(1, NROWS / 16), 128, 0, stream>>>(hbuf, gcnws + (size_t)i * 16384,
                                                         nullptr, t1, 128, 128, 0);
    spmm_kernel<<<NROWS, HDIM, 0, stream>>>(t1, dinv, colcnt, colidx, t2);
    ln_kernel<<<NROWS, HDIM, 0, stream>>>(t2, gcnbs + (i + 1) * 128, nullptr,
                                          lng + (i + 1) * 128, lnb + (i + 1) * 128,
                                          hbuf, 1, hbuf);
  }
  to_x_kernel<<<NROWS * HDIM / 256, 256, 0, stream>>>(hbuf, maskf, pos, xbuf);

  // ---- transformer ----
  for (int l = 0; l < 5; ++l) {
    gemm_kernel<<<dim3(3, NROWS / 16), 128, 0, stream>>>(xbuf, wTqkv + (size_t)l * 49152,
                                                         tbqkv + l * 384, big, 128, 384, 0);
    attn_kernel<<<BNODES, 256, 0, stream>>>(big, maskf, t1);
    gemm_kernel<<<dim3(1, NROWS / 16), 128, 0, stream>>>(t1, wTo + (size_t)l * 16384,
                                                         tbo + l * 128, t2, 128, 128, 0);
    ln_kernel<<<NROWS, HDIM, 0, stream>>>(t2, nullptr, xbuf, tln1g + l * 128,
                                          tln1b + l * 128, nullptr, 0, xbuf);
    gemm_kernel<<<dim3(4, NROWS / 16), 128, 0, stream>>>(xbuf, wTw1 + (size_t)l * 65536,
                                                         tb1 + l * 512, big, 128, 512, 1);
    gemm_kernel<<<dim3(1, NROWS / 16), 128, 0, stream>>>(big, wTw2 + (size_t)l * 65536,
                                                         tb2 + l * 128, t2, 512, 128, 0);
    ln_kernel<<<NROWS, HDIM, 0, stream>>>(t2, nullptr, xbuf, tln2g + l * 128,
                                          tln2b + l * 128, nullptr, 0, xbuf);
  }

  // x [BN,T,H] is exactly out [B,N,T,H]
  hipMemcpyAsync(d_out, xbuf, (size_t)NROWS * HDIM * 4, hipMemcpyDeviceToDevice, stream);
}

// Round 3
// 2015.535 us; speedup vs baseline: 3.9533x; 3.4739x over previous
//
#include <hip/hip_runtime.h>
#include <hip/hip_bf16.h>
#include <cstdint>
#include <cstddef>

#define BNODES 2048
#define NT 20
#define HDIM 128
#define NROWS (NT * BNODES)      // 40960
#define CAP 64

typedef __attribute__((ext_vector_type(8))) short short8;
typedef __attribute__((ext_vector_type(4))) float floatx4;

// ---------------- mask expansion (dtype auto-detect) ----------------
__global__ void expand_mask_kernel(const void* __restrict__ ego, float* __restrict__ maskf) {
  int gid = blockIdx.x * blockDim.x + threadIdx.x;
  if (gid >= 8 * NT * 256) return;
  unsigned int w0 = ((const unsigned int*)ego)[0];
  int val;
  if (w0 == 1u)                 val = ((const int*)ego)[gid] != 0;
  else if (w0 == 0x3F800000u)   val = ((const float*)ego)[gid] != 0.0f;
  else if (w0 == 0x3F803F80u)   val = ((const unsigned short*)ego)[gid] != 0;
  else                          val = ((const unsigned char*)ego)[gid] != 0;
  int b = gid / (NT * 256);
  int t = (gid / 256) % NT;
  int n = gid % 256;
  maskf[t * BNODES + b * 256 + n] = val ? 1.0f : 0.0f;
}

// ---------------- edge-list build: streaming scatter ----------------
__global__ void zero_cnt_kernel(int* __restrict__ colcnt) {
  int gid = blockIdx.x * blockDim.x + threadIdx.x;
  if (gid < NROWS) colcnt[gid] = 0;
}

__global__ __launch_bounds__(256) void build_edges_kernel(const float* __restrict__ adj,
                                                          const float* __restrict__ maskf,
                                                          int* __restrict__ colcnt,
                                                          int* __restrict__ colidx) {
  size_t e4 = (size_t)blockIdx.x * 256 + threadIdx.x;
  const float4 a = ((const float4*)adj)[e4];
  if (a.x == 0.0f && a.y == 0.0f && a.z == 0.0f && a.w == 0.0f) return;
  size_t e = e4 * 4;
  int i0 = (int)(e & (BNODES - 1));
  size_t row = e >> 11;                     // t*BNODES + j
  if (maskf[row] == 0.0f) return;
  int t = (int)(row >> 11);
  int j = (int)(row & (BNODES - 1));
  int base = t * BNODES;
  if (a.x != 0.0f) { int p = atomicAdd(&colcnt[base + i0 + 0], 1); if (p < CAP) colidx[(size_t)(base + i0 + 0) * CAP + p] = j; }
  if (a.y != 0.0f) { int p = atomicAdd(&colcnt[base + i0 + 1], 1); if (p < CAP) colidx[(size_t)(base + i0 + 1) * CAP + p] = j; }
  if (a.z != 0.0f) { int p = atomicAdd(&colcnt[base + i0 + 2], 1); if (p < CAP) colidx[(size_t)(base + i0 + 2) * CAP + p] = j; }
  if (a.w != 0.0f) { int p = atomicAdd(&colcnt[base + i0 + 3], 1); if (p < CAP) colidx[(size_t)(base + i0 + 3) * CAP + p] = j; }
}

__global__ void finalize_deg_kernel(const float* __restrict__ maskf, int* __restrict__ colcnt,
                                    float* __restrict__ dinv) {
  int gid = blockIdx.x * blockDim.x + threadIdx.x;
  if (gid >= NROWS) return;
  int cnt = colcnt[gid];
  dinv[gid] = (maskf[gid] != 0.0f) ? rsqrtf((float)cnt + 1.0f) : 0.0f;
  colcnt[gid] = cnt < CAP ? cnt : CAP;
}

// ---------------- weight conversion ----------------
__global__ void conv_bf16_kernel(const float* __restrict__ src, __hip_bfloat16* __restrict__ dst, int n) {
  int gid = blockIdx.x * blockDim.x + threadIdx.x;
  if (gid < n) dst[gid] = __float2bfloat16(src[gid]);
}

// gcn_ws [5][K=128][N=128] applied as h@W -> need Bt[n][k] = W[k][n]
__global__ void conv_t_bf16_kernel(const float* __restrict__ src, __hip_bfloat16* __restrict__ dst) {
  int gid = blockIdx.x * blockDim.x + threadIdx.x;
  if (gid >= 5 * 16384) return;
  int l = gid >> 14, rem = gid & 16383;
  int n = rem >> 7, k = rem & 127;
  dst[gid] = __float2bfloat16(src[(l << 14) + (k << 7) + n]);
}

// ---------------- first GCN linear: [NROWS,2] @ [2,128] ----------------
__global__ void lin0_kernel(const float* __restrict__ x, const float* __restrict__ w,
                            float* __restrict__ out) {
  int gid = blockIdx.x * blockDim.x + threadIdx.x;
  if (gid >= NROWS * HDIM) return;
  int r = gid >> 7, c = gid & 127;
  out[gid] = x[r * 2] * w[c] + x[r * 2 + 1] * w[HDIM + c];
}

// ---------------- SpMM (fp32) ----------------
__global__ __launch_bounds__(HDIM) void spmm_kernel(const float* __restrict__ Y,
                                                    const float* __restrict__ dinv,
                                                    const int* __restrict__ colcnt,
                                                    const int* __restrict__ colidx,
                                                    float* __restrict__ out) {
  int r = blockIdx.x;
  int c = threadIdx.x;
  int t = r / BNODES;
  float di = dinv[r];
  float* orow = out + (size_t)r * HDIM;
  if (di == 0.0f) { orow[c] = 0.0f; return; }
  float acc = di * Y[(size_t)r * HDIM + c];
  int cnt = colcnt[r];
  const int* cols = colidx + (size_t)r * CAP;
  const float* dt = dinv + t * BNODES;
  const float* Yt = Y + (size_t)t * BNODES * HDIM;
  for (int k = 0; k < cnt; ++k) {
    int j = cols[k];
    acc += dt[j] * Yt[(size_t)j * HDIM + c];
  }
  orow[c] = di * acc;
}

// ---------------- fused LayerNorm; optional bf16 mirror output ----------------
__global__ __launch_bounds__(HDIM) void ln_kernel(const float* __restrict__ src,
                                                  const float* __restrict__ bias,
                                                  const float* __restrict__ pre,
                                                  const float* __restrict__ gamma,
                                                  const float* __restrict__ beta,
                                                  const float* __restrict__ post,
                                                  int relu, float* __restrict__ dst,
                                                  __hip_bfloat16* __restrict__ dst_bf) {
  int r = blockIdx.x, c = threadIdx.x;
  size_t idx = (size_t)r * HDIM + c;
  float v = src[idx];
  if (bias) v += bias[c];
  if (pre) v += pre[idx];
  float s = v, q = v * v;
  #pragma unroll
  for (int off = 32; off > 0; off >>= 1) {
    s += __shfl_down(s, off, 64);
    q += __shfl_down(q, off, 64);
  }
  __shared__ float ls[2], lq[2];
  int wid = c >> 6, lane = c & 63;
  if (lane == 0) { ls[wid] = s; lq[wid] = q; }
  __syncthreads();
  float mu = (ls[0] + ls[1]) * (1.0f / HDIM);
  float var = (lq[0] + lq[1]) * (1.0f / HDIM) - mu * mu;
  var = fmaxf(var, 0.0f);
  float rs = rsqrtf(var + 1e-5f);
  float o = (v - mu) * rs * gamma[c] + beta[c];
  if (post) o += post[idx];
  if (relu) o = fmaxf(o, 0.0f);
  if (dst) dst[idx] = o;
  if (dst_bf) dst_bf[idx] = __float2bfloat16(o);
}

// ---------------- MFMA GEMM: C[M,N] = A[M,K] @ Bt[N,K]^T (+bias)(+relu) ----------------
// 128x128 tile, 4 waves each 64x64 (4x4 of 16x16x32 bf16 MFMA), BK=32.
// LDS staged via global_load_lds width=16; k-chunks XOR-swizzled (slot = chunk ^ (row&3))
// so ds_read_b128 fragment loads are <=2-way bank-aliased.
__device__ __forceinline__ void async16(const void* g, void* l) {
  __builtin_amdgcn_global_load_lds(
      (const __attribute__((address_space(1))) unsigned int*)g,
      (__attribute__((address_space(3))) unsigned int*)l, 16, 0, 0);
}

__global__ __launch_bounds__(256) void gemm_bt_mfma(const __hip_bfloat16* __restrict__ A,
                                                    const __hip_bfloat16* __restrict__ Bt,
                                                    const float* __restrict__ bias,
                                                    float* __restrict__ Cf,
                                                    __hip_bfloat16* __restrict__ Cb,
                                                    int K, int N, int relu) {
  __shared__ __align__(16) __hip_bfloat16 As[128 * 32];
  __shared__ __align__(16) __hip_bfloat16 Bs[128 * 32];
  const int tid = threadIdx.x;
  const int w = tid >> 6, lane = tid & 63;
  const int n0 = blockIdx.x << 7, m0 = blockIdx.y << 7;
  const int wm = (w & 1) << 6, wn = (w >> 1) << 6;
  const int lr = lane & 15, lq = lane >> 4;

  floatx4 acc[4][4];
  #pragma unroll
  for (int mi = 0; mi < 4; ++mi)
    #pragma unroll
    for (int ni = 0; ni < 4; ++ni) acc[mi][ni] = (floatx4)0.0f;

  // staging indices (per wave: 2 calls of 1KB each for A and B)
  const int rl0 = (w << 5);               // wave's 32-row group base
  const int rsub = lane >> 2;             // 0..15 row within 16-row half
  const int slot = lane & 3;              // k-chunk slot this lane fills

  for (int k0 = 0; k0 < K; k0 += 32) {
    __syncthreads();
    #pragma unroll
    for (int c = 0; c < 2; ++c) {
      int rloc = rl0 + (c << 4) + rsub;
      int srcChunk = slot ^ (rloc & 3);
      size_t gOffA = ((size_t)(m0 + rloc) * K + k0) * 2 + (size_t)srcChunk * 16;
      size_t gOffB = ((size_t)(n0 + rloc) * K + k0) * 2 + (size_t)srcChunk * 16;
      async16((const char*)A + gOffA, (char*)As + ((rl0 + (c << 4)) << 6));
      async16((const char*)Bt + gOffB, (char*)Bs + ((rl0 + (c << 4)) << 6));
    }
    __syncthreads();

    short8 af[4], bf[4];
    #pragma unroll
    for (int mi = 0; mi < 4; ++mi) {
      int R = wm + (mi << 4) + lr;
      af[mi] = *(const short8*)(As + (R << 5) + ((lq ^ (R & 3)) << 3));
    }
    #pragma unroll
    for (int ni = 0; ni < 4; ++ni) {
      int R = wn + (ni << 4) + lr;
      bf[ni] = *(const short8*)(Bs + (R << 5) + ((lq ^ (R & 3)) << 3));
    }
    #pragma unroll
    for (int mi = 0; mi < 4; ++mi)
      #pragma unroll
      for (int ni = 0; ni < 4; ++ni)
        acc[mi][ni] = __builtin_amdgcn_mfma_f32_16x16x32_bf16(af[mi], bf[ni], acc[mi][ni], 0, 0, 0);
  }

  // epilogue: C[row=(lane>>4)*4+reg][col=lane&15] per 16x16 tile
  #pragma unroll
  for (int ni = 0; ni < 4; ++ni) {
    int cn = n0 + wn + (ni << 4) + lr;
    float bv = bias ? bias[cn] : 0.0f;
    #pragma unroll
    for (int mi = 0; mi < 4; ++mi) {
      #pragma unroll
      for (int r = 0; r < 4; ++r) {
        int rm = m0 + wm + (mi << 4) + (lq << 2) + r;
        float v = acc[mi][ni][r] + bv;
        if (relu) v = fmaxf(v, 0.0f);
        size_t o = (size_t)rm * N + cn;
        if (Cf) Cf[o] = v;
        if (Cb) Cb[o] = __float2bfloat16(v);
      }
    }
  }
}

// ---------------- GCN output -> transformer input layout (fp32 + bf16) ----------------
__global__ void to_x_kernel(const float* __restrict__ h, const float* __restrict__ maskf,
                            const float* __restrict__ pos, float* __restrict__ xbuf,
                            __hip_bfloat16* __restrict__ xbf) {
  int gid = blockIdx.x * blockDim.x + threadIdx.x;
  if (gid >= NROWS * HDIM) return;
  int r = gid >> 7, c = gid & 127;
  int t = r / BNODES, bn = r % BNODES;
  float v = h[gid] * maskf[r] + pos[t * HDIM + c];
  size_t o = ((size_t)bn * NT + t) * HDIM + c;
  xbuf[o] = v;
  xbf[o] = __float2bfloat16(v);
}

// ---------------- attention: one block per sequence bn (bf16 in/out) ----------------
__global__ __launch_bounds__(256) void attn_kernel(const __hip_bfloat16* __restrict__ qkv,
                                                   const float* __restrict__ maskf,
                                                   __hip_bfloat16* __restrict__ o) {
  int bn = blockIdx.x;
  __shared__ float q[NT][HDIM], kk[NT][HDIM], vv[NT][HDIM];
  __shared__ float sc[8][NT][NT];
  int tid = threadIdx.x;
  for (int idx = tid; idx < NT * 384; idx += 256) {
    int t = idx / 384, col = idx % 384;
    float val = __bfloat162float(qkv[((size_t)bn * NT + t) * 384 + col]);
    if (col < 128) q[t][col] = val;
    else if (col < 256) kk[t][col - 128] = val;
    else vv[t][col - 256] = val;
  }
  __syncthreads();
  for (int idx = tid; idx < 8 * NT * NT; idx += 256) {
    int h = idx / (NT * NT), rr = idx % (NT * NT);
    int tq = rr / NT, tk = rr % NT;
    float s = 0.0f;
    #pragma unroll
    for (int d = 0; d < 16; ++d) s += q[tq][h * 16 + d] * kk[tk][h * 16 + d];
    s *= 0.25f;
    if (maskf[tk * BNODES + bn] == 0.0f) s = -1e30f;
    sc[h][tq][tk] = s;
  }
  __syncthreads();
  if (tid < 8 * NT) {
    int h = tid / NT, tq = tid % NT;
    float mx = -1e30f;
    for (int tk = 0; tk < NT; ++tk) mx = fmaxf(mx, sc[h][tq][tk]);
    float sum = 0.0f;
    for (int tk = 0; tk < NT; ++tk) { float e = __expf(sc[h][tq][tk] - mx); sc[h][tq][tk] = e; sum += e; }
    float inv = 1.0f / sum;
    for (int tk = 0; tk < NT; ++tk) sc[h][tq][tk] *= inv;
  }
  __syncthreads();
  for (int idx = tid; idx < NT * HDIM; idx += 256) {
    int tq = idx / HDIM, col = idx % HDIM;
    int h = col >> 4;
    float s = 0.0f;
    #pragma unroll
    for (int tk = 0; tk < NT; ++tk) s += sc[h][tq][tk] * vv[tk][col];
    o[((size_t)bn * NT + tq) * HDIM + col] = __float2bfloat16(s);
  }
}

extern "C" void kernel_launch(void* const* d_in, const int* in_sizes, int n_in,
                              void* d_out, int out_size, void* d_ws, size_t ws_size,
                              hipStream_t stream) {
  const void*  ego   = d_in[0];
  const float* xraw  = (const float*)d_in[1];
  const float* adj   = (const float*)d_in[2];
  const float* gcn1w = (const float*)d_in[3];
  const float* gcnws = (const float*)d_in[4];
  const float* gcnbs = (const float*)d_in[5];
  const float* lng   = (const float*)d_in[6];
  const float* lnb   = (const float*)d_in[7];
  const float* pos   = (const float*)d_in[8];
  const float* twqkv = (const float*)d_in[9];
  const float* tbqkv = (const float*)d_in[10];
  const float* two   = (const float*)d_in[11];
  const float* tbo   = (const float*)d_in[12];
  const float* tln1g = (const float*)d_in[13];
  const float* tln1b = (const float*)d_in[14];
  const float* tw1   = (const float*)d_in[15];
  const float* tb1   = (const float*)d_in[16];
  const float* tw2   = (const float*)d_in[17];
  const float* tb2   = (const float*)d_in[18];
  const float* tln2g = (const float*)d_in[19];
  const float* tln2b = (const float*)d_in[20];

  char* base = (char*)d_ws;
  size_t off = 0;
  auto alloc = [&](size_t bytes) -> void* {
    void* p = base + off;
    off = (off + bytes + 255) & ~(size_t)255;
    return p;
  };
  float* maskf  = (float*)alloc((size_t)NROWS * 4);
  float* dinv   = (float*)alloc((size_t)NROWS * 4);
  int*   colcnt = (int*)  alloc((size_t)NROWS * 4);
  // region shared: colidx (GCN phase) / qkv_bf (transformer phase)
  void*  regA   = alloc((size_t)NROWS * 384 * 2);            // 31.5 MB
  int*   colidx = (int*)regA;                                // NROWS*CAP*4 = 10.5 MB
  __hip_bfloat16* qkv_bf = (__hip_bfloat16*)regA;
  // region shared: t1 fp32 (GCN) / big_bf (transformer ff hidden)
  void*  regB   = alloc((size_t)NROWS * 512 * 2);            // 42 MB
  float* t1     = (float*)regB;                              // 21 MB
  __hip_bfloat16* big_bf = (__hip_bfloat16*)regB;
  // region shared: hbuf_bf (GCN) / attn_bf (transformer)
  void*  regC   = alloc((size_t)NROWS * HDIM * 2);           // 10.5 MB
  __hip_bfloat16* hbuf_bf = (__hip_bfloat16*)regC;
  __hip_bfloat16* attn_bf = (__hip_bfloat16*)regC;
  float* t2     = (float*)alloc((size_t)NROWS * HDIM * 4);
  float* hbuf   = (float*)alloc((size_t)NROWS * HDIM * 4);
  float* xbuf   = (float*)alloc((size_t)NROWS * HDIM * 4);
  __hip_bfloat16* xbf = (__hip_bfloat16*)alloc((size_t)NROWS * HDIM * 2);
  __hip_bfloat16* wqkv_bf = (__hip_bfloat16*)alloc((size_t)245760 * 2);
  __hip_bfloat16* wo_bf   = (__hip_bfloat16*)alloc((size_t)81920 * 2);
  __hip_bfloat16* w1_bf   = (__hip_bfloat16*)alloc((size_t)327680 * 2);
  __hip_bfloat16* w2_bf   = (__hip_bfloat16*)alloc((size_t)327680 * 2);
  __hip_bfloat16* wsT_bf  = (__hip_bfloat16*)alloc((size_t)81920 * 2);

  // ---- setup ----
  expand_mask_kernel<<<160, 256, 0, stream>>>(ego, maskf);
  conv_bf16_kernel<<<960, 256, 0, stream>>>(twqkv, wqkv_bf, 245760);
  conv_bf16_kernel<<<320, 256, 0, stream>>>(two, wo_bf, 81920);
  conv_bf16_kernel<<<1280, 256, 0, stream>>>(tw1, w1_bf, 327680);
  conv_bf16_kernel<<<1280, 256, 0, stream>>>(tw2, w2_bf, 327680);
  conv_t_bf16_kernel<<<320, 256, 0, stream>>>(gcnws, wsT_bf);
  zero_cnt_kernel<<<160, 256, 0, stream>>>(colcnt);
  build_edges_kernel<<<81920, 256, 0, stream>>>(adj, maskf, colcnt, colidx);
  finalize_deg_kernel<<<160, 256, 0, stream>>>(maskf, colcnt, dinv);

  // ---- GCN ----
  lin0_kernel<<<NROWS * HDIM / 256, 256, 0, stream>>>(xraw, gcn1w, t1);
  spmm_kernel<<<NROWS, HDIM, 0, stream>>>(t1, dinv, colcnt, colidx, t2);
  ln_kernel<<<NROWS, HDIM, 0, stream>>>(t2, gcnbs, nullptr, lng, lnb, nullptr, 1, hbuf, hbuf_bf);
  for (int i = 0; i < 5; ++i) {
    gemm_bt_mfma<<<dim3(1, NROWS / 128), 256, 0, stream>>>(hbuf_bf, wsT_bf + (size_t)i * 16384,
                                                           nullptr, t1, nullptr, 128, 128, 0);
    spmm_kernel<<<NROWS, HDIM, 0, stream>>>(t1, dinv, colcnt, colidx, t2);
    ln_kernel<<<NROWS, HDIM, 0, stream>>>(t2, gcnbs + (i + 1) * 128, nullptr,
                                          lng + (i + 1) * 128, lnb + (i + 1) * 128,
                                          hbuf, 1, hbuf, hbuf_bf);
  }
  to_x_kernel<<<NROWS * HDIM / 256, 256, 0, stream>>>(hbuf, maskf, pos, xbuf, xbf);

  // ---- transformer ----
  for (int l = 0; l < 5; ++l) {
    gemm_bt_mfma<<<dim3(3, NROWS / 128), 256, 0, stream>>>(xbf, wqkv_bf + (size_t)l * 49152,
                                                           tbqkv + l * 384, nullptr, qkv_bf, 128, 384, 0);
    attn_kernel<<<BNODES, 256, 0, stream>>>(qkv_bf, maskf, attn_bf);
    gemm_bt_mfma<<<dim3(1, NROWS / 128), 256, 0, stream>>>(attn_bf, wo_bf + (size_t)l * 16384,
                                                           tbo + l * 128, t2, nullptr, 128, 128, 0);
    ln_kernel<<<NROWS, HDIM, 0, stream>>>(t2, nullptr, xbuf, tln1g + l * 128,
                                          tln1b + l * 128, nullptr, 0, xbuf, xbf);
    gemm_bt_mfma<<<dim3(4, NROWS / 128), 256, 0, stream>>>(xbf, w1_bf + (size_t)l * 65536,
                                                           tb1 + l * 512, nullptr, big_bf, 128, 512, 1);
    gemm_bt_mfma<<<dim3(1, NROWS / 128), 256, 0, stream>>>(big_bf, w2_bf + (size_t)l * 65536,
                                                           tb2 + l * 128, t2, nullptr, 512, 128, 0);
    ln_kernel<<<NROWS, HDIM, 0, stream>>>(t2, nullptr, xbuf, tln2g + l * 128,
                                          tln2b + l * 128, nullptr, 0, xbuf, xbf);
  }

  hipMemcpyAsync(d_out, xbuf, (size_t)NROWS * HDIM * 4, hipMemcpyDeviceToDevice, stream);
}

// Round 4
// 1757.843 us; speedup vs baseline: 4.5329x; 1.1466x over previous
//
#include <hip/hip_runtime.h>
#include <hip/hip_bf16.h>
#include <cstdint>
#include <cstddef>

#define BNODES 2048
#define NT 20
#define HDIM 128
#define NROWS (NT * BNODES)      // 40960
#define CAP 64

typedef __attribute__((ext_vector_type(8))) short short8;
typedef __attribute__((ext_vector_type(4))) float floatx4;

__device__ __forceinline__ float bf2f(short u) {
  return __uint_as_float(((unsigned int)(unsigned short)u) << 16);
}

// ---------------- mask expansion (dtype auto-detect) + colcnt zero ----------------
__global__ void expand_mask_kernel(const void* __restrict__ ego, float* __restrict__ maskf,
                                   int* __restrict__ colcnt) {
  int gid = blockIdx.x * blockDim.x + threadIdx.x;
  if (gid >= NROWS) return;
  unsigned int w0 = ((const unsigned int*)ego)[0];
  int val;
  if (w0 == 1u)                 val = ((const int*)ego)[gid] != 0;
  else if (w0 == 0x3F800000u)   val = ((const float*)ego)[gid] != 0.0f;
  else if (w0 == 0x3F803F80u)   val = ((const unsigned short*)ego)[gid] != 0;
  else                          val = ((const unsigned char*)ego)[gid] != 0;
  int b = gid / (NT * 256);
  int t = (gid / 256) % NT;
  int n = gid % 256;
  maskf[t * BNODES + b * 256 + n] = val ? 1.0f : 0.0f;
  colcnt[gid] = 0;
}

// ---------------- edge-list build: streaming scatter (mask early-out) ----------------
__global__ __launch_bounds__(256) void build_edges_kernel(const float* __restrict__ adj,
                                                          const float* __restrict__ maskf,
                                                          int* __restrict__ colcnt,
                                                          int* __restrict__ colidx) {
  size_t e4 = (size_t)blockIdx.x * 256 + threadIdx.x;
  size_t e = e4 * 4;
  size_t row = e >> 11;                     // t*BNODES + j (source row)
  if (maskf[row] == 0.0f) return;           // skip the load entirely: m[j]==0
  const float4 a = ((const float4*)adj)[e4];
  if (a.x == 0.0f && a.y == 0.0f && a.z == 0.0f && a.w == 0.0f) return;
  int i0 = (int)(e & (BNODES - 1));
  int t = (int)(row >> 11);
  int j = (int)(row & (BNODES - 1));
  int base = t * BNODES;
  if (a.x != 0.0f) { int p = atomicAdd(&colcnt[base + i0 + 0], 1); if (p < CAP) colidx[(size_t)(base + i0 + 0) * CAP + p] = j; }
  if (a.y != 0.0f) { int p = atomicAdd(&colcnt[base + i0 + 1], 1); if (p < CAP) colidx[(size_t)(base + i0 + 1) * CAP + p] = j; }
  if (a.z != 0.0f) { int p = atomicAdd(&colcnt[base + i0 + 2], 1); if (p < CAP) colidx[(size_t)(base + i0 + 2) * CAP + p] = j; }
  if (a.w != 0.0f) { int p = atomicAdd(&colcnt[base + i0 + 3], 1); if (p < CAP) colidx[(size_t)(base + i0 + 3) * CAP + p] = j; }
}

__global__ void finalize_deg_kernel(const float* __restrict__ maskf, int* __restrict__ colcnt,
                                    float* __restrict__ dinv) {
  int gid = blockIdx.x * blockDim.x + threadIdx.x;
  if (gid >= NROWS) return;
  int cnt = colcnt[gid];
  dinv[gid] = (maskf[gid] != 0.0f) ? rsqrtf((float)cnt + 1.0f) : 0.0f;
  colcnt[gid] = cnt < CAP ? cnt : CAP;
}

// ---------------- weight conversion (all 4 transformer weight sets in one) ----------------
__global__ void conv_all_kernel(const float* __restrict__ a, const float* __restrict__ b,
                                const float* __restrict__ c, const float* __restrict__ d,
                                __hip_bfloat16* __restrict__ oa, __hip_bfloat16* __restrict__ ob,
                                __hip_bfloat16* __restrict__ oc, __hip_bfloat16* __restrict__ od) {
  int gid = blockIdx.x * blockDim.x + threadIdx.x;   // 983040 total
  if (gid < 245760) { oa[gid] = __float2bfloat16(a[gid]); return; }
  gid -= 245760;
  if (gid < 81920) { ob[gid] = __float2bfloat16(b[gid]); return; }
  gid -= 81920;
  if (gid < 327680) { oc[gid] = __float2bfloat16(c[gid]); return; }
  gid -= 327680;
  od[gid] = __float2bfloat16(d[gid]);
}

// gcn_ws [5][K=128][N=128] applied as h@W -> need Bt[n][k] = W[k][n]
__global__ void conv_t_bf16_kernel(const float* __restrict__ src, __hip_bfloat16* __restrict__ dst) {
  int gid = blockIdx.x * blockDim.x + threadIdx.x;
  if (gid >= 5 * 16384) return;
  int l = gid >> 14, rem = gid & 16383;
  int n = rem >> 7, k = rem & 127;
  dst[gid] = __float2bfloat16(src[(l << 14) + (k << 7) + n]);
}

// ---------------- fused SpMM + bias + LN + residual + ReLU (+final permute) ----------------
// Y bf16 (GCN gemm output) or null => layer0: y(j,c) = xraw[2j]*g0 + xraw[2j+1]*g1
__global__ __launch_bounds__(HDIM) void spmm_ln_kernel(const __hip_bfloat16* __restrict__ Y,
                                                       const float* __restrict__ xraw,
                                                       const float* __restrict__ gw,
                                                       const float* __restrict__ dinv,
                                                       const int* __restrict__ colcnt,
                                                       const int* __restrict__ colidx,
                                                       const float* __restrict__ bias,
                                                       const float* __restrict__ gamma,
                                                       const float* __restrict__ beta,
                                                       const float* __restrict__ resid,
                                                       const float* __restrict__ maskf,
                                                       const float* __restrict__ pos,
                                                       float* __restrict__ dstF,
                                                       __hip_bfloat16* __restrict__ dstB) {
  int r = blockIdx.x, c = threadIdx.x;
  int t = r >> 11;
  float di = dinv[r];
  float g0 = 0.0f, g1 = 0.0f;
  if (!Y) { g0 = gw[c]; g1 = gw[HDIM + c]; }
  float acc = 0.0f;
  if (di != 0.0f) {
    float yself = Y ? bf2f(((const short*)Y)[(size_t)r * HDIM + c])
                    : fmaf(xraw[2 * r], g0, xraw[2 * r + 1] * g1);
    acc = di * yself;
    int cnt = colcnt[r];
    const int* cols = colidx + (size_t)r * CAP;
    const float* dt = dinv + t * BNODES;
    for (int k = 0; k < cnt; ++k) {
      int j = cols[k];
      size_t gr = (size_t)t * BNODES + j;
      float yv = Y ? bf2f(((const short*)Y)[gr * HDIM + c])
                   : fmaf(xraw[2 * gr], g0, xraw[2 * gr + 1] * g1);
      acc = fmaf(dt[j], yv, acc);
    }
    acc *= di;
  }
  float v = acc + bias[c];
  // LN over 128 threads (2 waves)
  float s = v, q = v * v;
  #pragma unroll
  for (int off = 32; off > 0; off >>= 1) {
    s += __shfl_down(s, off, 64);
    q += __shfl_down(q, off, 64);
  }
  __shared__ float ls[2], lq2[2];
  int wid = c >> 6, lane = c & 63;
  if (lane == 0) { ls[wid] = s; lq2[wid] = q; }
  __syncthreads();
  float mu = (ls[0] + ls[1]) * (1.0f / HDIM);
  float var = fmaxf((lq2[0] + lq2[1]) * (1.0f / HDIM) - mu * mu, 0.0f);
  float rs = rsqrtf(var + 1e-5f);
  float o = (v - mu) * rs * gamma[c] + beta[c];
  if (resid) o += resid[(size_t)r * HDIM + c];
  o = fmaxf(o, 0.0f);
  if (pos) {  // final GCN layer: write permuted x = h*m + pos
    int bn = r & (BNODES - 1);
    float val = o * maskf[r] + pos[t * HDIM + c];
    size_t oi = ((size_t)bn * NT + t) * HDIM + c;
    dstF[oi] = val;
    dstB[oi] = __float2bfloat16(val);
  } else {
    size_t oi = (size_t)r * HDIM + c;
    dstF[oi] = o;
    dstB[oi] = __float2bfloat16(o);
  }
}

// ---------------- MFMA GEMM: C[M,N] = A[M,K] @ Bt[N,K]^T (+bias)(+relu)(+fused LN) ----------------
// 128x128 tile, BK=128 (full-K for K=128), 4 waves x (4x4) 16x16x32 bf16 MFMA.
// LDS 64KB: As/Bs bf16 during compute, aliased as Cs fp32 for the fused-LN epilogue.
// 16B chunks XOR-swizzled: lds chunk s holds global chunk s^(row&15) -> ds_read_b128 2-way max.
__device__ __forceinline__ void async16(const void* g, void* l) {
  __builtin_amdgcn_global_load_lds(
      (const __attribute__((address_space(1))) unsigned int*)g,
      (__attribute__((address_space(3))) unsigned int*)l, 16, 0, 0);
}

__global__ __launch_bounds__(256) void gemm_fused(const __hip_bfloat16* __restrict__ A,
                                                  const __hip_bfloat16* __restrict__ Bt,
                                                  const float* __restrict__ bias,
                                                  int K, int N, int relu,
                                                  float* __restrict__ Cf,
                                                  __hip_bfloat16* __restrict__ Cb,
                                                  const float* __restrict__ resid,
                                                  const float* __restrict__ lng,
                                                  const float* __restrict__ lnb,
                                                  float* __restrict__ lnF,
                                                  __hip_bfloat16* __restrict__ lnB) {
  __shared__ __align__(16) char smem[65536];
  __hip_bfloat16* As = (__hip_bfloat16*)smem;            // 128x128 bf16
  __hip_bfloat16* Bs = As + 128 * 128;                   // 128x128 bf16
  float* Cs = (float*)smem;                              // 128x128 fp32 (aliased post-compute)

  const int tid = threadIdx.x;
  const int wv = tid >> 6, ln = tid & 63;
  const int n0 = blockIdx.x << 7, m0 = blockIdx.y << 7;
  const int wm = (wv & 1) << 6, wn = (wv >> 1) << 6;
  const int lr = ln & 15, lq = ln >> 4;
  const int rsub = ln >> 4;            // 0..3 (staging row within wave group)
  const int slot = ln & 15;            // 0..15 (lds chunk slot)

  floatx4 acc[4][4];
  #pragma unroll
  for (int mi = 0; mi < 4; ++mi)
    #pragma unroll
    for (int ni = 0; ni < 4; ++ni) acc[mi][ni] = (floatx4)0.0f;

  for (int k0 = 0; k0 < K; k0 += 128) {
    if (k0) __syncthreads();
    #pragma unroll
    for (int i = 0; i < 8; ++i) {
      int rloc = i * 16 + wv * 4 + rsub;
      int sc = slot ^ (rloc & 15);
      async16((const char*)A + ((size_t)(m0 + rloc) * K + k0) * 2 + (size_t)sc * 16,
              (char*)As + (size_t)(i * 16 + wv * 4) * 256);
      async16((const char*)Bt + ((size_t)(n0 + rloc) * K + k0) * 2 + (size_t)sc * 16,
              (char*)Bs + (size_t)(i * 16 + wv * 4) * 256);
    }
    __syncthreads();
    #pragma unroll
    for (int kc = 0; kc < 4; ++kc) {
      short8 af[4], bfr[4];
      #pragma unroll
      for (int mi = 0; mi < 4; ++mi) {
        int R = wm + (mi << 4) + lr;
        int ch = ((kc << 2) + lq) ^ (R & 15);
        af[mi] = *(const short8*)(As + (R << 7) + (ch << 3));
      }
      #pragma unroll
      for (int ni = 0; ni < 4; ++ni) {
        int R = wn + (ni << 4) + lr;
        int ch = ((kc << 2) + lq) ^ (R & 15);
        bfr[ni] = *(const short8*)(Bs + (R << 7) + (ch << 3));
      }
      #pragma unroll
      for (int mi = 0; mi < 4; ++mi)
        #pragma unroll
        for (int ni = 0; ni < 4; ++ni)
          acc[mi][ni] = __builtin_amdgcn_mfma_f32_16x16x32_bf16(af[mi], bfr[ni], acc[mi][ni], 0, 0, 0);
    }
  }

  if (!lng) {
    // plain epilogue
    #pragma unroll
    for (int ni = 0; ni < 4; ++ni) {
      int cn = n0 + wn + (ni << 4) + lr;
      float bv = bias ? bias[cn] : 0.0f;
      #pragma unroll
      for (int mi = 0; mi < 4; ++mi) {
        #pragma unroll
        for (int r = 0; r < 4; ++r) {
          int rm = m0 + wm + (mi << 4) + (lq << 2) + r;
          float v = acc[mi][ni][r] + bv;
          if (relu) v = fmaxf(v, 0.0f);
          size_t o = (size_t)rm * N + cn;
          if (Cf) Cf[o] = v;
          if (Cb) Cb[o] = __float2bfloat16(v);
        }
      }
    }
    return;
  }

  // fused-LN epilogue (requires N==128, gridDim.x==1): v = C + bias + resid; x = LN(v)
  __syncthreads();  // all LDS frag reads done before aliasing as Cs
  #pragma unroll
  for (int ni = 0; ni < 4; ++ni) {
    int cn = wn + (ni << 4) + lr;
    float bv = bias[cn];
    #pragma unroll
    for (int mi = 0; mi < 4; ++mi) {
      #pragma unroll
      for (int r = 0; r < 4; ++r) {
        int rl = wm + (mi << 4) + (lq << 2) + r;
        float v = acc[mi][ni][r] + bv + resid[(size_t)(m0 + rl) * HDIM + cn];
        Cs[(rl << 7) + cn] = v;
      }
    }
  }
  __syncthreads();
  float2 gam = *(const float2*)(lng + ln * 2);
  float2 bet = *(const float2*)(lnb + ln * 2);
  #pragma unroll 4
  for (int p = 0; p < 32; ++p) {
    int rl = p * 4 + wv;
    float2 xv = *(const float2*)(Cs + (rl << 7) + ln * 2);
    float s = xv.x + xv.y, q = xv.x * xv.x + xv.y * xv.y;
    #pragma unroll
    for (int off = 32; off > 0; off >>= 1) {
      s += __shfl_xor(s, off, 64);
      q += __shfl_xor(q, off, 64);
    }
    float mu = s * (1.0f / HDIM);
    float var = fmaxf(q * (1.0f / HDIM) - mu * mu, 0.0f);
    float rs = rsqrtf(var + 1e-5f);
    float o0 = (xv.x - mu) * rs * gam.x + bet.x;
    float o1 = (xv.y - mu) * rs * gam.y + bet.y;
    size_t rowoff = (size_t)(m0 + rl) * HDIM;
    if (lnF) *(float2*)(lnF + rowoff + ln * 2) = make_float2(o0, o1);
    if (lnB) {
      __hip_bfloat16 b0 = __float2bfloat16(o0), b1 = __float2bfloat16(o1);
      unsigned int pk = ((unsigned int)*(unsigned short*)&b1 << 16) | *(unsigned short*)&b0;
      *(unsigned int*)((char*)lnB + (rowoff + ln * 2) * 2) = pk;
    }
  }
}

// ---------------- attention: one block per sequence bn (bf16 in/out) ----------------
__global__ __launch_bounds__(256) void attn_kernel(const __hip_bfloat16* __restrict__ qkv,
                                                   const float* __restrict__ maskf,
                                                   __hip_bfloat16* __restrict__ o) {
  int bn = blockIdx.x;
  __shared__ float q[NT][HDIM], kk[NT][HDIM], vv[NT][HDIM];
  __shared__ float sc[8][NT][NT];
  int tid = threadIdx.x;
  for (int idx = tid; idx < NT * 48; idx += 256) {   // 960 short8 loads
    int t = idx / 48, c8 = idx % 48;
    short8 v8 = *(const short8*)((const short*)qkv + ((size_t)bn * NT + t) * 384 + c8 * 8);
    float* dst = (c8 < 16) ? &q[t][c8 * 8] : (c8 < 32) ? &kk[t][(c8 - 16) * 8] : &vv[t][(c8 - 32) * 8];
    #pragma unroll
    for (int i = 0; i < 8; ++i) dst[i] = bf2f(v8[i]);
  }
  __syncthreads();
  for (int idx = tid; idx < 8 * NT * NT; idx += 256) {
    int h = idx / (NT * NT), rr = idx % (NT * NT);
    int tq = rr / NT, tk = rr % NT;
    float s = 0.0f;
    #pragma unroll
    for (int d = 0; d < 16; ++d) s += q[tq][h * 16 + d] * kk[tk][h * 16 + d];
    s *= 0.25f;
    if (maskf[tk * BNODES + bn] == 0.0f) s = -1e30f;
    sc[h][tq][tk] = s;
  }
  __syncthreads();
  if (tid < 8 * NT) {
    int h = tid / NT, tq = tid % NT;
    float mx = -1e30f;
    for (int tk = 0; tk < NT; ++tk) mx = fmaxf(mx, sc[h][tq][tk]);
    float sum = 0.0f;
    for (int tk = 0; tk < NT; ++tk) { float e = __expf(sc[h][tq][tk] - mx); sc[h][tq][tk] = e; sum += e; }
    float inv = 1.0f / sum;
    for (int tk = 0; tk < NT; ++tk) sc[h][tq][tk] *= inv;
  }
  __syncthreads();
  for (int idx = tid; idx < NT * HDIM; idx += 256) {
    int tq = idx / HDIM, col = idx % HDIM;
    int h = col >> 4;
    float s = 0.0f;
    #pragma unroll
    for (int tk = 0; tk < NT; ++tk) s += sc[h][tq][tk] * vv[tk][col];
    o[((size_t)bn * NT + tq) * HDIM + col] = __float2bfloat16(s);
  }
}

extern "C" void kernel_launch(void* const* d_in, const int* in_sizes, int n_in,
                              void* d_out, int out_size, void* d_ws, size_t ws_size,
                              hipStream_t stream) {
  const void*  ego   = d_in[0];
  const float* xraw  = (const float*)d_in[1];
  const float* adj   = (const float*)d_in[2];
  const float* gcn1w = (const float*)d_in[3];
  const float* gcnws = (const float*)d_in[4];
  const float* gcnbs = (const float*)d_in[5];
  const float* lng   = (const float*)d_in[6];
  const float* lnb   = (const float*)d_in[7];
  const float* pos   = (const float*)d_in[8];
  const float* twqkv = (const float*)d_in[9];
  const float* tbqkv = (const float*)d_in[10];
  const float* two   = (const float*)d_in[11];
  const float* tbo   = (const float*)d_in[12];
  const float* tln1g = (const float*)d_in[13];
  const float* tln1b = (const float*)d_in[14];
  const float* tw1   = (const float*)d_in[15];
  const float* tb1   = (const float*)d_in[16];
  const float* tw2   = (const float*)d_in[17];
  const float* tb2   = (const float*)d_in[18];
  const float* tln2g = (const float*)d_in[19];
  const float* tln2b = (const float*)d_in[20];

  char* base = (char*)d_ws;
  size_t off = 0;
  auto alloc = [&](size_t bytes) -> void* {
    void* p = base + off;
    off = (off + bytes + 255) & ~(size_t)255;
    return p;
  };
  float* maskf  = (float*)alloc((size_t)NROWS * 4);
  float* dinv   = (float*)alloc((size_t)NROWS * 4);
  int*   colcnt = (int*)  alloc((size_t)NROWS * 4);
  // region shared: colidx (GCN phase) / qkv_bf (transformer phase)
  void*  regA   = alloc((size_t)NROWS * 384 * 2);
  int*   colidx = (int*)regA;
  __hip_bfloat16* qkv_bf = (__hip_bfloat16*)regA;
  // region shared: t1_bf (GCN gemm out) / big_bf (ff hidden)
  void*  regB   = alloc((size_t)NROWS * 512 * 2);
  __hip_bfloat16* t1_bf  = (__hip_bfloat16*)regB;
  __hip_bfloat16* big_bf = (__hip_bfloat16*)regB;
  // region shared: hbuf_bf (GCN) / attn_bf (transformer)
  void*  regC   = alloc((size_t)NROWS * HDIM * 2);
  __hip_bfloat16* hbuf_bf = (__hip_bfloat16*)regC;
  __hip_bfloat16* attn_bf = (__hip_bfloat16*)regC;
  float* hbuf   = (float*)alloc((size_t)NROWS * HDIM * 4);
  float* xbuf   = (float*)alloc((size_t)NROWS * HDIM * 4);
  __hip_bfloat16* xbf = (__hip_bfloat16*)alloc((size_t)NROWS * HDIM * 2);
  __hip_bfloat16* wqkv_bf = (__hip_bfloat16*)alloc((size_t)245760 * 2);
  __hip_bfloat16* wo_bf   = (__hip_bfloat16*)alloc((size_t)81920 * 2);
  __hip_bfloat16* w1_bf   = (__hip_bfloat16*)alloc((size_t)327680 * 2);
  __hip_bfloat16* w2_bf   = (__hip_bfloat16*)alloc((size_t)327680 * 2);
  __hip_bfloat16* wsT_bf  = (__hip_bfloat16*)alloc((size_t)81920 * 2);

  // ---- setup ----
  expand_mask_kernel<<<160, 256, 0, stream>>>(ego, maskf, colcnt);
  conv_all_kernel<<<3840, 256, 0, stream>>>(twqkv, two, tw1, tw2, wqkv_bf, wo_bf, w1_bf, w2_bf);
  conv_t_bf16_kernel<<<320, 256, 0, stream>>>(gcnws, wsT_bf);
  build_edges_kernel<<<81920, 256, 0, stream>>>(adj, maskf, colcnt, colidx);
  finalize_deg_kernel<<<160, 256, 0, stream>>>(maskf, colcnt, dinv);

  // ---- GCN ----
  // layer 0: SpMM computes x@gcn1_w on the fly; +b, LN, ReLU -> hbuf/hbuf_bf
  spmm_ln_kernel<<<NROWS, HDIM, 0, stream>>>(nullptr, xraw, gcn1w, dinv, colcnt, colidx,
                                             gcnbs, lng, lnb, nullptr, nullptr, nullptr,
                                             hbuf, hbuf_bf);
  for (int i = 0; i < 5; ++i) {
    gemm_fused<<<dim3(1, NROWS / 128), 256, 0, stream>>>(
        hbuf_bf, wsT_bf + (size_t)i * 16384, nullptr, 128, 128, 0,
        nullptr, t1_bf, nullptr, nullptr, nullptr, nullptr, nullptr);
    const float* fin_mask = (i == 4) ? maskf : nullptr;
    const float* fin_pos  = (i == 4) ? pos : nullptr;
    float* dF = (i == 4) ? xbuf : hbuf;
    __hip_bfloat16* dB = (i == 4) ? xbf : hbuf_bf;
    spmm_ln_kernel<<<NROWS, HDIM, 0, stream>>>(t1_bf, nullptr, nullptr, dinv, colcnt, colidx,
                                               gcnbs + (i + 1) * 128, lng + (i + 1) * 128,
                                               lnb + (i + 1) * 128, hbuf, fin_mask, fin_pos,
                                               dF, dB);
  }

  // ---- transformer ----
  for (int l = 0; l < 5; ++l) {
    gemm_fused<<<dim3(3, NROWS / 128), 256, 0, stream>>>(
        xbf, wqkv_bf + (size_t)l * 49152, tbqkv + l * 384, 128, 384, 0,
        nullptr, qkv_bf, nullptr, nullptr, nullptr, nullptr, nullptr);
    attn_kernel<<<BNODES, 256, 0, stream>>>(qkv_bf, maskf, attn_bf);
    // o-proj + residual + LN1 -> xbuf/xbf
    gemm_fused<<<dim3(1, NROWS / 128), 256, 0, stream>>>(
        attn_bf, wo_bf + (size_t)l * 16384, tbo + l * 128, 128, 128, 0,
        nullptr, nullptr, xbuf, tln1g + l * 128, tln1b + l * 128, xbuf, xbf);
    gemm_fused<<<dim3(4, NROWS / 128), 256, 0, stream>>>(
        xbf, w1_bf + (size_t)l * 65536, tb1 + l * 512, 128, 512, 1,
        nullptr, big_bf, nullptr, nullptr, nullptr, nullptr, nullptr);
    // ff2 + residual + LN2 -> xbuf/xbf (last layer: straight to d_out)
    float* oF = (l == 4) ? (float*)d_out : xbuf;
    __hip_bfloat16* oB = (l == 4) ? nullptr : xbf;
    gemm_fused<<<dim3(1, NROWS / 128), 256, 0, stream>>>(
        big_bf, w2_bf + (size_t)l * 65536, tb2 + l * 128, 512, 128, 0,
        nullptr, nullptr, xbuf, tln2g + l * 128, tln2b + l * 128, oF, oB);
  }
}

// Round 5
// 1655.302 us; speedup vs baseline: 4.8137x; 1.0619x over previous
//
#include <hip/hip_runtime.h>
#include <hip/hip_bf16.h>
#include <cstdint>
#include <cstddef>

#define BNODES 2048
#define NT 20
#define HDIM 128
#define NROWS (NT * BNODES)      // 40960
#define CAP 64

typedef __attribute__((ext_vector_type(8))) short short8;
typedef __attribute__((ext_vector_type(4))) float floatx4;

__device__ __forceinline__ float bf2f(short u) {
  return __uint_as_float(((unsigned int)(unsigned short)u) << 16);
}

// ---------------- combined setup: mask expand + colcnt zero + all weight converts ----------------
__global__ void setup_kernel(const void* __restrict__ ego, float* __restrict__ maskf,
                             int* __restrict__ colcnt,
                             const float* __restrict__ twqkv, const float* __restrict__ two,
                             const float* __restrict__ tw1, const float* __restrict__ tw2,
                             const float* __restrict__ gcnws,
                             __hip_bfloat16* __restrict__ wqkv, __hip_bfloat16* __restrict__ wo,
                             __hip_bfloat16* __restrict__ w1, __hip_bfloat16* __restrict__ w2,
                             __hip_bfloat16* __restrict__ wsT) {
  int gid = blockIdx.x * blockDim.x + threadIdx.x;
  if (gid < NROWS) {
    unsigned int w0 = ((const unsigned int*)ego)[0];
    int val;
    if (w0 == 1u)                 val = ((const int*)ego)[gid] != 0;
    else if (w0 == 0x3F800000u)   val = ((const float*)ego)[gid] != 0.0f;
    else if (w0 == 0x3F803F80u)   val = ((const unsigned short*)ego)[gid] != 0;
    else                          val = ((const unsigned char*)ego)[gid] != 0;
    int b = gid / (NT * 256);
    int t = (gid / 256) % NT;
    int n = gid % 256;
    maskf[t * BNODES + b * 256 + n] = val ? 1.0f : 0.0f;
    colcnt[gid] = 0;
    return;
  }
  gid -= NROWS;
  if (gid < 245760) { wqkv[gid] = __float2bfloat16(twqkv[gid]); return; }
  gid -= 245760;
  if (gid < 81920) { wo[gid] = __float2bfloat16(two[gid]); return; }
  gid -= 81920;
  if (gid < 327680) { w1[gid] = __float2bfloat16(tw1[gid]); return; }
  gid -= 327680;
  if (gid < 327680) { w2[gid] = __float2bfloat16(tw2[gid]); return; }
  gid -= 327680;
  if (gid < 81920) {  // gcn_ws [5][K][N] -> Bt[l][n][k]
    int l = gid >> 14, rem = gid & 16383;
    int n = rem >> 7, k = rem & 127;
    wsT[gid] = __float2bfloat16(gcnws[(l << 14) + (k << 7) + n]);
  }
}

// ---------------- edge-list build: streaming scatter (mask early-out) ----------------
__global__ __launch_bounds__(256) void build_edges_kernel(const float* __restrict__ adj,
                                                          const float* __restrict__ maskf,
                                                          int* __restrict__ colcnt,
                                                          int* __restrict__ colidx) {
  size_t e4 = (size_t)blockIdx.x * 256 + threadIdx.x;
  size_t e = e4 * 4;
  size_t row = e >> 11;                     // t*BNODES + j (source row)
  if (maskf[row] == 0.0f) return;           // m[j]==0: skip the load entirely
  const float4 a = ((const float4*)adj)[e4];
  if (a.x == 0.0f && a.y == 0.0f && a.z == 0.0f && a.w == 0.0f) return;
  int i0 = (int)(e & (BNODES - 1));
  int t = (int)(row >> 11);
  int j = (int)(row & (BNODES - 1));
  int base = t * BNODES;
  if (a.x != 0.0f) { int p = atomicAdd(&colcnt[base + i0 + 0], 1); if (p < CAP) colidx[(size_t)(base + i0 + 0) * CAP + p] = j; }
  if (a.y != 0.0f) { int p = atomicAdd(&colcnt[base + i0 + 1], 1); if (p < CAP) colidx[(size_t)(base + i0 + 1) * CAP + p] = j; }
  if (a.z != 0.0f) { int p = atomicAdd(&colcnt[base + i0 + 2], 1); if (p < CAP) colidx[(size_t)(base + i0 + 2) * CAP + p] = j; }
  if (a.w != 0.0f) { int p = atomicAdd(&colcnt[base + i0 + 3], 1); if (p < CAP) colidx[(size_t)(base + i0 + 3) * CAP + p] = j; }
}

__global__ void finalize_deg_kernel(const float* __restrict__ maskf, int* __restrict__ colcnt,
                                    float* __restrict__ dinv) {
  int gid = blockIdx.x * blockDim.x + threadIdx.x;
  if (gid >= NROWS) return;
  int cnt = colcnt[gid];
  dinv[gid] = (maskf[gid] != 0.0f) ? rsqrtf((float)cnt + 1.0f) : 0.0f;
  colcnt[gid] = cnt < CAP ? cnt : CAP;
}

// ---------------- GCN layer 0: SpMM(xraw on-the-fly @gcn1_w) + bias + LN + ReLU ----------------
__global__ __launch_bounds__(HDIM) void spmm_ln0_kernel(const float* __restrict__ xraw,
                                                        const float* __restrict__ gw,
                                                        const float* __restrict__ dinv,
                                                        const int* __restrict__ colcnt,
                                                        const int* __restrict__ colidx,
                                                        const float* __restrict__ bias,
                                                        const float* __restrict__ gamma,
                                                        const float* __restrict__ beta,
                                                        float* __restrict__ dstF,
                                                        __hip_bfloat16* __restrict__ dstB) {
  int r = blockIdx.x, c = threadIdx.x;
  int t = r >> 11;
  float di = dinv[r];
  float g0 = gw[c], g1 = gw[HDIM + c];
  float acc = 0.0f;
  if (di != 0.0f) {
    acc = di * fmaf(xraw[2 * r], g0, xraw[2 * r + 1] * g1);
    int cnt = colcnt[r];
    const int* cols = colidx + (size_t)r * CAP;
    const float* dt = dinv + t * BNODES;
    for (int k = 0; k < cnt; ++k) {
      int j = cols[k];
      size_t gr = (size_t)t * BNODES + j;
      acc = fmaf(dt[j], fmaf(xraw[2 * gr], g0, xraw[2 * gr + 1] * g1), acc);
    }
    acc *= di;
  }
  float v = acc + bias[c];
  float s = v, q = v * v;
  #pragma unroll
  for (int off = 32; off > 0; off >>= 1) {
    s += __shfl_down(s, off, 64);
    q += __shfl_down(q, off, 64);
  }
  __shared__ float ls[2], lq2[2];
  int wid = c >> 6, lane = c & 63;
  if (lane == 0) { ls[wid] = s; lq2[wid] = q; }
  __syncthreads();
  float mu = (ls[0] + ls[1]) * (1.0f / HDIM);
  float var = fmaxf((lq2[0] + lq2[1]) * (1.0f / HDIM) - mu * mu, 0.0f);
  float rs = rsqrtf(var + 1e-5f);
  float o = fmaxf((v - mu) * rs * gamma[c] + beta[c], 0.0f);
  size_t oi = (size_t)r * HDIM + c;
  dstF[oi] = o;
  dstB[oi] = __float2bfloat16(o);
}

// ---------------- pure SpMM gather: out_bf = S @ Y (bf16 -> bf16) ----------------
__global__ __launch_bounds__(HDIM) void spmm_kernel(const __hip_bfloat16* __restrict__ Y,
                                                    const float* __restrict__ dinv,
                                                    const int* __restrict__ colcnt,
                                                    const int* __restrict__ colidx,
                                                    __hip_bfloat16* __restrict__ out) {
  int r = blockIdx.x, c = threadIdx.x;
  int t = r >> 11;
  float di = dinv[r];
  size_t oi = (size_t)r * HDIM + c;
  if (di == 0.0f) { out[oi] = __float2bfloat16(0.0f); return; }
  const short* Ys = (const short*)Y;
  float acc = di * bf2f(Ys[oi]);
  int cnt = colcnt[r];
  const int* cols = colidx + (size_t)r * CAP;
  const float* dt = dinv + t * BNODES;
  const short* Yt = Ys + (size_t)t * BNODES * HDIM;
  for (int k = 0; k < cnt; ++k) {
    int j = cols[k];
    acc = fmaf(dt[j], bf2f(Yt[(size_t)j * HDIM + c]), acc);
  }
  out[oi] = __float2bfloat16(di * acc);
}

// ---------------- async 16B global->LDS ----------------
__device__ __forceinline__ void async16(const void* g, void* l) {
  __builtin_amdgcn_global_load_lds(
      (const __attribute__((address_space(1))) unsigned int*)g,
      (__attribute__((address_space(3))) unsigned int*)l, 16, 0, 0);
}

// ---------------- plain MFMA GEMM: C[M,N] = A[M,K] @ Bt[N,K]^T (+bias)(+relu), bf16 out ----------------
// 128x128 tile, BK=128, 4 waves x (4x4) 16x16x32 bf16 MFMA. XOR-swizzled 16B chunks.
__global__ __launch_bounds__(256) void gemm_plain(const __hip_bfloat16* __restrict__ A,
                                                  const __hip_bfloat16* __restrict__ Bt,
                                                  const float* __restrict__ bias,
                                                  int K, int N, int relu,
                                                  __hip_bfloat16* __restrict__ Cb) {
  __shared__ __align__(16) char smem[65536];
  __hip_bfloat16* As = (__hip_bfloat16*)smem;
  __hip_bfloat16* Bs = As + 128 * 128;
  const int tid = threadIdx.x;
  const int wv = tid >> 6, ln = tid & 63;
  const int n0 = blockIdx.x << 7, m0 = blockIdx.y << 7;
  const int wm = (wv & 1) << 6, wn = (wv >> 1) << 6;
  const int lr = ln & 15, lq = ln >> 4;

  floatx4 acc[4][4];
  #pragma unroll
  for (int mi = 0; mi < 4; ++mi)
    #pragma unroll
    for (int ni = 0; ni < 4; ++ni) acc[mi][ni] = (floatx4)0.0f;

  for (int k0 = 0; k0 < K; k0 += 128) {
    if (k0) __syncthreads();
    #pragma unroll
    for (int i = 0; i < 8; ++i) {
      int rloc = i * 16 + wv * 4 + lq;
      int sc = (ln & 15) ^ (rloc & 15);
      async16((const char*)A + ((size_t)(m0 + rloc) * K + k0) * 2 + (size_t)sc * 16,
              (char*)As + (size_t)(i * 16 + wv * 4) * 256);
      async16((const char*)Bt + ((size_t)(n0 + rloc) * K + k0) * 2 + (size_t)sc * 16,
              (char*)Bs + (size_t)(i * 16 + wv * 4) * 256);
    }
    __syncthreads();
    #pragma unroll
    for (int kc = 0; kc < 4; ++kc) {
      short8 af[4], bfr[4];
      #pragma unroll
      for (int mi = 0; mi < 4; ++mi) {
        int R = wm + (mi << 4) + lr;
        int ch = ((kc << 2) + lq) ^ (R & 15);
        af[mi] = *(const short8*)(As + (R << 7) + (ch << 3));
      }
      #pragma unroll
      for (int ni = 0; ni < 4; ++ni) {
        int R = wn + (ni << 4) + lr;
        int ch = ((kc << 2) + lq) ^ (R & 15);
        bfr[ni] = *(const short8*)(Bs + (R << 7) + (ch << 3));
      }
      #pragma unroll
      for (int mi = 0; mi < 4; ++mi)
        #pragma unroll
        for (int ni = 0; ni < 4; ++ni)
          acc[mi][ni] = __builtin_amdgcn_mfma_f32_16x16x32_bf16(af[mi], bfr[ni], acc[mi][ni], 0, 0, 0);
    }
  }
  #pragma unroll
  for (int ni = 0; ni < 4; ++ni) {
    int cn = n0 + wn + (ni << 4) + lr;
    float bv = bias ? bias[cn] : 0.0f;
    #pragma unroll
    for (int mi = 0; mi < 4; ++mi) {
      #pragma unroll
      for (int r = 0; r < 4; ++r) {
        int rm = m0 + wm + (mi << 4) + (lq << 2) + r;
        float v = acc[mi][ni][r] + bv;
        if (relu) v = fmaxf(v, 0.0f);
        Cb[(size_t)rm * N + cn] = __float2bfloat16(v);
      }
    }
  }
}

// ---------------- fused-LN MFMA GEMM: N==128 only, 64x128 tile (grid = M/64) ----------------
// gcn_mode=1:  out = relu(LN(A@Bt^T + bias) + resid)   [+ optional mask/pos permute]
// gcn_mode=0:  out = LN(A@Bt^T + bias + resid)
__global__ __launch_bounds__(256) void gemm_ln(const __hip_bfloat16* __restrict__ A,
                                               const __hip_bfloat16* __restrict__ Bt,
                                               const float* __restrict__ bias,
                                               int K, int gcn_mode,
                                               const float* __restrict__ resid,
                                               const float* __restrict__ lng,
                                               const float* __restrict__ lnb,
                                               const float* __restrict__ maskf,
                                               const float* __restrict__ pos,
                                               float* __restrict__ outF,
                                               __hip_bfloat16* __restrict__ outB) {
  __shared__ __align__(16) char smem[49152];
  __hip_bfloat16* As = (__hip_bfloat16*)smem;   // 64x128 bf16 (16KB)
  __hip_bfloat16* Bs = As + 64 * 128;           // 128x128 bf16 (32KB)
  float* Cs = (float*)smem;                     // 64x128 fp32 (32KB, aliased post-compute)
  const int tid = threadIdx.x;
  const int wv = tid >> 6, ln = tid & 63;
  const int m0 = blockIdx.x << 6;
  const int wm = (wv & 1) << 5, wn = (wv >> 1) << 6;
  const int lr = ln & 15, lq = ln >> 4;

  floatx4 acc[2][4];
  #pragma unroll
  for (int mi = 0; mi < 2; ++mi)
    #pragma unroll
    for (int ni = 0; ni < 4; ++ni) acc[mi][ni] = (floatx4)0.0f;

  for (int k0 = 0; k0 < K; k0 += 128) {
    if (k0) __syncthreads();
    #pragma unroll
    for (int i = 0; i < 4; ++i) {   // A: 64 rows
      int rloc = i * 16 + wv * 4 + lq;
      int sc = (ln & 15) ^ (rloc & 15);
      async16((const char*)A + ((size_t)(m0 + rloc) * K + k0) * 2 + (size_t)sc * 16,
              (char*)As + (size_t)(i * 16 + wv * 4) * 256);
    }
    #pragma unroll
    for (int i = 0; i < 8; ++i) {   // B: 128 rows
      int rloc = i * 16 + wv * 4 + lq;
      int sc = (ln & 15) ^ (rloc & 15);
      async16((const char*)Bt + ((size_t)rloc * K + k0) * 2 + (size_t)sc * 16,
              (char*)Bs + (size_t)(i * 16 + wv * 4) * 256);
    }
    __syncthreads();
    #pragma unroll
    for (int kc = 0; kc < 4; ++kc) {
      short8 af[2], bfr[4];
      #pragma unroll
      for (int mi = 0; mi < 2; ++mi) {
        int R = wm + (mi << 4) + lr;
        int ch = ((kc << 2) + lq) ^ (R & 15);
        af[mi] = *(const short8*)(As + (R << 7) + (ch << 3));
      }
      #pragma unroll
      for (int ni = 0; ni < 4; ++ni) {
        int R = wn + (ni << 4) + lr;
        int ch = ((kc << 2) + lq) ^ (R & 15);
        bfr[ni] = *(const short8*)(Bs + (R << 7) + (ch << 3));
      }
      #pragma unroll
      for (int mi = 0; mi < 2; ++mi)
        #pragma unroll
        for (int ni = 0; ni < 4; ++ni)
          acc[mi][ni] = __builtin_amdgcn_mfma_f32_16x16x32_bf16(af[mi], bfr[ni], acc[mi][ni], 0, 0, 0);
    }
  }

  // stage C (+bias, +pre-LN resid for transformer) into LDS fp32
  __syncthreads();
  #pragma unroll
  for (int ni = 0; ni < 4; ++ni) {
    int cn = wn + (ni << 4) + lr;
    float bv = bias[cn];
    #pragma unroll
    for (int mi = 0; mi < 2; ++mi) {
      #pragma unroll
      for (int r = 0; r < 4; ++r) {
        int rl = wm + (mi << 4) + (lq << 2) + r;
        float v = acc[mi][ni][r] + bv;
        if (!gcn_mode) v += resid[(size_t)(m0 + rl) * HDIM + cn];
        Cs[(rl << 7) + cn] = v;
      }
    }
  }
  __syncthreads();
  float2 gam = *(const float2*)(lng + ln * 2);
  float2 bet = *(const float2*)(lnb + ln * 2);
  #pragma unroll 4
  for (int p = 0; p < 16; ++p) {
    int rl = p * 4 + wv;
    int grow = m0 + rl;
    float2 xv = *(const float2*)(Cs + (rl << 7) + ln * 2);
    float s = xv.x + xv.y, q = xv.x * xv.x + xv.y * xv.y;
    #pragma unroll
    for (int off = 32; off > 0; off >>= 1) {
      s += __shfl_xor(s, off, 64);
      q += __shfl_xor(q, off, 64);
    }
    float mu = s * (1.0f / HDIM);
    float var = fmaxf(q * (1.0f / HDIM) - mu * mu, 0.0f);
    float rs = rsqrtf(var + 1e-5f);
    float o0 = (xv.x - mu) * rs * gam.x + bet.x;
    float o1 = (xv.y - mu) * rs * gam.y + bet.y;
    if (gcn_mode) {
      float2 rv = *(const float2*)(resid + (size_t)grow * HDIM + ln * 2);
      o0 = fmaxf(o0 + rv.x, 0.0f);
      o1 = fmaxf(o1 + rv.y, 0.0f);
    }
    size_t oi;
    if (pos) {  // final GCN layer: x = h*m + pos, permuted [bn,t]
      int t = grow >> 11, bn = grow & (BNODES - 1);
      float m = maskf[grow];
      float2 pv = *(const float2*)(pos + t * HDIM + ln * 2);
      o0 = o0 * m + pv.x;
      o1 = o1 * m + pv.y;
      oi = ((size_t)bn * NT + t) * HDIM + ln * 2;
    } else {
      oi = (size_t)grow * HDIM + ln * 2;
    }
    if (outF) *(float2*)(outF + oi) = make_float2(o0, o1);
    if (outB) {
      __hip_bfloat16 b0 = __float2bfloat16(o0), b1 = __float2bfloat16(o1);
      unsigned int pk = ((unsigned int)*(unsigned short*)&b1 << 16) | *(unsigned short*)&b0;
      *(unsigned int*)((char*)outB + oi * 2) = pk;
    }
  }
}

// ---------------- attention: one block per sequence bn (bf16 in/out) ----------------
__global__ __launch_bounds__(256) void attn_kernel(const __hip_bfloat16* __restrict__ qkv,
                                                   const float* __restrict__ maskf,
                                                   __hip_bfloat16* __restrict__ o) {
  int bn = blockIdx.x;
  __shared__ float q[NT][HDIM], kk[NT][HDIM], vv[NT][HDIM];
  __shared__ float sc[8][NT][NT];
  int tid = threadIdx.x;
  for (int idx = tid; idx < NT * 48; idx += 256) {
    int t = idx / 48, c8 = idx % 48;
    short8 v8 = *(const short8*)((const short*)qkv + ((size_t)bn * NT + t) * 384 + c8 * 8);
    float* dst = (c8 < 16) ? &q[t][c8 * 8] : (c8 < 32) ? &kk[t][(c8 - 16) * 8] : &vv[t][(c8 - 32) * 8];
    #pragma unroll
    for (int i = 0; i < 8; ++i) dst[i] = bf2f(v8[i]);
  }
  __syncthreads();
  for (int idx = tid; idx < 8 * NT * NT; idx += 256) {
    int h = idx / (NT * NT), rr = idx % (NT * NT);
    int tq = rr / NT, tk = rr % NT;
    float s = 0.0f;
    #pragma unroll
    for (int d = 0; d < 16; ++d) s += q[tq][h * 16 + d] * kk[tk][h * 16 + d];
    s *= 0.25f;
    if (maskf[tk * BNODES + bn] == 0.0f) s = -1e30f;
    sc[h][tq][tk] = s;
  }
  __syncthreads();
  if (tid < 8 * NT) {
    int h = tid / NT, tq = tid % NT;
    float mx = -1e30f;
    for (int tk = 0; tk < NT; ++tk) mx = fmaxf(mx, sc[h][tq][tk]);
    float sum = 0.0f;
    for (int tk = 0; tk < NT; ++tk) { float e = __expf(sc[h][tq][tk] - mx); sc[h][tq][tk] = e; sum += e; }
    float inv = 1.0f / sum;
    for (int tk = 0; tk < NT; ++tk) sc[h][tq][tk] *= inv;
  }
  __syncthreads();
  for (int idx = tid; idx < NT * HDIM; idx += 256) {
    int tq = idx / HDIM, col = idx % HDIM;
    int h = col >> 4;
    float s = 0.0f;
    #pragma unroll
    for (int tk = 0; tk < NT; ++tk) s += sc[h][tq][tk] * vv[tk][col];
    o[((size_t)bn * NT + tq) * HDIM + col] = __float2bfloat16(s);
  }
}

extern "C" void kernel_launch(void* const* d_in, const int* in_sizes, int n_in,
                              void* d_out, int out_size, void* d_ws, size_t ws_size,
                              hipStream_t stream) {
  const void*  ego   = d_in[0];
  const float* xraw  = (const float*)d_in[1];
  const float* adj   = (const float*)d_in[2];
  const float* gcn1w = (const float*)d_in[3];
  const float* gcnws = (const float*)d_in[4];
  const float* gcnbs = (const float*)d_in[5];
  const float* lng   = (const float*)d_in[6];
  const float* lnb   = (const float*)d_in[7];
  const float* pos   = (const float*)d_in[8];
  const float* twqkv = (const float*)d_in[9];
  const float* tbqkv = (const float*)d_in[10];
  const float* two   = (const float*)d_in[11];
  const float* tbo   = (const float*)d_in[12];
  const float* tln1g = (const float*)d_in[13];
  const float* tln1b = (const float*)d_in[14];
  const float* tw1   = (const float*)d_in[15];
  const float* tb1   = (const float*)d_in[16];
  const float* tw2   = (const float*)d_in[17];
  const float* tb2   = (const float*)d_in[18];
  const float* tln2g = (const float*)d_in[19];
  const float* tln2b = (const float*)d_in[20];

  char* base = (char*)d_ws;
  size_t off = 0;
  auto alloc = [&](size_t bytes) -> void* {
    void* p = base + off;
    off = (off + bytes + 255) & ~(size_t)255;
    return p;
  };
  float* maskf  = (float*)alloc((size_t)NROWS * 4);
  float* dinv   = (float*)alloc((size_t)NROWS * 4);
  int*   colcnt = (int*)  alloc((size_t)NROWS * 4);
  // region shared: colidx (GCN phase) / qkv_bf (transformer phase)
  void*  regA   = alloc((size_t)NROWS * 384 * 2);
  int*   colidx = (int*)regA;
  __hip_bfloat16* qkv_bf = (__hip_bfloat16*)regA;
  // region shared: g_bf (GCN spmm out) / big_bf (ff hidden)
  void*  regB   = alloc((size_t)NROWS * 512 * 2);
  __hip_bfloat16* g_bf   = (__hip_bfloat16*)regB;
  __hip_bfloat16* big_bf = (__hip_bfloat16*)regB;
  // region shared: hbuf_bf (GCN) / attn_bf (transformer)
  void*  regC   = alloc((size_t)NROWS * HDIM * 2);
  __hip_bfloat16* hbuf_bf = (__hip_bfloat16*)regC;
  __hip_bfloat16* attn_bf = (__hip_bfloat16*)regC;
  float* hbuf   = (float*)alloc((size_t)NROWS * HDIM * 4);
  float* xbuf   = (float*)alloc((size_t)NROWS * HDIM * 4);
  __hip_bfloat16* xbf = (__hip_bfloat16*)alloc((size_t)NROWS * HDIM * 2);
  __hip_bfloat16* wqkv_bf = (__hip_bfloat16*)alloc((size_t)245760 * 2);
  __hip_bfloat16* wo_bf   = (__hip_bfloat16*)alloc((size_t)81920 * 2);
  __hip_bfloat16* w1_bf   = (__hip_bfloat16*)alloc((size_t)327680 * 2);
  __hip_bfloat16* w2_bf   = (__hip_bfloat16*)alloc((size_t)327680 * 2);
  __hip_bfloat16* wsT_bf  = (__hip_bfloat16*)alloc((size_t)81920 * 2);

  // ---- setup ----
  setup_kernel<<<4320, 256, 0, stream>>>(ego, maskf, colcnt, twqkv, two, tw1, tw2, gcnws,
                                         wqkv_bf, wo_bf, w1_bf, w2_bf, wsT_bf);
  build_edges_kernel<<<81920, 256, 0, stream>>>(adj, maskf, colcnt, colidx);
  finalize_deg_kernel<<<160, 256, 0, stream>>>(maskf, colcnt, dinv);

  // ---- GCN (reassociated: S@(h@W) == (S@h)@W) ----
  spmm_ln0_kernel<<<NROWS, HDIM, 0, stream>>>(xraw, gcn1w, dinv, colcnt, colidx,
                                              gcnbs, lng, lnb, hbuf, hbuf_bf);
  for (int i = 0; i < 5; ++i) {
    spmm_kernel<<<NROWS, HDIM, 0, stream>>>(hbuf_bf, dinv, colcnt, colidx, g_bf);
    const float* fm = (i == 4) ? maskf : nullptr;
    const float* fp = (i == 4) ? pos : nullptr;
    float* oF = (i == 4) ? xbuf : hbuf;
    __hip_bfloat16* oB = (i == 4) ? xbf : hbuf_bf;
    gemm_ln<<<NROWS / 64, 256, 0, stream>>>(g_bf, wsT_bf + (size_t)i * 16384,
                                            gcnbs + (i + 1) * 128, 128, 1, hbuf,
                                            lng + (i + 1) * 128, lnb + (i + 1) * 128,
                                            fm, fp, oF, oB);
  }

  // ---- transformer ----
  for (int l = 0; l < 5; ++l) {
    gemm_plain<<<dim3(3, NROWS / 128), 256, 0, stream>>>(
        xbf, wqkv_bf + (size_t)l * 49152, tbqkv + l * 384, 128, 384, 0, qkv_bf);
    attn_kernel<<<BNODES, 256, 0, stream>>>(qkv_bf, maskf, attn_bf);
    gemm_ln<<<NROWS / 64, 256, 0, stream>>>(attn_bf, wo_bf + (size_t)l * 16384,
                                            tbo + l * 128, 128, 0, xbuf,
                                            tln1g + l * 128, tln1b + l * 128,
                                            nullptr, nullptr, xbuf, xbf);
    gemm_plain<<<dim3(4, NROWS / 128), 256, 0, stream>>>(
        xbf, w1_bf + (size_t)l * 65536, tb1 + l * 512, 128, 512, 1, big_bf);
    float* oF = (l == 4) ? (float*)d_out : xbuf;
    __hip_bfloat16* oB = (l == 4) ? nullptr : xbf;
    gemm_ln<<<NROWS / 64, 256, 0, stream>>>(big_bf, w2_bf + (size_t)l * 65536,
                                            tb2 + l * 128, 512, 0, xbuf,
                                            tln2g + l * 128, tln2b + l * 128,
                                            nullptr, nullptr, oF, oB);
  }
}

// Round 8
// 1529.694 us; speedup vs baseline: 5.2089x; 1.0821x over previous
//
#include <hip/hip_runtime.h>
#include <hip/hip_bf16.h>
#include <cstdint>
#include <cstddef>

#define BNODES 2048
#define NT 20
#define HDIM 128
#define NROWS (NT * BNODES)      // 40960
#define CAP 64
#define QP 129                   // padded LDS row stride (floats) for attn

typedef __attribute__((ext_vector_type(8))) short short8;
typedef __attribute__((ext_vector_type(4))) float floatx4;

__device__ __forceinline__ float bf2f(short u) {
  return __uint_as_float(((unsigned int)(unsigned short)u) << 16);
}

// ---------------- combined setup: mask expand + colcnt zero + all weight converts ----------------
__global__ void setup_kernel(const void* __restrict__ ego, float* __restrict__ maskf,
                             int* __restrict__ colcnt,
                             const float* __restrict__ twqkv, const float* __restrict__ two,
                             const float* __restrict__ tw1, const float* __restrict__ tw2,
                             const float* __restrict__ gcnws,
                             __hip_bfloat16* __restrict__ wqkv, __hip_bfloat16* __restrict__ wo,
                             __hip_bfloat16* __restrict__ w1, __hip_bfloat16* __restrict__ w2,
                             __hip_bfloat16* __restrict__ wsT) {
  int gid = blockIdx.x * blockDim.x + threadIdx.x;
  if (gid < NROWS) {
    unsigned int w0 = ((const unsigned int*)ego)[0];
    int val;
    if (w0 == 1u)                 val = ((const int*)ego)[gid] != 0;
    else if (w0 == 0x3F800000u)   val = ((const float*)ego)[gid] != 0.0f;
    else if (w0 == 0x3F803F80u)   val = ((const unsigned short*)ego)[gid] != 0;
    else                          val = ((const unsigned char*)ego)[gid] != 0;
    int b = gid / (NT * 256);
    int t = (gid / 256) % NT;
    int n = gid % 256;
    maskf[t * BNODES + b * 256 + n] = val ? 1.0f : 0.0f;
    colcnt[gid] = 0;
    return;
  }
  gid -= NROWS;
  if (gid < 245760) { wqkv[gid] = __float2bfloat16(twqkv[gid]); return; }
  gid -= 245760;
  if (gid < 81920) { wo[gid] = __float2bfloat16(two[gid]); return; }
  gid -= 81920;
  if (gid < 327680) { w1[gid] = __float2bfloat16(tw1[gid]); return; }
  gid -= 327680;
  if (gid < 327680) { w2[gid] = __float2bfloat16(tw2[gid]); return; }
  gid -= 327680;
  if (gid < 81920) {  // gcn_ws [5][K][N] -> Bt[l][n][k]
    int l = gid >> 14, rem = gid & 16383;
    int n = rem >> 7, k = rem & 127;
    wsT[gid] = __float2bfloat16(gcnws[(l << 14) + (k << 7) + n]);
  }
}

// ---------------- edge-list build: streaming scatter (mask early-out) ----------------
__global__ __launch_bounds__(256) void build_edges_kernel(const float* __restrict__ adj,
                                                          const float* __restrict__ maskf,
                                                          int* __restrict__ colcnt,
                                                          int* __restrict__ colidx) {
  size_t e4 = (size_t)blockIdx.x * 256 + threadIdx.x;
  size_t e = e4 * 4;
  size_t row = e >> 11;                     // t*BNODES + j (source row)
  if (maskf[row] == 0.0f) return;           // m[j]==0: skip the load entirely
  const float4 a = ((const float4*)adj)[e4];
  if (a.x == 0.0f && a.y == 0.0f && a.z == 0.0f && a.w == 0.0f) return;
  int i0 = (int)(e & (BNODES - 1));
  int t = (int)(row >> 11);
  int j = (int)(row & (BNODES - 1));
  int base = t * BNODES;
  if (a.x != 0.0f) { int p = atomicAdd(&colcnt[base + i0 + 0], 1); if (p < CAP) colidx[(size_t)(base + i0 + 0) * CAP + p] = j; }
  if (a.y != 0.0f) { int p = atomicAdd(&colcnt[base + i0 + 1], 1); if (p < CAP) colidx[(size_t)(base + i0 + 1) * CAP + p] = j; }
  if (a.z != 0.0f) { int p = atomicAdd(&colcnt[base + i0 + 2], 1); if (p < CAP) colidx[(size_t)(base + i0 + 2) * CAP + p] = j; }
  if (a.w != 0.0f) { int p = atomicAdd(&colcnt[base + i0 + 3], 1); if (p < CAP) colidx[(size_t)(base + i0 + 3) * CAP + p] = j; }
}

__global__ void finalize_deg_kernel(const float* __restrict__ maskf, int* __restrict__ colcnt,
                                    float* __restrict__ dinv) {
  int gid = blockIdx.x * blockDim.x + threadIdx.x;
  if (gid >= NROWS) return;
  int cnt = colcnt[gid];
  dinv[gid] = (maskf[gid] != 0.0f) ? rsqrtf((float)cnt + 1.0f) : 0.0f;
  colcnt[gid] = cnt < CAP ? cnt : CAP;
}

// ---------------- GCN layer 0: SpMM(xraw on-the-fly @gcn1_w) + bias + LN + ReLU ----------------
__global__ __launch_bounds__(HDIM) void spmm_ln0_kernel(const float* __restrict__ xraw,
                                                        const float* __restrict__ gw,
                                                        const float* __restrict__ dinv,
                                                        const int* __restrict__ colcnt,
                                                        const int* __restrict__ colidx,
                                                        const float* __restrict__ bias,
                                                        const float* __restrict__ gamma,
                                                        const float* __restrict__ beta,
                                                        float* __restrict__ dstF,
                                                        __hip_bfloat16* __restrict__ dstB) {
  int r = blockIdx.x, c = threadIdx.x;
  int t = r >> 11;
  float di = dinv[r];
  float g0 = gw[c], g1 = gw[HDIM + c];
  float acc = 0.0f;
  if (di != 0.0f) {
    acc = di * fmaf(xraw[2 * r], g0, xraw[2 * r + 1] * g1);
    int cnt = colcnt[r];
    const int* cols = colidx + (size_t)r * CAP;
    const float* dt = dinv + t * BNODES;
    for (int k = 0; k < cnt; ++k) {
      int j = cols[k];
      size_t gr = (size_t)t * BNODES + j;
      acc = fmaf(dt[j], fmaf(xraw[2 * gr], g0, xraw[2 * gr + 1] * g1), acc);
    }
    acc *= di;
  }
  float v = acc + bias[c];
  float s = v, q = v * v;
  #pragma unroll
  for (int off = 32; off > 0; off >>= 1) {
    s += __shfl_down(s, off, 64);
    q += __shfl_down(q, off, 64);
  }
  __shared__ float ls[2], lq2[2];
  int wid = c >> 6, lane = c & 63;
  if (lane == 0) { ls[wid] = s; lq2[wid] = q; }
  __syncthreads();
  float mu = (ls[0] + ls[1]) * (1.0f / HDIM);
  float var = fmaxf((lq2[0] + lq2[1]) * (1.0f / HDIM) - mu * mu, 0.0f);
  float rs = rsqrtf(var + 1e-5f);
  float o = fmaxf((v - mu) * rs * gamma[c] + beta[c], 0.0f);
  size_t oi = (size_t)r * HDIM + c;
  dstF[oi] = o;
  dstB[oi] = __float2bfloat16(o);
}

// ---------------- pure SpMM gather: out_bf = S @ Y (bf16 -> bf16) ----------------
__global__ __launch_bounds__(HDIM) void spmm_kernel(const __hip_bfloat16* __restrict__ Y,
                                                    const float* __restrict__ dinv,
                                                    const int* __restrict__ colcnt,
                                                    const int* __restrict__ colidx,
                                                    __hip_bfloat16* __restrict__ out) {
  int r = blockIdx.x, c = threadIdx.x;
  int t = r >> 11;
  float di = dinv[r];
  size_t oi = (size_t)r * HDIM + c;
  if (di == 0.0f) { out[oi] = __float2bfloat16(0.0f); return; }
  const short* Ys = (const short*)Y;
  float acc = di * bf2f(Ys[oi]);
  int cnt = colcnt[r];
  const int* cols = colidx + (size_t)r * CAP;
  const float* dt = dinv + t * BNODES;
  const short* Yt = Ys + (size_t)t * BNODES * HDIM;
  for (int k = 0; k < cnt; ++k) {
    int j = cols[k];
    acc = fmaf(dt[j], bf2f(Yt[(size_t)j * HDIM + c]), acc);
  }
  out[oi] = __float2bfloat16(di * acc);
}

// ---------------- async 16B global->LDS ----------------
__device__ __forceinline__ void async16(const void* g, void* l) {
  __builtin_amdgcn_global_load_lds(
      (const __attribute__((address_space(1))) unsigned int*)g,
      (__attribute__((address_space(3))) unsigned int*)l, 16, 0, 0);
}

// ---------------- plain MFMA GEMM: C[M,N] = A[M,K] @ Bt[N,K]^T (+bias)(+relu), bf16 out ----------------
__global__ __launch_bounds__(256) void gemm_plain(const __hip_bfloat16* __restrict__ A,
                                                  const __hip_bfloat16* __restrict__ Bt,
                                                  const float* __restrict__ bias,
                                                  int K, int N, int relu,
                                                  __hip_bfloat16* __restrict__ Cb) {
  __shared__ __align__(16) char smem[65536];
  __hip_bfloat16* As = (__hip_bfloat16*)smem;
  __hip_bfloat16* Bs = As + 128 * 128;
  const int tid = threadIdx.x;
  const int wv = tid >> 6, ln = tid & 63;
  const int n0 = blockIdx.x << 7, m0 = blockIdx.y << 7;
  const int wm = (wv & 1) << 6, wn = (wv >> 1) << 6;
  const int lr = ln & 15, lq = ln >> 4;

  floatx4 acc[4][4];
  #pragma unroll
  for (int mi = 0; mi < 4; ++mi)
    #pragma unroll
    for (int ni = 0; ni < 4; ++ni) acc[mi][ni] = (floatx4)0.0f;

  for (int k0 = 0; k0 < K; k0 += 128) {
    if (k0) __syncthreads();
    #pragma unroll
    for (int i = 0; i < 8; ++i) {
      int rloc = i * 16 + wv * 4 + lq;
      int sc = (ln & 15) ^ (rloc & 15);
      async16((const char*)A + ((size_t)(m0 + rloc) * K + k0) * 2 + (size_t)sc * 16,
              (char*)As + (size_t)(i * 16 + wv * 4) * 256);
      async16((const char*)Bt + ((size_t)(n0 + rloc) * K + k0) * 2 + (size_t)sc * 16,
              (char*)Bs + (size_t)(i * 16 + wv * 4) * 256);
    }
    __syncthreads();
    #pragma unroll
    for (int kc = 0; kc < 4; ++kc) {
      short8 af[4], bfr[4];
      #pragma unroll
      for (int mi = 0; mi < 4; ++mi) {
        int R = wm + (mi << 4) + lr;
        int ch = ((kc << 2) + lq) ^ (R & 15);
        af[mi] = *(const short8*)(As + (R << 7) + (ch << 3));
      }
      #pragma unroll
      for (int ni = 0; ni < 4; ++ni) {
        int R = wn + (ni << 4) + lr;
        int ch = ((kc << 2) + lq) ^ (R & 15);
        bfr[ni] = *(const short8*)(Bs + (R << 7) + (ch << 3));
      }
      #pragma unroll
      for (int mi = 0; mi < 4; ++mi)
        #pragma unroll
        for (int ni = 0; ni < 4; ++ni)
          acc[mi][ni] = __builtin_amdgcn_mfma_f32_16x16x32_bf16(af[mi], bfr[ni], acc[mi][ni], 0, 0, 0);
    }
  }
  #pragma unroll
  for (int ni = 0; ni < 4; ++ni) {
    int cn = n0 + wn + (ni << 4) + lr;
    float bv = bias ? bias[cn] : 0.0f;
    #pragma unroll
    for (int mi = 0; mi < 4; ++mi) {
      #pragma unroll
      for (int r = 0; r < 4; ++r) {
        int rm = m0 + wm + (mi << 4) + (lq << 2) + r;
        float v = acc[mi][ni][r] + bv;
        if (relu) v = fmaxf(v, 0.0f);
        Cb[(size_t)rm * N + cn] = __float2bfloat16(v);
      }
    }
  }
}

// ---------------- fused-LN MFMA GEMM (N==128), 64x128 tile ----------------
// gcn_mode=1: out = relu(LN(A@Bt^T + bias) + residF)   [+ optional mask/pos permute]
// gcn_mode=0: out = LN(A@Bt^T + bias + residF)
// residF fp32 carry; in-place outF==residF is safe (rows block-owned).
__global__ __launch_bounds__(256) void gemm_ln(const __hip_bfloat16* __restrict__ A,
                                               const __hip_bfloat16* __restrict__ Bt,
                                               const float* __restrict__ bias,
                                               int K, int gcn_mode,
                                               const float* __restrict__ residF,
                                               const float* __restrict__ lng,
                                               const float* __restrict__ lnb,
                                               const float* __restrict__ maskf,
                                               const float* __restrict__ pos,
                                               float* __restrict__ outF,
                                               __hip_bfloat16* __restrict__ outB) {
  __shared__ __align__(16) char smem[49152];
  __hip_bfloat16* As = (__hip_bfloat16*)smem;   // 64x128 bf16 (16KB)
  __hip_bfloat16* Bs = As + 64 * 128;           // 128x128 bf16 (32KB)
  float* Cs = (float*)smem;                     // 64x128 fp32 (32KB, aliased post-compute)
  const int tid = threadIdx.x;
  const int wv = tid >> 6, ln = tid & 63;
  const int m0 = blockIdx.x << 6;
  const int wm = (wv & 1) << 5, wn = (wv >> 1) << 6;
  const int lr = ln & 15, lq = ln >> 4;

  floatx4 acc[2][4];
  #pragma unroll
  for (int mi = 0; mi < 2; ++mi)
    #pragma unroll
    for (int ni = 0; ni < 4; ++ni) acc[mi][ni] = (floatx4)0.0f;

  for (int k0 = 0; k0 < K; k0 += 128) {
    if (k0) __syncthreads();
    #pragma unroll
    for (int i = 0; i < 4; ++i) {   // A: 64 rows
      int rloc = i * 16 + wv * 4 + lq;
      int sc = (ln & 15) ^ (rloc & 15);
      async16((const char*)A + ((size_t)(m0 + rloc) * K + k0) * 2 + (size_t)sc * 16,
              (char*)As + (size_t)(i * 16 + wv * 4) * 256);
    }
    #pragma unroll
    for (int i = 0; i < 8; ++i) {   // B: 128 rows
      int rloc = i * 16 + wv * 4 + lq;
      int sc = (ln & 15) ^ (rloc & 15);
      async16((const char*)Bt + ((size_t)rloc * K + k0) * 2 + (size_t)sc * 16,
              (char*)Bs + (size_t)(i * 16 + wv * 4) * 256);
    }
    __syncthreads();
    #pragma unroll
    for (int kc = 0; kc < 4; ++kc) {
      short8 af[2], bfr[4];
      #pragma unroll
      for (int mi = 0; mi < 2; ++mi) {
        int R = wm + (mi << 4) + lr;
        int ch = ((kc << 2) + lq) ^ (R & 15);
        af[mi] = *(const short8*)(As + (R << 7) + (ch << 3));
      }
      #pragma unroll
      for (int ni = 0; ni < 4; ++ni) {
        int R = wn + (ni << 4) + lr;
        int ch = ((kc << 2) + lq) ^ (R & 15);
        bfr[ni] = *(const short8*)(Bs + (R << 7) + (ch << 3));
      }
      #pragma unroll
      for (int mi = 0; mi < 2; ++mi)
        #pragma unroll
        for (int ni = 0; ni < 4; ++ni)
          acc[mi][ni] = __builtin_amdgcn_mfma_f32_16x16x32_bf16(af[mi], bfr[ni], acc[mi][ni], 0, 0, 0);
    }
  }

  // stage C (+bias, +pre-LN fp32 resid for transformer) into LDS fp32
  __syncthreads();
  #pragma unroll
  for (int ni = 0; ni < 4; ++ni) {
    int cn = wn + (ni << 4) + lr;
    float bv = bias[cn];
    #pragma unroll
    for (int mi = 0; mi < 2; ++mi) {
      #pragma unroll
      for (int r = 0; r < 4; ++r) {
        int rl = wm + (mi << 4) + (lq << 2) + r;
        float v = acc[mi][ni][r] + bv;
        if (!gcn_mode) v += residF[(size_t)(m0 + rl) * HDIM + cn];
        Cs[(rl << 7) + cn] = v;
      }
    }
  }
  __syncthreads();
  float2 gam = *(const float2*)(lng + ln * 2);
  float2 bet = *(const float2*)(lnb + ln * 2);
  #pragma unroll 4
  for (int p = 0; p < 16; ++p) {
    int rl = p * 4 + wv;
    int grow = m0 + rl;
    float2 xv = *(const float2*)(Cs + (rl << 7) + ln * 2);
    float s = xv.x + xv.y, q = xv.x * xv.x + xv.y * xv.y;
    #pragma unroll
    for (int off = 32; off > 0; off >>= 1) {
      s += __shfl_xor(s, off, 64);
      q += __shfl_xor(q, off, 64);
    }
    float mu = s * (1.0f / HDIM);
    float var = fmaxf(q * (1.0f / HDIM) - mu * mu, 0.0f);
    float rs = rsqrtf(var + 1e-5f);
    float o0 = (xv.x - mu) * rs * gam.x + bet.x;
    float o1 = (xv.y - mu) * rs * gam.y + bet.y;
    if (gcn_mode) {   // post-LN fp32 residual + relu
      float2 rv = *(const float2*)(residF + (size_t)grow * HDIM + ln * 2);
      o0 = fmaxf(o0 + rv.x, 0.0f);
      o1 = fmaxf(o1 + rv.y, 0.0f);
    }
    size_t oi;
    if (pos) {  // final GCN layer: x = h*m + pos, permuted [bn,t]
      int t = grow >> 11, bn = grow & (BNODES - 1);
      float m = maskf[grow];
      float2 pv = *(const float2*)(pos + t * HDIM + ln * 2);
      o0 = o0 * m + pv.x;
      o1 = o1 * m + pv.y;
      oi = ((size_t)bn * NT + t) * HDIM + ln * 2;
    } else {
      oi = (size_t)grow * HDIM + ln * 2;
    }
    if (outF) *(float2*)(outF + oi) = make_float2(o0, o1);
    if (outB) {
      __hip_bfloat16 b0 = __float2bfloat16(o0), b1 = __float2bfloat16(o1);
      unsigned int pk = ((unsigned int)*(unsigned short*)&b1 << 16) | *(unsigned short*)&b0;
      *(unsigned int*)((char*)outB + oi * 2) = pk;
    }
  }
}

// ---------------- attention: one block per sequence bn; padded LDS + short8 loads ----------------
__global__ __launch_bounds__(256) void attn_kernel(const __hip_bfloat16* __restrict__ qkv,
                                                   const float* __restrict__ maskf,
                                                   __hip_bfloat16* __restrict__ o) {
  int bn = blockIdx.x;
  __shared__ float q[NT][QP], kk[NT][QP], vv[NT][QP];
  __shared__ float sc[8][NT][NT];
  __shared__ float mb[NT];
  int tid = threadIdx.x;
  if (tid < NT) mb[tid] = (maskf[tid * BNODES + bn] == 0.0f) ? -1e30f : 0.0f;
  for (int idx = tid; idx < NT * 48; idx += 256) {   // 960 short8 loads
    int t = idx / 48, c8 = idx % 48;
    short8 v8 = *(const short8*)((const short*)qkv + ((size_t)bn * NT + t) * 384 + c8 * 8);
    float* dst = (c8 < 16) ? &q[t][c8 * 8] : (c8 < 32) ? &kk[t][(c8 - 16) * 8] : &vv[t][(c8 - 32) * 8];
    #pragma unroll
    for (int i = 0; i < 8; ++i) dst[i] = bf2f(v8[i]);
  }
  __syncthreads();
  for (int idx = tid; idx < 8 * NT * NT; idx += 256) {
    int h = idx / (NT * NT), rr = idx % (NT * NT);
    int tq = rr / NT, tk = rr % NT;
    float s = 0.0f;
    #pragma unroll
    for (int d = 0; d < 16; ++d) s += q[tq][h * 16 + d] * kk[tk][h * 16 + d];
    sc[h][tq][tk] = s * 0.25f + mb[tk];
  }
  __syncthreads();
  if (tid < 8 * NT) {
    int h = tid / NT, tq = tid % NT;
    float mx = -1e30f;
    for (int tk = 0; tk < NT; ++tk) mx = fmaxf(mx, sc[h][tq][tk]);
    float sum = 0.0f;
    for (int tk = 0; tk < NT; ++tk) { float e = __expf(sc[h][tq][tk] - mx); sc[h][tq][tk] = e; sum += e; }
    float inv = 1.0f / sum;
    for (int tk = 0; tk < NT; ++tk) sc[h][tq][tk] *= inv;
  }
  __syncthreads();
  for (int idx = tid; idx < NT * HDIM; idx += 256) {
    int tq = idx / HDIM, col = idx % HDIM;
    int h = col >> 4;
    float s = 0.0f;
    #pragma unroll
    for (int tk = 0; tk < NT; ++tk) s += sc[h][tq][tk] * vv[tk][col];
    o[((size_t)bn * NT + tq) * HDIM + col] = __float2bfloat16(s);
  }
}

extern "C" void kernel_launch(void* const* d_in, const int* in_sizes, int n_in,
                              void* d_out, int out_size, void* d_ws, size_t ws_size,
                              hipStream_t stream) {
  const void*  ego   = d_in[0];
  const float* xraw  = (const float*)d_in[1];
  const float* adj   = (const float*)d_in[2];
  const float* gcn1w = (const float*)d_in[3];
  const float* gcnws = (const float*)d_in[4];
  const float* gcnbs = (const float*)d_in[5];
  const float* lng   = (const float*)d_in[6];
  const float* lnb   = (const float*)d_in[7];
  const float* pos   = (const float*)d_in[8];
  const float* twqkv = (const float*)d_in[9];
  const float* tbqkv = (const float*)d_in[10];
  const float* two   = (const float*)d_in[11];
  const float* tbo   = (const float*)d_in[12];
  const float* tln1g = (const float*)d_in[13];
  const float* tln1b = (const float*)d_in[14];
  const float* tw1   = (const float*)d_in[15];
  const float* tb1   = (const float*)d_in[16];
  const float* tw2   = (const float*)d_in[17];
  const float* tb2   = (const float*)d_in[18];
  const float* tln2g = (const float*)d_in[19];
  const float* tln2b = (const float*)d_in[20];

  char* base = (char*)d_ws;
  size_t off = 0;
  auto alloc = [&](size_t bytes) -> void* {
    void* p = base + off;
    off = (off + bytes + 255) & ~(size_t)255;
    return p;
  };
  float* maskf  = (float*)alloc((size_t)NROWS * 4);
  float* dinv   = (float*)alloc((size_t)NROWS * 4);
  int*   colcnt = (int*)  alloc((size_t)NROWS * 4);
  // region shared: colidx (GCN phase) / qkv_bf (transformer phase)
  void*  regA   = alloc((size_t)NROWS * 384 * 2);
  int*   colidx = (int*)regA;
  __hip_bfloat16* qkv_bf = (__hip_bfloat16*)regA;
  // region shared: g_bf (GCN spmm out) / big_bf (ff hidden)
  void*  regB   = alloc((size_t)NROWS * 512 * 2);
  __hip_bfloat16* g_bf   = (__hip_bfloat16*)regB;
  __hip_bfloat16* big_bf = (__hip_bfloat16*)regB;
  __hip_bfloat16* attn_bf = (__hip_bfloat16*)alloc((size_t)NROWS * HDIM * 2);
  __hip_bfloat16* hbufA   = (__hip_bfloat16*)alloc((size_t)NROWS * HDIM * 2);  // bf16 h mirror
  __hip_bfloat16* xbf     = (__hip_bfloat16*)alloc((size_t)NROWS * HDIM * 2);
  float* hbufF  = (float*)alloc((size_t)NROWS * HDIM * 4);   // fp32 GCN residual carry
  float* xbuf   = (float*)alloc((size_t)NROWS * HDIM * 4);   // fp32 transformer residual carry
  __hip_bfloat16* wqkv_bf = (__hip_bfloat16*)alloc((size_t)245760 * 2);
  __hip_bfloat16* wo_bf   = (__hip_bfloat16*)alloc((size_t)81920 * 2);
  __hip_bfloat16* w1_bf   = (__hip_bfloat16*)alloc((size_t)327680 * 2);
  __hip_bfloat16* w2_bf   = (__hip_bfloat16*)alloc((size_t)327680 * 2);
  __hip_bfloat16* wsT_bf  = (__hip_bfloat16*)alloc((size_t)81920 * 2);

  // ---- setup ----
  setup_kernel<<<4320, 256, 0, stream>>>(ego, maskf, colcnt, twqkv, two, tw1, tw2, gcnws,
                                         wqkv_bf, wo_bf, w1_bf, w2_bf, wsT_bf);
  build_edges_kernel<<<81920, 256, 0, stream>>>(adj, maskf, colcnt, colidx);
  finalize_deg_kernel<<<160, 256, 0, stream>>>(maskf, colcnt, dinv);

  // ---- GCN (round-5 pipeline: separate spmm, fp32 carry) ----
  spmm_ln0_kernel<<<NROWS, HDIM, 0, stream>>>(xraw, gcn1w, dinv, colcnt, colidx,
                                              gcnbs, lng, lnb, hbufF, hbufA);
  for (int i = 0; i < 5; ++i) {
    spmm_kernel<<<NROWS, HDIM, 0, stream>>>(hbufA, dinv, colcnt, colidx, g_bf);
    const float* fm = (i == 4) ? maskf : nullptr;
    const float* fp = (i == 4) ? pos : nullptr;
    float* oF = (i == 4) ? xbuf : hbufF;
    __hip_bfloat16* oB = (i == 4) ? xbf : hbufA;
    gemm_ln<<<NROWS / 64, 256, 0, stream>>>(
        g_bf, wsT_bf + (size_t)i * 16384, gcnbs + (i + 1) * 128, 128, 1,
        hbufF, lng + (i + 1) * 128, lnb + (i + 1) * 128, fm, fp, oF, oB);
  }

  // ---- transformer (fp32 carry in xbuf, bf16 operand mirror in xbf) ----
  for (int l = 0; l < 5; ++l) {
    gemm_plain<<<dim3(3, NROWS / 128), 256, 0, stream>>>(
        xbf, wqkv_bf + (size_t)l * 49152, tbqkv + l * 384, 128, 384, 0, qkv_bf);
    attn_kernel<<<BNODES, 256, 0, stream>>>(qkv_bf, maskf, attn_bf);
    gemm_ln<<<NROWS / 64, 256, 0, stream>>>(
        attn_bf, wo_bf + (size_t)l * 16384, tbo + l * 128, 128, 0,
        xbuf, tln1g + l * 128, tln1b + l * 128, nullptr, nullptr, xbuf, xbf);
    gemm_plain<<<dim3(4, NROWS / 128), 256, 0, stream>>>(
        xbf, w1_bf + (size_t)l * 65536, tb1 + l * 512, 128, 512, 1, big_bf);
    float* oF = (l == 4) ? (float*)d_out : xbuf;
    __hip_bfloat16* oB = (l == 4) ? nullptr : xbf;
    gemm_ln<<<NROWS / 64, 256, 0, stream>>>(
        big_bf, w2_bf + (size_t)l * 65536, tb2 + l * 128, 512, 0,
        xbuf, tln2g + l * 128, tln2b + l * 128, nullptr, nullptr, oF, oB);
  }
}

// Round 9
// 1495.282 us; speedup vs baseline: 5.3288x; 1.0230x over previous
//
#include <hip/hip_runtime.h>
#include <hip/hip_bf16.h>
#include <cstdint>
#include <cstddef>

#define BNODES 2048
#define NT 20
#define HDIM 128
#define NROWS (NT * BNODES)      // 40960
#define CAP 64
#define QP 129                   // padded LDS row stride (floats) for attn

typedef __attribute__((ext_vector_type(8))) short short8;
typedef __attribute__((ext_vector_type(4))) float floatx4;

__device__ __forceinline__ float bf2f(short u) {
  return __uint_as_float(((unsigned int)(unsigned short)u) << 16);
}
__device__ __forceinline__ unsigned int pack2(float a, float b) {
  __hip_bfloat16 b0 = __float2bfloat16(a), b1 = __float2bfloat16(b);
  return ((unsigned int)*(unsigned short*)&b1 << 16) | *(unsigned short*)&b0;
}

// ---------------- combined setup: mask expand + colcnt zero + all weight converts ----------------
__global__ void setup_kernel(const void* __restrict__ ego, float* __restrict__ maskf,
                             int* __restrict__ colcnt,
                             const float* __restrict__ twqkv, const float* __restrict__ two,
                             const float* __restrict__ tw1, const float* __restrict__ tw2,
                             const float* __restrict__ gcnws,
                             __hip_bfloat16* __restrict__ wqkv, __hip_bfloat16* __restrict__ wo,
                             __hip_bfloat16* __restrict__ w1, __hip_bfloat16* __restrict__ w2,
                             __hip_bfloat16* __restrict__ wsT) {
  int gid = blockIdx.x * blockDim.x + threadIdx.x;
  if (gid < NROWS) {
    unsigned int w0 = ((const unsigned int*)ego)[0];
    int val;
    if (w0 == 1u)                 val = ((const int*)ego)[gid] != 0;
    else if (w0 == 0x3F800000u)   val = ((const float*)ego)[gid] != 0.0f;
    else if (w0 == 0x3F803F80u)   val = ((const unsigned short*)ego)[gid] != 0;
    else                          val = ((const unsigned char*)ego)[gid] != 0;
    int b = gid / (NT * 256);
    int t = (gid / 256) % NT;
    int n = gid % 256;
    maskf[t * BNODES + b * 256 + n] = val ? 1.0f : 0.0f;
    colcnt[gid] = 0;
    return;
  }
  gid -= NROWS;
  if (gid < 245760) { wqkv[gid] = __float2bfloat16(twqkv[gid]); return; }
  gid -= 245760;
  if (gid < 81920) { wo[gid] = __float2bfloat16(two[gid]); return; }
  gid -= 81920;
  if (gid < 327680) { w1[gid] = __float2bfloat16(tw1[gid]); return; }
  gid -= 327680;
  if (gid < 327680) { w2[gid] = __float2bfloat16(tw2[gid]); return; }
  gid -= 327680;
  if (gid < 81920) {  // gcn_ws [5][K][N] -> Bt[l][n][k]
    int l = gid >> 14, rem = gid & 16383;
    int n = rem >> 7, k = rem & 127;
    wsT[gid] = __float2bfloat16(gcnws[(l << 14) + (k << 7) + n]);
  }
}

// ---------------- edge-list build: streaming scatter (mask early-out) ----------------
__global__ __launch_bounds__(256) void build_edges_kernel(const float* __restrict__ adj,
                                                          const float* __restrict__ maskf,
                                                          int* __restrict__ colcnt,
                                                          int* __restrict__ colidx) {
  size_t e4 = (size_t)blockIdx.x * 256 + threadIdx.x;
  size_t e = e4 * 4;
  size_t row = e >> 11;                     // t*BNODES + j (source row)
  if (maskf[row] == 0.0f) return;           // m[j]==0: skip the load entirely
  const float4 a = ((const float4*)adj)[e4];
  if (a.x == 0.0f && a.y == 0.0f && a.z == 0.0f && a.w == 0.0f) return;
  int i0 = (int)(e & (BNODES - 1));
  int t = (int)(row >> 11);
  int j = (int)(row & (BNODES - 1));
  int base = t * BNODES;
  if (a.x != 0.0f) { int p = atomicAdd(&colcnt[base + i0 + 0], 1); if (p < CAP) colidx[(size_t)(base + i0 + 0) * CAP + p] = j; }
  if (a.y != 0.0f) { int p = atomicAdd(&colcnt[base + i0 + 1], 1); if (p < CAP) colidx[(size_t)(base + i0 + 1) * CAP + p] = j; }
  if (a.z != 0.0f) { int p = atomicAdd(&colcnt[base + i0 + 2], 1); if (p < CAP) colidx[(size_t)(base + i0 + 2) * CAP + p] = j; }
  if (a.w != 0.0f) { int p = atomicAdd(&colcnt[base + i0 + 3], 1); if (p < CAP) colidx[(size_t)(base + i0 + 3) * CAP + p] = j; }
}

__global__ void finalize_deg_kernel(const float* __restrict__ maskf, int* __restrict__ colcnt,
                                    float* __restrict__ dinv) {
  int gid = blockIdx.x * blockDim.x + threadIdx.x;
  if (gid >= NROWS) return;
  int cnt = colcnt[gid];
  dinv[gid] = (maskf[gid] != 0.0f) ? rsqrtf((float)cnt + 1.0f) : 0.0f;
  colcnt[gid] = cnt < CAP ? cnt : CAP;
}

// ---------------- GCN layer 0: SpMM(xraw@gcn1_w on the fly) + bias + LN + ReLU ----------------
// 4 rows/block, 64 lanes/row, 2 cols/lane. LN via single-wave shuffle.
__global__ __launch_bounds__(256) void spmm_ln0_kernel(const float* __restrict__ xraw,
                                                       const float* __restrict__ gw,
                                                       const float* __restrict__ dinv,
                                                       const int* __restrict__ colcnt,
                                                       const int* __restrict__ colidx,
                                                       const float* __restrict__ bias,
                                                       const float* __restrict__ gamma,
                                                       const float* __restrict__ beta,
                                                       float* __restrict__ dstF,
                                                       __hip_bfloat16* __restrict__ dstB) {
  int tid = threadIdx.x;
  int r = (blockIdx.x << 2) + (tid >> 6);
  int lane = tid & 63;
  int c0 = lane << 1;
  int t = r >> 11;
  float di = dinv[r];
  float g00 = gw[c0], g01 = gw[c0 + 1], g10 = gw[HDIM + c0], g11 = gw[HDIM + c0 + 1];
  float a0 = 0.0f, a1 = 0.0f;
  if (di != 0.0f) {
    float x0 = xraw[2 * r], x1 = xraw[2 * r + 1];
    a0 = di * fmaf(x0, g00, x1 * g10);
    a1 = di * fmaf(x0, g01, x1 * g11);
    int cnt = colcnt[r];
    const int* cols = colidx + (size_t)r * CAP;
    const float* dt = dinv + (t << 11);
    for (int k = 0; k < cnt; ++k) {
      int j = cols[k];
      size_t gr = ((size_t)t << 11) + j;
      float y0 = xraw[2 * gr], y1 = xraw[2 * gr + 1];
      float dj = dt[j];
      a0 = fmaf(dj, fmaf(y0, g00, y1 * g10), a0);
      a1 = fmaf(dj, fmaf(y0, g01, y1 * g11), a1);
    }
    a0 *= di; a1 *= di;
  }
  a0 += bias[c0]; a1 += bias[c0 + 1];
  float s = a0 + a1, q = a0 * a0 + a1 * a1;
  #pragma unroll
  for (int off = 32; off > 0; off >>= 1) {
    s += __shfl_xor(s, off, 64);
    q += __shfl_xor(q, off, 64);
  }
  float mu = s * (1.0f / HDIM);
  float var = fmaxf(q * (1.0f / HDIM) - mu * mu, 0.0f);
  float rs = rsqrtf(var + 1e-5f);
  float o0 = fmaxf((a0 - mu) * rs * gamma[c0] + beta[c0], 0.0f);
  float o1 = fmaxf((a1 - mu) * rs * gamma[c0 + 1] + beta[c0 + 1], 0.0f);
  size_t oi = (size_t)r * HDIM + c0;
  *(float2*)(dstF + oi) = make_float2(o0, o1);
  *(unsigned int*)((char*)dstB + oi * 2) = pack2(o0, o1);
}

// ---------------- pure SpMM gather: out_bf = S @ Y (bf16 -> bf16), 4 rows/block ----------------
__global__ __launch_bounds__(256) void spmm_kernel(const __hip_bfloat16* __restrict__ Y,
                                                   const float* __restrict__ dinv,
                                                   const int* __restrict__ colcnt,
                                                   const int* __restrict__ colidx,
                                                   __hip_bfloat16* __restrict__ out) {
  int tid = threadIdx.x;
  int r = (blockIdx.x << 2) + (tid >> 6);
  int lane = tid & 63;
  int t = r >> 11;
  float di = dinv[r];
  const unsigned int* Yrow = (const unsigned int*)((const short*)Y + (size_t)r * HDIM) + lane;
  unsigned int* orow = (unsigned int*)((short*)out + (size_t)r * HDIM) + lane;
  if (di == 0.0f) { *orow = 0u; return; }
  unsigned int sv = *Yrow;
  float a0 = di * bf2f((short)(sv & 0xffff));
  float a1 = di * bf2f((short)(sv >> 16));
  int cnt = colcnt[r];
  const int* cols = colidx + (size_t)r * CAP;
  const float* dt = dinv + (t << 11);
  const unsigned int* Yt = (const unsigned int*)((const short*)Y + (((size_t)t << 11) * HDIM)) + lane;
  for (int k = 0; k < cnt; ++k) {
    int j = cols[k];
    float dj = dt[j];
    unsigned int v = Yt[(size_t)j << 6];
    a0 = fmaf(dj, bf2f((short)(v & 0xffff)), a0);
    a1 = fmaf(dj, bf2f((short)(v >> 16)), a1);
  }
  a0 *= di; a1 *= di;
  *orow = pack2(a0, a1);
}

// ---------------- async 16B global->LDS ----------------
__device__ __forceinline__ void async16(const void* g, void* l) {
  __builtin_amdgcn_global_load_lds(
      (const __attribute__((address_space(1))) unsigned int*)g,
      (__attribute__((address_space(3))) unsigned int*)l, 16, 0, 0);
}

// ---------------- plain MFMA GEMM: C[M,N] = A[M,K] @ Bt[N,K]^T (+bias)(+relu), bf16 out ----------------
__global__ __launch_bounds__(256) void gemm_plain(const __hip_bfloat16* __restrict__ A,
                                                  const __hip_bfloat16* __restrict__ Bt,
                                                  const float* __restrict__ bias,
                                                  int K, int N, int relu,
                                                  __hip_bfloat16* __restrict__ Cb) {
  __shared__ __align__(16) char smem[65536];
  __hip_bfloat16* As = (__hip_bfloat16*)smem;
  __hip_bfloat16* Bs = As + 128 * 128;
  const int tid = threadIdx.x;
  const int wv = tid >> 6, ln = tid & 63;
  const int n0 = blockIdx.x << 7, m0 = blockIdx.y << 7;
  const int wm = (wv & 1) << 6, wn = (wv >> 1) << 6;
  const int lr = ln & 15, lq = ln >> 4;

  floatx4 acc[4][4];
  #pragma unroll
  for (int mi = 0; mi < 4; ++mi)
    #pragma unroll
    for (int ni = 0; ni < 4; ++ni) acc[mi][ni] = (floatx4)0.0f;

  for (int k0 = 0; k0 < K; k0 += 128) {
    if (k0) __syncthreads();
    #pragma unroll
    for (int i = 0; i < 8; ++i) {
      int rloc = i * 16 + wv * 4 + lq;
      int sc = (ln & 15) ^ (rloc & 15);
      async16((const char*)A + ((size_t)(m0 + rloc) * K + k0) * 2 + (size_t)sc * 16,
              (char*)As + (size_t)(i * 16 + wv * 4) * 256);
      async16((const char*)Bt + ((size_t)(n0 + rloc) * K + k0) * 2 + (size_t)sc * 16,
              (char*)Bs + (size_t)(i * 16 + wv * 4) * 256);
    }
    __syncthreads();
    #pragma unroll
    for (int kc = 0; kc < 4; ++kc) {
      short8 af[4], bfr[4];
      #pragma unroll
      for (int mi = 0; mi < 4; ++mi) {
        int R = wm + (mi << 4) + lr;
        int ch = ((kc << 2) + lq) ^ (R & 15);
        af[mi] = *(const short8*)(As + (R << 7) + (ch << 3));
      }
      #pragma unroll
      for (int ni = 0; ni < 4; ++ni) {
        int R = wn + (ni << 4) + lr;
        int ch = ((kc << 2) + lq) ^ (R & 15);
        bfr[ni] = *(const short8*)(Bs + (R << 7) + (ch << 3));
      }
      #pragma unroll
      for (int mi = 0; mi < 4; ++mi)
        #pragma unroll
        for (int ni = 0; ni < 4; ++ni)
          acc[mi][ni] = __builtin_amdgcn_mfma_f32_16x16x32_bf16(af[mi], bfr[ni], acc[mi][ni], 0, 0, 0);
    }
  }
  #pragma unroll
  for (int ni = 0; ni < 4; ++ni) {
    int cn = n0 + wn + (ni << 4) + lr;
    float bv = bias ? bias[cn] : 0.0f;
    #pragma unroll
    for (int mi = 0; mi < 4; ++mi) {
      #pragma unroll
      for (int r = 0; r < 4; ++r) {
        int rm = m0 + wm + (mi << 4) + (lq << 2) + r;
        float v = acc[mi][ni][r] + bv;
        if (relu) v = fmaxf(v, 0.0f);
        Cb[(size_t)rm * N + cn] = __float2bfloat16(v);
      }
    }
  }
}

// ---------------- fused-LN MFMA GEMM (N==128), 64x128 tile ----------------
// gcn_mode=1: out = relu(LN(A@Bt^T + bias) + residF)   [+ optional mask/pos permute]
// gcn_mode=0: out = LN(A@Bt^T + bias + residF)
// residF fp32 carry; in-place outF==residF is safe (rows block-owned).
__global__ __launch_bounds__(256) void gemm_ln(const __hip_bfloat16* __restrict__ A,
                                               const __hip_bfloat16* __restrict__ Bt,
                                               const float* __restrict__ bias,
                                               int K, int gcn_mode,
                                               const float* __restrict__ residF,
                                               const float* __restrict__ lng,
                                               const float* __restrict__ lnb,
                                               const float* __restrict__ maskf,
                                               const float* __restrict__ pos,
                                               float* __restrict__ outF,
                                               __hip_bfloat16* __restrict__ outB) {
  __shared__ __align__(16) char smem[49152];
  __hip_bfloat16* As = (__hip_bfloat16*)smem;   // 64x128 bf16 (16KB)
  __hip_bfloat16* Bs = As + 64 * 128;           // 128x128 bf16 (32KB)
  float* Cs = (float*)smem;                     // 64x128 fp32 (32KB, aliased post-compute)
  const int tid = threadIdx.x;
  const int wv = tid >> 6, ln = tid & 63;
  const int m0 = blockIdx.x << 6;
  const int wm = (wv & 1) << 5, wn = (wv >> 1) << 6;
  const int lr = ln & 15, lq = ln >> 4;

  floatx4 acc[2][4];
  #pragma unroll
  for (int mi = 0; mi < 2; ++mi)
    #pragma unroll
    for (int ni = 0; ni < 4; ++ni) acc[mi][ni] = (floatx4)0.0f;

  for (int k0 = 0; k0 < K; k0 += 128) {
    if (k0) __syncthreads();
    #pragma unroll
    for (int i = 0; i < 4; ++i) {   // A: 64 rows
      int rloc = i * 16 + wv * 4 + lq;
      int sc = (ln & 15) ^ (rloc & 15);
      async16((const char*)A + ((size_t)(m0 + rloc) * K + k0) * 2 + (size_t)sc * 16,
              (char*)As + (size_t)(i * 16 + wv * 4) * 256);
    }
    #pragma unroll
    for (int i = 0; i < 8; ++i) {   // B: 128 rows
      int rloc = i * 16 + wv * 4 + lq;
      int sc = (ln & 15) ^ (rloc & 15);
      async16((const char*)Bt + ((size_t)rloc * K + k0) * 2 + (size_t)sc * 16,
              (char*)Bs + (size_t)(i * 16 + wv * 4) * 256);
    }
    __syncthreads();
    #pragma unroll
    for (int kc = 0; kc < 4; ++kc) {
      short8 af[2], bfr[4];
      #pragma unroll
      for (int mi = 0; mi < 2; ++mi) {
        int R = wm + (mi << 4) + lr;
        int ch = ((kc << 2) + lq) ^ (R & 15);
        af[mi] = *(const short8*)(As + (R << 7) + (ch << 3));
      }
      #pragma unroll
      for (int ni = 0; ni < 4; ++ni) {
        int R = wn + (ni << 4) + lr;
        int ch = ((kc << 2) + lq) ^ (R & 15);
        bfr[ni] = *(const short8*)(Bs + (R << 7) + (ch << 3));
      }
      #pragma unroll
      for (int mi = 0; mi < 2; ++mi)
        #pragma unroll
        for (int ni = 0; ni < 4; ++ni)
          acc[mi][ni] = __builtin_amdgcn_mfma_f32_16x16x32_bf16(af[mi], bfr[ni], acc[mi][ni], 0, 0, 0);
    }
  }

  // stage C (+bias, +pre-LN fp32 resid for transformer) into LDS fp32
  __syncthreads();
  #pragma unroll
  for (int ni = 0; ni < 4; ++ni) {
    int cn = wn + (ni << 4) + lr;
    float bv = bias[cn];
    #pragma unroll
    for (int mi = 0; mi < 2; ++mi) {
      #pragma unroll
      for (int r = 0; r < 4; ++r) {
        int rl = wm + (mi << 4) + (lq << 2) + r;
        float v = acc[mi][ni][r] + bv;
        if (!gcn_mode) v += residF[(size_t)(m0 + rl) * HDIM + cn];
        Cs[(rl << 7) + cn] = v;
      }
    }
  }
  __syncthreads();
  float2 gam = *(const float2*)(lng + ln * 2);
  float2 bet = *(const float2*)(lnb + ln * 2);
  #pragma unroll 4
  for (int p = 0; p < 16; ++p) {
    int rl = p * 4 + wv;
    int grow = m0 + rl;
    float2 xv = *(const float2*)(Cs + (rl << 7) + ln * 2);
    float s = xv.x + xv.y, q = xv.x * xv.x + xv.y * xv.y;
    #pragma unroll
    for (int off = 32; off > 0; off >>= 1) {
      s += __shfl_xor(s, off, 64);
      q += __shfl_xor(q, off, 64);
    }
    float mu = s * (1.0f / HDIM);
    float var = fmaxf(q * (1.0f / HDIM) - mu * mu, 0.0f);
    float rs = rsqrtf(var + 1e-5f);
    float o0 = (xv.x - mu) * rs * gam.x + bet.x;
    float o1 = (xv.y - mu) * rs * gam.y + bet.y;
    if (gcn_mode) {   // post-LN fp32 residual + relu
      float2 rv = *(const float2*)(residF + (size_t)grow * HDIM + ln * 2);
      o0 = fmaxf(o0 + rv.x, 0.0f);
      o1 = fmaxf(o1 + rv.y, 0.0f);
    }
    size_t oi;
    if (pos) {  // final GCN layer: x = h*m + pos, permuted [bn,t]
      int t = grow >> 11, bn = grow & (BNODES - 1);
      float m = maskf[grow];
      float2 pv = *(const float2*)(pos + t * HDIM + ln * 2);
      o0 = o0 * m + pv.x;
      o1 = o1 * m + pv.y;
      oi = ((size_t)bn * NT + t) * HDIM + ln * 2;
    } else {
      oi = (size_t)grow * HDIM + ln * 2;
    }
    if (outF) *(float2*)(outF + oi) = make_float2(o0, o1);
    if (outB) *(unsigned int*)((char*)outB + oi * 2) = pack2(o0, o1);
  }
}

// ---------------- attention: one block per sequence; register softmax (no score LDS) ----------------
__global__ __launch_bounds__(256) void attn_kernel(const __hip_bfloat16* __restrict__ qkv,
                                                   const float* __restrict__ maskf,
                                                   __hip_bfloat16* __restrict__ o) {
  int bn = blockIdx.x;
  __shared__ float q[NT][QP], kk[NT][QP], vv[NT][QP];
  __shared__ float mb[NT];
  int tid = threadIdx.x;
  if (tid < NT) mb[tid] = (maskf[tid * BNODES + bn] == 0.0f) ? -1e30f : 0.0f;
  for (int idx = tid; idx < NT * 48; idx += 256) {   // 960 short8 loads
    int t = idx / 48, c8 = idx % 48;
    short8 v8 = *(const short8*)((const short*)qkv + ((size_t)bn * NT + t) * 384 + c8 * 8);
    float* dst = (c8 < 16) ? &q[t][c8 * 8] : (c8 < 32) ? &kk[t][(c8 - 16) * 8] : &vv[t][(c8 - 32) * 8];
    #pragma unroll
    for (int i = 0; i < 8; ++i) dst[i] = bf2f(v8[i]);
  }
  __syncthreads();
  if (tid >= 8 * NT) return;          // 160 active: one (head, tq) each
  int h = tid / NT, tq = tid % NT;
  float qr[16];
  #pragma unroll
  for (int d = 0; d < 16; ++d) qr[d] = q[tq][h * 16 + d];
  float p[NT];
  float mx = -1e30f;
  #pragma unroll
  for (int tk = 0; tk < NT; ++tk) {
    float s = 0.0f;
    #pragma unroll
    for (int d = 0; d < 16; ++d) s = fmaf(qr[d], kk[tk][h * 16 + d], s);
    s = s * 0.25f + mb[tk];
    p[tk] = s;
    mx = fmaxf(mx, s);
  }
  float sum = 0.0f;
  #pragma unroll
  for (int tk = 0; tk < NT; ++tk) { float e = __expf(p[tk] - mx); p[tk] = e; sum += e; }
  float inv = 1.0f / sum;
  float oacc[16];
  #pragma unroll
  for (int d = 0; d < 16; ++d) oacc[d] = 0.0f;
  #pragma unroll
  for (int tk = 0; tk < NT; ++tk) {
    float pv = p[tk] * inv;
    #pragma unroll
    for (int d = 0; d < 16; ++d) oacc[d] = fmaf(pv, vv[tk][h * 16 + d], oacc[d]);
  }
  short* op = (short*)o + ((size_t)bn * NT + tq) * HDIM + h * 16;
  short8 o8a, o8b;
  #pragma unroll
  for (int d = 0; d < 8; ++d) {
    __hip_bfloat16 b = __float2bfloat16(oacc[d]);
    o8a[d] = *(short*)&b;
  }
  #pragma unroll
  for (int d = 0; d < 8; ++d) {
    __hip_bfloat16 b = __float2bfloat16(oacc[8 + d]);
    o8b[d] = *(short*)&b;
  }
  *(short8*)op = o8a;
  *(short8*)(op + 8) = o8b;
}

extern "C" void kernel_launch(void* const* d_in, const int* in_sizes, int n_in,
                              void* d_out, int out_size, void* d_ws, size_t ws_size,
                              hipStream_t stream) {
  const void*  ego   = d_in[0];
  const float* xraw  = (const float*)d_in[1];
  const float* adj   = (const float*)d_in[2];
  const float* gcn1w = (const float*)d_in[3];
  const float* gcnws = (const float*)d_in[4];
  const float* gcnbs = (const float*)d_in[5];
  const float* lng   = (const float*)d_in[6];
  const float* lnb   = (const float*)d_in[7];
  const float* pos   = (const float*)d_in[8];
  const float* twqkv = (const float*)d_in[9];
  const float* tbqkv = (const float*)d_in[10];
  const float* two   = (const float*)d_in[11];
  const float* tbo   = (const float*)d_in[12];
  const float* tln1g = (const float*)d_in[13];
  const float* tln1b = (const float*)d_in[14];
  const float* tw1   = (const float*)d_in[15];
  const float* tb1   = (const float*)d_in[16];
  const float* tw2   = (const float*)d_in[17];
  const float* tb2   = (const float*)d_in[18];
  const float* tln2g = (const float*)d_in[19];
  const float* tln2b = (const float*)d_in[20];

  char* base = (char*)d_ws;
  size_t off = 0;
  auto alloc = [&](size_t bytes) -> void* {
    void* p = base + off;
    off = (off + bytes + 255) & ~(size_t)255;
    return p;
  };
  float* maskf  = (float*)alloc((size_t)NROWS * 4);
  float* dinv   = (float*)alloc((size_t)NROWS * 4);
  int*   colcnt = (int*)  alloc((size_t)NROWS * 4);
  // region shared: colidx (GCN phase) / qkv_bf (transformer phase)
  void*  regA   = alloc((size_t)NROWS * 384 * 2);
  int*   colidx = (int*)regA;
  __hip_bfloat16* qkv_bf = (__hip_bfloat16*)regA;
  // region shared: g_bf (GCN spmm out) / big_bf (ff hidden)
  void*  regB   = alloc((size_t)NROWS * 512 * 2);
  __hip_bfloat16* g_bf   = (__hip_bfloat16*)regB;
  __hip_bfloat16* big_bf = (__hip_bfloat16*)regB;
  __hip_bfloat16* attn_bf = (__hip_bfloat16*)alloc((size_t)NROWS * HDIM * 2);
  __hip_bfloat16* hbufA   = (__hip_bfloat16*)alloc((size_t)NROWS * HDIM * 2);  // bf16 h mirror
  __hip_bfloat16* xbf     = (__hip_bfloat16*)alloc((size_t)NROWS * HDIM * 2);
  float* hbufF  = (float*)alloc((size_t)NROWS * HDIM * 4);   // fp32 GCN residual carry
  float* xbuf   = (float*)alloc((size_t)NROWS * HDIM * 4);   // fp32 transformer residual carry
  __hip_bfloat16* wqkv_bf = (__hip_bfloat16*)alloc((size_t)245760 * 2);
  __hip_bfloat16* wo_bf   = (__hip_bfloat16*)alloc((size_t)81920 * 2);
  __hip_bfloat16* w1_bf   = (__hip_bfloat16*)alloc((size_t)327680 * 2);
  __hip_bfloat16* w2_bf   = (__hip_bfloat16*)alloc((size_t)327680 * 2);
  __hip_bfloat16* wsT_bf  = (__hip_bfloat16*)alloc((size_t)81920 * 2);

  // ---- setup ----
  setup_kernel<<<4320, 256, 0, stream>>>(ego, maskf, colcnt, twqkv, two, tw1, tw2, gcnws,
                                         wqkv_bf, wo_bf, w1_bf, w2_bf, wsT_bf);
  build_edges_kernel<<<81920, 256, 0, stream>>>(adj, maskf, colcnt, colidx);
  finalize_deg_kernel<<<160, 256, 0, stream>>>(maskf, colcnt, dinv);

  // ---- GCN (separate spmm, fp32 carry) ----
  spmm_ln0_kernel<<<NROWS / 4, 256, 0, stream>>>(xraw, gcn1w, dinv, colcnt, colidx,
                                                 gcnbs, lng, lnb, hbufF, hbufA);
  for (int i = 0; i < 5; ++i) {
    spmm_kernel<<<NROWS / 4, 256, 0, stream>>>(hbufA, dinv, colcnt, colidx, g_bf);
    const float* fm = (i == 4) ? maskf : nullptr;
    const float* fp = (i == 4) ? pos : nullptr;
    float* oF = (i == 4) ? xbuf : hbufF;
    __hip_bfloat16* oB = (i == 4) ? xbf : hbufA;
    gemm_ln<<<NROWS / 64, 256, 0, stream>>>(
        g_bf, wsT_bf + (size_t)i * 16384, gcnbs + (i + 1) * 128, 128, 1,
        hbufF, lng + (i + 1) * 128, lnb + (i + 1) * 128, fm, fp, oF, oB);
  }

  // ---- transformer (fp32 carry in xbuf, bf16 operand mirror in xbf) ----
  for (int l = 0; l < 5; ++l) {
    gemm_plain<<<dim3(3, NROWS / 128), 256, 0, stream>>>(
        xbf, wqkv_bf + (size_t)l * 49152, tbqkv + l * 384, 128, 384, 0, qkv_bf);
    attn_kernel<<<BNODES, 256, 0, stream>>>(qkv_bf, maskf, attn_bf);
    gemm_ln<<<NROWS / 64, 256, 0, stream>>>(
        attn_bf, wo_bf + (size_t)l * 16384, tbo + l * 128, 128, 0,
        xbuf, tln1g + l * 128, tln1b + l * 128, nullptr, nullptr, xbuf, xbf);
    gemm_plain<<<dim3(4, NROWS / 128), 256, 0, stream>>>(
        xbf, w1_bf + (size_t)l * 65536, tb1 + l * 512, 128, 512, 1, big_bf);
    float* oF = (l == 4) ? (float*)d_out : xbuf;
    __hip_bfloat16* oB = (l == 4) ? nullptr : xbf;
    gemm_ln<<<NROWS / 64, 256, 0, stream>>>(
        big_bf, w2_bf + (size_t)l * 65536, tb2 + l * 128, 512, 0,
        xbuf, tln2g + l * 128, tln2b + l * 128, nullptr, nullptr, oF, oB);
  }
}

// Round 10
// 1461.043 us; speedup vs baseline: 5.4537x; 1.0234x over previous
//
#include <hip/hip_runtime.h>
#include <hip/hip_bf16.h>
#include <cstdint>
#include <cstddef>

#define BNODES 2048
#define NT 20
#define HDIM 128
#define NROWS (NT * BNODES)      // 40960
#define CAP 64
#define QP 129                   // padded LDS row stride (floats) for attn

typedef __attribute__((ext_vector_type(8))) short short8;
typedef __attribute__((ext_vector_type(4))) float floatx4;

__device__ __forceinline__ float bf2f(short u) {
  return __uint_as_float(((unsigned int)(unsigned short)u) << 16);
}
__device__ __forceinline__ unsigned int pack2(float a, float b) {
  __hip_bfloat16 b0 = __float2bfloat16(a), b1 = __float2bfloat16(b);
  return ((unsigned int)*(unsigned short*)&b1 << 16) | *(unsigned short*)&b0;
}
__device__ __forceinline__ short f2bf_s(float a) {
  __hip_bfloat16 b = __float2bfloat16(a);
  return *(short*)&b;
}

// ---------------- combined setup: mask expand + colcnt zero + all weight converts ----------------
__global__ void setup_kernel(const void* __restrict__ ego, float* __restrict__ maskf,
                             int* __restrict__ colcnt,
                             const float* __restrict__ twqkv, const float* __restrict__ two,
                             const float* __restrict__ tw1, const float* __restrict__ tw2,
                             const float* __restrict__ gcnws,
                             __hip_bfloat16* __restrict__ wqkv, __hip_bfloat16* __restrict__ wo,
                             __hip_bfloat16* __restrict__ w1, __hip_bfloat16* __restrict__ w2,
                             __hip_bfloat16* __restrict__ wsT) {
  int gid = blockIdx.x * blockDim.x + threadIdx.x;
  if (gid < NROWS) {
    unsigned int w0 = ((const unsigned int*)ego)[0];
    int val;
    if (w0 == 1u)                 val = ((const int*)ego)[gid] != 0;
    else if (w0 == 0x3F800000u)   val = ((const float*)ego)[gid] != 0.0f;
    else if (w0 == 0x3F803F80u)   val = ((const unsigned short*)ego)[gid] != 0;
    else                          val = ((const unsigned char*)ego)[gid] != 0;
    int b = gid / (NT * 256);
    int t = (gid / 256) % NT;
    int n = gid % 256;
    maskf[t * BNODES + b * 256 + n] = val ? 1.0f : 0.0f;
    colcnt[gid] = 0;
    return;
  }
  gid -= NROWS;
  if (gid < 245760) { wqkv[gid] = __float2bfloat16(twqkv[gid]); return; }
  gid -= 245760;
  if (gid < 81920) { wo[gid] = __float2bfloat16(two[gid]); return; }
  gid -= 81920;
  if (gid < 327680) { w1[gid] = __float2bfloat16(tw1[gid]); return; }
  gid -= 327680;
  if (gid < 327680) { w2[gid] = __float2bfloat16(tw2[gid]); return; }
  gid -= 327680;
  if (gid < 81920) {  // gcn_ws [5][K][N] -> Bt[l][n][k]
    int l = gid >> 14, rem = gid & 16383;
    int n = rem >> 7, k = rem & 127;
    wsT[gid] = __float2bfloat16(gcnws[(l << 14) + (k << 7) + n]);
  }
}

// ---------------- edge-list build: grid-stride streaming scatter (mask early-out) ----------------
__global__ __launch_bounds__(256) void build_edges_kernel(const float* __restrict__ adj,
                                                          const float* __restrict__ maskf,
                                                          int* __restrict__ colcnt,
                                                          int* __restrict__ colidx) {
  const size_t total = (size_t)NROWS * BNODES / 4;
  const size_t stride = (size_t)gridDim.x * 256;
  for (size_t e4 = (size_t)blockIdx.x * 256 + threadIdx.x; e4 < total; e4 += stride) {
    size_t e = e4 * 4;
    size_t row = e >> 11;                   // t*BNODES + j (source row)
    if (maskf[row] == 0.0f) continue;       // m[j]==0: skip the load entirely
    const float4 a = ((const float4*)adj)[e4];
    if (a.x == 0.0f && a.y == 0.0f && a.z == 0.0f && a.w == 0.0f) continue;
    int i0 = (int)(e & (BNODES - 1));
    int t = (int)(row >> 11);
    int j = (int)(row & (BNODES - 1));
    int base = t * BNODES;
    if (a.x != 0.0f) { int p = atomicAdd(&colcnt[base + i0 + 0], 1); if (p < CAP) colidx[(size_t)(base + i0 + 0) * CAP + p] = j; }
    if (a.y != 0.0f) { int p = atomicAdd(&colcnt[base + i0 + 1], 1); if (p < CAP) colidx[(size_t)(base + i0 + 1) * CAP + p] = j; }
    if (a.z != 0.0f) { int p = atomicAdd(&colcnt[base + i0 + 2], 1); if (p < CAP) colidx[(size_t)(base + i0 + 2) * CAP + p] = j; }
    if (a.w != 0.0f) { int p = atomicAdd(&colcnt[base + i0 + 3], 1); if (p < CAP) colidx[(size_t)(base + i0 + 3) * CAP + p] = j; }
  }
}

__global__ void finalize_deg_kernel(const float* __restrict__ maskf, int* __restrict__ colcnt,
                                    float* __restrict__ dinv) {
  int gid = blockIdx.x * blockDim.x + threadIdx.x;
  if (gid >= NROWS) return;
  int cnt = colcnt[gid];
  dinv[gid] = (maskf[gid] != 0.0f) ? rsqrtf((float)cnt + 1.0f) : 0.0f;
  colcnt[gid] = cnt < CAP ? cnt : CAP;
}

// ---------------- GCN layer 0: SpMM(xraw@gcn1_w on the fly) + bias + LN + ReLU ----------------
__global__ __launch_bounds__(256) void spmm_ln0_kernel(const float* __restrict__ xraw,
                                                       const float* __restrict__ gw,
                                                       const float* __restrict__ dinv,
                                                       const int* __restrict__ colcnt,
                                                       const int* __restrict__ colidx,
                                                       const float* __restrict__ bias,
                                                       const float* __restrict__ gamma,
                                                       const float* __restrict__ beta,
                                                       float* __restrict__ dstF,
                                                       __hip_bfloat16* __restrict__ dstB) {
  int tid = threadIdx.x;
  int r = (blockIdx.x << 2) + (tid >> 6);
  int lane = tid & 63;
  int c0 = lane << 1;
  int t = r >> 11;
  float di = dinv[r];
  float g00 = gw[c0], g01 = gw[c0 + 1], g10 = gw[HDIM + c0], g11 = gw[HDIM + c0 + 1];
  float a0 = 0.0f, a1 = 0.0f;
  if (di != 0.0f) {
    float x0 = xraw[2 * r], x1 = xraw[2 * r + 1];
    a0 = di * fmaf(x0, g00, x1 * g10);
    a1 = di * fmaf(x0, g01, x1 * g11);
    int cnt = colcnt[r];
    const int* cols = colidx + (size_t)r * CAP;
    const float* dt = dinv + (t << 11);
    for (int k = 0; k < cnt; ++k) {
      int j = cols[k];
      size_t gr = ((size_t)t << 11) + j;
      float y0 = xraw[2 * gr], y1 = xraw[2 * gr + 1];
      float dj = dt[j];
      a0 = fmaf(dj, fmaf(y0, g00, y1 * g10), a0);
      a1 = fmaf(dj, fmaf(y0, g01, y1 * g11), a1);
    }
    a0 *= di; a1 *= di;
  }
  a0 += bias[c0]; a1 += bias[c0 + 1];
  float s = a0 + a1, q = a0 * a0 + a1 * a1;
  #pragma unroll
  for (int off = 32; off > 0; off >>= 1) {
    s += __shfl_xor(s, off, 64);
    q += __shfl_xor(q, off, 64);
  }
  float mu = s * (1.0f / HDIM);
  float var = fmaxf(q * (1.0f / HDIM) - mu * mu, 0.0f);
  float rs = rsqrtf(var + 1e-5f);
  float o0 = fmaxf((a0 - mu) * rs * gamma[c0] + beta[c0], 0.0f);
  float o1 = fmaxf((a1 - mu) * rs * gamma[c0 + 1] + beta[c0 + 1], 0.0f);
  size_t oi = (size_t)r * HDIM + c0;
  *(float2*)(dstF + oi) = make_float2(o0, o1);
  *(unsigned int*)((char*)dstB + oi * 2) = pack2(o0, o1);
}

// ---------------- pure SpMM gather: out_bf = S @ Y (bf16 -> bf16), 4 rows/block ----------------
__global__ __launch_bounds__(256) void spmm_kernel(const __hip_bfloat16* __restrict__ Y,
                                                   const float* __restrict__ dinv,
                                                   const int* __restrict__ colcnt,
                                                   const int* __restrict__ colidx,
                                                   __hip_bfloat16* __restrict__ out) {
  int tid = threadIdx.x;
  int r = (blockIdx.x << 2) + (tid >> 6);
  int lane = tid & 63;
  int t = r >> 11;
  float di = dinv[r];
  const unsigned int* Yrow = (const unsigned int*)((const short*)Y + (size_t)r * HDIM) + lane;
  unsigned int* orow = (unsigned int*)((short*)out + (size_t)r * HDIM) + lane;
  if (di == 0.0f) { *orow = 0u; return; }
  unsigned int sv = *Yrow;
  float a0 = di * bf2f((short)(sv & 0xffff));
  float a1 = di * bf2f((short)(sv >> 16));
  int cnt = colcnt[r];
  const int* cols = colidx + (size_t)r * CAP;
  const float* dt = dinv + (t << 11);
  const unsigned int* Yt = (const unsigned int*)((const short*)Y + (((size_t)t << 11) * HDIM)) + lane;
  for (int k = 0; k < cnt; ++k) {
    int j = cols[k];
    float dj = dt[j];
    unsigned int v = Yt[(size_t)j << 6];
    a0 = fmaf(dj, bf2f((short)(v & 0xffff)), a0);
    a1 = fmaf(dj, bf2f((short)(v >> 16)), a1);
  }
  a0 *= di; a1 *= di;
  *orow = pack2(a0, a1);
}

// ---------------- async 16B global->LDS ----------------
__device__ __forceinline__ void async16(const void* g, void* l) {
  __builtin_amdgcn_global_load_lds(
      (const __attribute__((address_space(1))) unsigned int*)g,
      (__attribute__((address_space(3))) unsigned int*)l, 16, 0, 0);
}

// ---------------- plain MFMA GEMM: C[M,N] = A[M,K] @ Bt[N,K]^T (+bias)(+relu), bf16 out ----------------
__global__ __launch_bounds__(256) void gemm_plain(const __hip_bfloat16* __restrict__ A,
                                                  const __hip_bfloat16* __restrict__ Bt,
                                                  const float* __restrict__ bias,
                                                  int K, int N, int relu,
                                                  __hip_bfloat16* __restrict__ Cb) {
  __shared__ __align__(16) char smem[65536];
  __hip_bfloat16* As = (__hip_bfloat16*)smem;
  __hip_bfloat16* Bs = As + 128 * 128;
  const int tid = threadIdx.x;
  const int wv = tid >> 6, ln = tid & 63;
  const int n0 = blockIdx.x << 7, m0 = blockIdx.y << 7;
  const int wm = (wv & 1) << 6, wn = (wv >> 1) << 6;
  const int lr = ln & 15, lq = ln >> 4;

  floatx4 acc[4][4];
  #pragma unroll
  for (int mi = 0; mi < 4; ++mi)
    #pragma unroll
    for (int ni = 0; ni < 4; ++ni) acc[mi][ni] = (floatx4)0.0f;

  for (int k0 = 0; k0 < K; k0 += 128) {
    if (k0) __syncthreads();
    #pragma unroll
    for (int i = 0; i < 8; ++i) {
      int rloc = i * 16 + wv * 4 + lq;
      int sc = (ln & 15) ^ (rloc & 15);
      async16((const char*)A + ((size_t)(m0 + rloc) * K + k0) * 2 + (size_t)sc * 16,
              (char*)As + (size_t)(i * 16 + wv * 4) * 256);
      async16((const char*)Bt + ((size_t)(n0 + rloc) * K + k0) * 2 + (size_t)sc * 16,
              (char*)Bs + (size_t)(i * 16 + wv * 4) * 256);
    }
    __syncthreads();
    #pragma unroll
    for (int kc = 0; kc < 4; ++kc) {
      short8 af[4], bfr[4];
      #pragma unroll
      for (int mi = 0; mi < 4; ++mi) {
        int R = wm + (mi << 4) + lr;
        int ch = ((kc << 2) + lq) ^ (R & 15);
        af[mi] = *(const short8*)(As + (R << 7) + (ch << 3));
      }
      #pragma unroll
      for (int ni = 0; ni < 4; ++ni) {
        int R = wn + (ni << 4) + lr;
        int ch = ((kc << 2) + lq) ^ (R & 15);
        bfr[ni] = *(const short8*)(Bs + (R << 7) + (ch << 3));
      }
      #pragma unroll
      for (int mi = 0; mi < 4; ++mi)
        #pragma unroll
        for (int ni = 0; ni < 4; ++ni)
          acc[mi][ni] = __builtin_amdgcn_mfma_f32_16x16x32_bf16(af[mi], bfr[ni], acc[mi][ni], 0, 0, 0);
    }
  }
  #pragma unroll
  for (int ni = 0; ni < 4; ++ni) {
    int cn = n0 + wn + (ni << 4) + lr;
    float bv = bias ? bias[cn] : 0.0f;
    #pragma unroll
    for (int mi = 0; mi < 4; ++mi) {
      #pragma unroll
      for (int r = 0; r < 4; ++r) {
        int rm = m0 + wm + (mi << 4) + (lq << 2) + r;
        float v = acc[mi][ni][r] + bv;
        if (relu) v = fmaxf(v, 0.0f);
        Cb[(size_t)rm * N + cn] = __float2bfloat16(v);
      }
    }
  }
}

// ---------------- fused-LN MFMA GEMM (N==128), 64x128 tile ----------------
// gcn_mode=1: out = relu(LN(A@Bt^T + bias) + residF)   [+ optional mask/pos permute]
// gcn_mode=0: out = LN(A@Bt^T + bias + residF)
__global__ __launch_bounds__(256) void gemm_ln(const __hip_bfloat16* __restrict__ A,
                                               const __hip_bfloat16* __restrict__ Bt,
                                               const float* __restrict__ bias,
                                               int K, int gcn_mode,
                                               const float* __restrict__ residF,
                                               const float* __restrict__ lng,
                                               const float* __restrict__ lnb,
                                               const float* __restrict__ maskf,
                                               const float* __restrict__ pos,
                                               float* __restrict__ outF,
                                               __hip_bfloat16* __restrict__ outB) {
  __shared__ __align__(16) char smem[49152];
  __hip_bfloat16* As = (__hip_bfloat16*)smem;   // 64x128 bf16 (16KB)
  __hip_bfloat16* Bs = As + 64 * 128;           // 128x128 bf16 (32KB)
  float* Cs = (float*)smem;                     // 64x128 fp32 (32KB, aliased post-compute)
  const int tid = threadIdx.x;
  const int wv = tid >> 6, ln = tid & 63;
  const int m0 = blockIdx.x << 6;
  const int wm = (wv & 1) << 5, wn = (wv >> 1) << 6;
  const int lr = ln & 15, lq = ln >> 4;

  floatx4 acc[2][4];
  #pragma unroll
  for (int mi = 0; mi < 2; ++mi)
    #pragma unroll
    for (int ni = 0; ni < 4; ++ni) acc[mi][ni] = (floatx4)0.0f;

  for (int k0 = 0; k0 < K; k0 += 128) {
    if (k0) __syncthreads();
    #pragma unroll
    for (int i = 0; i < 4; ++i) {   // A: 64 rows
      int rloc = i * 16 + wv * 4 + lq;
      int sc = (ln & 15) ^ (rloc & 15);
      async16((const char*)A + ((size_t)(m0 + rloc) * K + k0) * 2 + (size_t)sc * 16,
              (char*)As + (size_t)(i * 16 + wv * 4) * 256);
    }
    #pragma unroll
    for (int i = 0; i < 8; ++i) {   // B: 128 rows
      int rloc = i * 16 + wv * 4 + lq;
      int sc = (ln & 15) ^ (rloc & 15);
      async16((const char*)Bt + ((size_t)rloc * K + k0) * 2 + (size_t)sc * 16,
              (char*)Bs + (size_t)(i * 16 + wv * 4) * 256);
    }
    __syncthreads();
    #pragma unroll
    for (int kc = 0; kc < 4; ++kc) {
      short8 af[2], bfr[4];
      #pragma unroll
      for (int mi = 0; mi < 2; ++mi) {
        int R = wm + (mi << 4) + lr;
        int ch = ((kc << 2) + lq) ^ (R & 15);
        af[mi] = *(const short8*)(As + (R << 7) + (ch << 3));
      }
      #pragma unroll
      for (int ni = 0; ni < 4; ++ni) {
        int R = wn + (ni << 4) + lr;
        int ch = ((kc << 2) + lq) ^ (R & 15);
        bfr[ni] = *(const short8*)(Bs + (R << 7) + (ch << 3));
      }
      #pragma unroll
      for (int mi = 0; mi < 2; ++mi)
        #pragma unroll
        for (int ni = 0; ni < 4; ++ni)
          acc[mi][ni] = __builtin_amdgcn_mfma_f32_16x16x32_bf16(af[mi], bfr[ni], acc[mi][ni], 0, 0, 0);
    }
  }

  __syncthreads();
  #pragma unroll
  for (int ni = 0; ni < 4; ++ni) {
    int cn = wn + (ni << 4) + lr;
    float bv = bias[cn];
    #pragma unroll
    for (int mi = 0; mi < 2; ++mi) {
      #pragma unroll
      for (int r = 0; r < 4; ++r) {
        int rl = wm + (mi << 4) + (lq << 2) + r;
        float v = acc[mi][ni][r] + bv;
        if (!gcn_mode) v += residF[(size_t)(m0 + rl) * HDIM + cn];
        Cs[(rl << 7) + cn] = v;
      }
    }
  }
  __syncthreads();
  float2 gam = *(const float2*)(lng + ln * 2);
  float2 bet = *(const float2*)(lnb + ln * 2);
  #pragma unroll 4
  for (int p = 0; p < 16; ++p) {
    int rl = p * 4 + wv;
    int grow = m0 + rl;
    float2 xv = *(const float2*)(Cs + (rl << 7) + ln * 2);
    float s = xv.x + xv.y, q = xv.x * xv.x + xv.y * xv.y;
    #pragma unroll
    for (int off = 32; off > 0; off >>= 1) {
      s += __shfl_xor(s, off, 64);
      q += __shfl_xor(q, off, 64);
    }
    float mu = s * (1.0f / HDIM);
    float var = fmaxf(q * (1.0f / HDIM) - mu * mu, 0.0f);
    float rs = rsqrtf(var + 1e-5f);
    float o0 = (xv.x - mu) * rs * gam.x + bet.x;
    float o1 = (xv.y - mu) * rs * gam.y + bet.y;
    if (gcn_mode) {
      float2 rv = *(const float2*)(residF + (size_t)grow * HDIM + ln * 2);
      o0 = fmaxf(o0 + rv.x, 0.0f);
      o1 = fmaxf(o1 + rv.y, 0.0f);
    }
    size_t oi;
    if (pos) {
      int t = grow >> 11, bn = grow & (BNODES - 1);
      float m = maskf[grow];
      float2 pv = *(const float2*)(pos + t * HDIM + ln * 2);
      o0 = o0 * m + pv.x;
      o1 = o1 * m + pv.y;
      oi = ((size_t)bn * NT + t) * HDIM + ln * 2;
    } else {
      oi = (size_t)grow * HDIM + ln * 2;
    }
    if (outF) *(float2*)(outF + oi) = make_float2(o0, o1);
    if (outB) *(unsigned int*)((char*)outB + oi * 2) = pack2(o0, o1);
  }
}

// ---------------- fused FFN: out = LN2(relu(X@W1t^T + b1)@W2t^T + b2 + residF) ----------------
// 32-row tile (grid M/32), hidden 32x512 kept in LDS as 4 swizzled bf16 panels.
__global__ __launch_bounds__(256) void ffn_kernel(const __hip_bfloat16* __restrict__ X,
                                                  const __hip_bfloat16* __restrict__ W1t,  // [512][128]
                                                  const __hip_bfloat16* __restrict__ W2t,  // [128][512]
                                                  const float* __restrict__ b1,
                                                  const float* __restrict__ b2,
                                                  const float* __restrict__ residF,
                                                  const float* __restrict__ lng,
                                                  const float* __restrict__ lnb,
                                                  float* __restrict__ outF,
                                                  __hip_bfloat16* __restrict__ outB) {
  __shared__ __align__(16) char smem[73728];            // 72 KB
  __hip_bfloat16* As  = (__hip_bfloat16*)smem;          // 32x128 (8 KB)
  __hip_bfloat16* Bs  = (__hip_bfloat16*)(smem + 8192); // 128x128 (32 KB)
  __hip_bfloat16* Hid = (__hip_bfloat16*)(smem + 40960);// 4 panels x 32x128 (32 KB)
  float* Cs = (float*)smem;                             // 32x128 fp32 (16 KB, aliased at end)
  const int tid = threadIdx.x;
  const int wv = tid >> 6, ln = tid & 63;
  const int m0 = blockIdx.x << 5;
  const int wn = wv << 5;                               // wave's 32-col slice
  const int lr = ln & 15, lq = ln >> 4;

  // stage A (32 rows of X) once
  #pragma unroll
  for (int i = 0; i < 2; ++i) {
    int rloc = (i << 4) + (wv << 2) + lq;
    int sc = (ln & 15) ^ (rloc & 15);
    async16((const char*)X + ((size_t)(m0 + rloc) * HDIM) * 2 + (size_t)sc * 16,
            (char*)As + (size_t)((i << 4) + (wv << 2)) * 256);
  }

  floatx4 acc2[2][2];
  #pragma unroll
  for (int mi = 0; mi < 2; ++mi)
    #pragma unroll
    for (int ni = 0; ni < 2; ++ni) acc2[mi][ni] = (floatx4)0.0f;

  // ---- ff1: hidden = relu(X @ W1t^T + b1), stored per 128-col panel ----
  for (int nc = 0; nc < 4; ++nc) {
    if (nc) __syncthreads();     // protect Bs + Hid writes ordering
    #pragma unroll
    for (int i = 0; i < 8; ++i) {
      int rloc = (i << 4) + (wv << 2) + lq;
      int sc = (ln & 15) ^ (rloc & 15);
      async16((const char*)W1t + ((size_t)((nc << 7) + rloc) * HDIM) * 2 + (size_t)sc * 16,
              (char*)Bs + (size_t)((i << 4) + (wv << 2)) * 256);
    }
    __syncthreads();
    floatx4 acc[2][2];
    #pragma unroll
    for (int mi = 0; mi < 2; ++mi)
      #pragma unroll
      for (int ni = 0; ni < 2; ++ni) acc[mi][ni] = (floatx4)0.0f;
    #pragma unroll
    for (int kc = 0; kc < 4; ++kc) {
      short8 af[2], bfr[2];
      #pragma unroll
      for (int mi = 0; mi < 2; ++mi) {
        int R = (mi << 4) + lr;
        int ch = ((kc << 2) + lq) ^ (R & 15);
        af[mi] = *(const short8*)(As + (R << 7) + (ch << 3));
      }
      #pragma unroll
      for (int ni = 0; ni < 2; ++ni) {
        int R = wn + (ni << 4) + lr;
        int ch = ((kc << 2) + lq) ^ (R & 15);
        bfr[ni] = *(const short8*)(Bs + (R << 7) + (ch << 3));
      }
      #pragma unroll
      for (int mi = 0; mi < 2; ++mi)
        #pragma unroll
        for (int ni = 0; ni < 2; ++ni)
          acc[mi][ni] = __builtin_amdgcn_mfma_f32_16x16x32_bf16(af[mi], bfr[ni], acc[mi][ni], 0, 0, 0);
    }
    // epilogue: +b1, relu, bf16 -> Hid panel nc (swizzled)
    __hip_bfloat16* panel = Hid + (nc << 12);
    #pragma unroll
    for (int ni = 0; ni < 2; ++ni) {
      int cn = wn + (ni << 4) + lr;
      float bv = b1[(nc << 7) + cn];
      #pragma unroll
      for (int mi = 0; mi < 2; ++mi) {
        #pragma unroll
        for (int r = 0; r < 4; ++r) {
          int row = (mi << 4) + (lq << 2) + r;
          float v = fmaxf(acc[mi][ni][r] + bv, 0.0f);
          panel[(row << 7) + ((((cn >> 3) ^ (row & 15)) << 3) | (cn & 7))] = __float2bfloat16(v);
        }
      }
    }
  }
  __syncthreads();   // hidden complete

  // ---- ff2: C = hidden @ W2t^T, accumulate over 4 k-panels ----
  for (int kc2 = 0; kc2 < 4; ++kc2) {
    if (kc2) __syncthreads();
    #pragma unroll
    for (int i = 0; i < 8; ++i) {
      int rloc = (i << 4) + (wv << 2) + lq;
      int sc = (ln & 15) ^ (rloc & 15);
      async16((const char*)W2t + ((size_t)rloc * 512 + (kc2 << 7)) * 2 + (size_t)sc * 16,
              (char*)Bs + (size_t)((i << 4) + (wv << 2)) * 256);
    }
    __syncthreads();
    const __hip_bfloat16* panel = Hid + (kc2 << 12);
    #pragma unroll
    for (int kc = 0; kc < 4; ++kc) {
      short8 af[2], bfr[2];
      #pragma unroll
      for (int mi = 0; mi < 2; ++mi) {
        int R = (mi << 4) + lr;
        int ch = ((kc << 2) + lq) ^ (R & 15);
        af[mi] = *(const short8*)(panel + (R << 7) + (ch << 3));
      }
      #pragma unroll
      for (int ni = 0; ni < 2; ++ni) {
        int R = wn + (ni << 4) + lr;
        int ch = ((kc << 2) + lq) ^ (R & 15);
        bfr[ni] = *(const short8*)(Bs + (R << 7) + (ch << 3));
      }
      #pragma unroll
      for (int mi = 0; mi < 2; ++mi)
        #pragma unroll
        for (int ni = 0; ni < 2; ++ni)
          acc2[mi][ni] = __builtin_amdgcn_mfma_f32_16x16x32_bf16(af[mi], bfr[ni], acc2[mi][ni], 0, 0, 0);
    }
  }

  // ---- LN2 epilogue (Cs aliases As/Bs region) ----
  __syncthreads();
  #pragma unroll
  for (int ni = 0; ni < 2; ++ni) {
    int cn = wn + (ni << 4) + lr;
    float bv = b2[cn];
    #pragma unroll
    for (int mi = 0; mi < 2; ++mi) {
      #pragma unroll
      for (int r = 0; r < 4; ++r) {
        int rl = (mi << 4) + (lq << 2) + r;
        Cs[(rl << 7) + cn] = acc2[mi][ni][r] + bv + residF[(size_t)(m0 + rl) * HDIM + cn];
      }
    }
  }
  __syncthreads();
  float2 gam = *(const float2*)(lng + ln * 2);
  float2 bet = *(const float2*)(lnb + ln * 2);
  #pragma unroll
  for (int p = 0; p < 8; ++p) {
    int rl = (p << 2) + wv;
    int grow = m0 + rl;
    float2 xv = *(const float2*)(Cs + (rl << 7) + ln * 2);
    float s = xv.x + xv.y, q = xv.x * xv.x + xv.y * xv.y;
    #pragma unroll
    for (int off = 32; off > 0; off >>= 1) {
      s += __shfl_xor(s, off, 64);
      q += __shfl_xor(q, off, 64);
    }
    float mu = s * (1.0f / HDIM);
    float var = fmaxf(q * (1.0f / HDIM) - mu * mu, 0.0f);
    float rs = rsqrtf(var + 1e-5f);
    float o0 = (xv.x - mu) * rs * gam.x + bet.x;
    float o1 = (xv.y - mu) * rs * gam.y + bet.y;
    size_t oi = (size_t)grow * HDIM + ln * 2;
    if (outF) *(float2*)(outF + oi) = make_float2(o0, o1);
    if (outB) *(unsigned int*)((char*)outB + oi * 2) = pack2(o0, o1);
  }
}

// ---------------- attention: one block per sequence; register softmax ----------------
__global__ __launch_bounds__(256) void attn_kernel(const __hip_bfloat16* __restrict__ qkv,
                                                   const float* __restrict__ maskf,
                                                   __hip_bfloat16* __restrict__ o) {
  int bn = blockIdx.x;
  __shared__ float q[NT][QP], kk[NT][QP], vv[NT][QP];
  __shared__ float mb[NT];
  int tid = threadIdx.x;
  if (tid < NT) mb[tid] = (maskf[tid * BNODES + bn] == 0.0f) ? -1e30f : 0.0f;
  for (int idx = tid; idx < NT * 48; idx += 256) {
    int t = idx / 48, c8 = idx % 48;
    short8 v8 = *(const short8*)((const short*)qkv + ((size_t)bn * NT + t) * 384 + c8 * 8);
    float* dst = (c8 < 16) ? &q[t][c8 * 8] : (c8 < 32) ? &kk[t][(c8 - 16) * 8] : &vv[t][(c8 - 32) * 8];
    #pragma unroll
    for (int i = 0; i < 8; ++i) dst[i] = bf2f(v8[i]);
  }
  __syncthreads();
  if (tid >= 8 * NT) return;
  int h = tid / NT, tq = tid % NT;
  float qr[16];
  #pragma unroll
  for (int d = 0; d < 16; ++d) qr[d] = q[tq][h * 16 + d];
  float p[NT];
  float mx = -1e30f;
  #pragma unroll
  for (int tk = 0; tk < NT; ++tk) {
    float s = 0.0f;
    #pragma unroll
    for (int d = 0; d < 16; ++d) s = fmaf(qr[d], kk[tk][h * 16 + d], s);
    s = s * 0.25f + mb[tk];
    p[tk] = s;
    mx = fmaxf(mx, s);
  }
  float sum = 0.0f;
  #pragma unroll
  for (int tk = 0; tk < NT; ++tk) { float e = __expf(p[tk] - mx); p[tk] = e; sum += e; }
  float inv = 1.0f / sum;
  float oacc[16];
  #pragma unroll
  for (int d = 0; d < 16; ++d) oacc[d] = 0.0f;
  #pragma unroll
  for (int tk = 0; tk < NT; ++tk) {
    float pv = p[tk] * inv;
    #pragma unroll
    for (int d = 0; d < 16; ++d) oacc[d] = fmaf(pv, vv[tk][h * 16 + d], oacc[d]);
  }
  short* op = (short*)o + ((size_t)bn * NT + tq) * HDIM + h * 16;
  short8 o8a, o8b;
  #pragma unroll
  for (int d = 0; d < 8; ++d) o8a[d] = f2bf_s(oacc[d]);
  #pragma unroll
  for (int d = 0; d < 8; ++d) o8b[d] = f2bf_s(oacc[8 + d]);
  *(short8*)op = o8a;
  *(short8*)(op + 8) = o8b;
}

extern "C" void kernel_launch(void* const* d_in, const int* in_sizes, int n_in,
                              void* d_out, int out_size, void* d_ws, size_t ws_size,
                              hipStream_t stream) {
  const void*  ego   = d_in[0];
  const float* xraw  = (const float*)d_in[1];
  const float* adj   = (const float*)d_in[2];
  const float* gcn1w = (const float*)d_in[3];
  const float* gcnws = (const float*)d_in[4];
  const float* gcnbs = (const float*)d_in[5];
  const float* lng   = (const float*)d_in[6];
  const float* lnb   = (const float*)d_in[7];
  const float* pos   = (const float*)d_in[8];
  const float* twqkv = (const float*)d_in[9];
  const float* tbqkv = (const float*)d_in[10];
  const float* two   = (const float*)d_in[11];
  const float* tbo   = (const float*)d_in[12];
  const float* tln1g = (const float*)d_in[13];
  const float* tln1b = (const float*)d_in[14];
  const float* tw1   = (const float*)d_in[15];
  const float* tb1   = (const float*)d_in[16];
  const float* tw2   = (const float*)d_in[17];
  const float* tb2   = (const float*)d_in[18];
  const float* tln2g = (const float*)d_in[19];
  const float* tln2b = (const float*)d_in[20];

  char* base = (char*)d_ws;
  size_t off = 0;
  auto alloc = [&](size_t bytes) -> void* {
    void* p = base + off;
    off = (off + bytes + 255) & ~(size_t)255;
    return p;
  };
  float* maskf  = (float*)alloc((size_t)NROWS * 4);
  float* dinv   = (float*)alloc((size_t)NROWS * 4);
  int*   colcnt = (int*)  alloc((size_t)NROWS * 4);
  // region shared: colidx (GCN phase) / qkv_bf (transformer phase)
  void*  regA   = alloc((size_t)NROWS * 384 * 2);
  int*   colidx = (int*)regA;
  __hip_bfloat16* qkv_bf = (__hip_bfloat16*)regA;
  __hip_bfloat16* g_bf    = (__hip_bfloat16*)alloc((size_t)NROWS * HDIM * 2);
  __hip_bfloat16* attn_bf = (__hip_bfloat16*)alloc((size_t)NROWS * HDIM * 2);
  __hip_bfloat16* hbufA   = (__hip_bfloat16*)alloc((size_t)NROWS * HDIM * 2);  // bf16 h mirror
  __hip_bfloat16* xbf     = (__hip_bfloat16*)alloc((size_t)NROWS * HDIM * 2);
  float* hbufF  = (float*)alloc((size_t)NROWS * HDIM * 4);   // fp32 GCN residual carry
  float* xbuf   = (float*)alloc((size_t)NROWS * HDIM * 4);   // fp32 transformer residual carry
  __hip_bfloat16* wqkv_bf = (__hip_bfloat16*)alloc((size_t)245760 * 2);
  __hip_bfloat16* wo_bf   = (__hip_bfloat16*)alloc((size_t)81920 * 2);
  __hip_bfloat16* w1_bf   = (__hip_bfloat16*)alloc((size_t)327680 * 2);
  __hip_bfloat16* w2_bf   = (__hip_bfloat16*)alloc((size_t)327680 * 2);
  __hip_bfloat16* wsT_bf  = (__hip_bfloat16*)alloc((size_t)81920 * 2);

  // ---- setup ----
  setup_kernel<<<4320, 256, 0, stream>>>(ego, maskf, colcnt, twqkv, two, tw1, tw2, gcnws,
                                         wqkv_bf, wo_bf, w1_bf, w2_bf, wsT_bf);
  build_edges_kernel<<<4096, 256, 0, stream>>>(adj, maskf, colcnt, colidx);
  finalize_deg_kernel<<<160, 256, 0, stream>>>(maskf, colcnt, dinv);

  // ---- GCN (separate spmm, fp32 carry) ----
  spmm_ln0_kernel<<<NROWS / 4, 256, 0, stream>>>(xraw, gcn1w, dinv, colcnt, colidx,
                                                 gcnbs, lng, lnb, hbufF, hbufA);
  for (int i = 0; i < 5; ++i) {
    spmm_kernel<<<NROWS / 4, 256, 0, stream>>>(hbufA, dinv, colcnt, colidx, g_bf);
    const float* fm = (i == 4) ? maskf : nullptr;
    const float* fp = (i == 4) ? pos : nullptr;
    float* oF = (i == 4) ? xbuf : hbufF;
    __hip_bfloat16* oB = (i == 4) ? xbf : hbufA;
    gemm_ln<<<NROWS / 64, 256, 0, stream>>>(
        g_bf, wsT_bf + (size_t)i * 16384, gcnbs + (i + 1) * 128, 128, 1,
        hbufF, lng + (i + 1) * 128, lnb + (i + 1) * 128, fm, fp, oF, oB);
  }

  // ---- transformer (fp32 carry in xbuf, bf16 operand mirror in xbf) ----
  for (int l = 0; l < 5; ++l) {
    gemm_plain<<<dim3(3, NROWS / 128), 256, 0, stream>>>(
        xbf, wqkv_bf + (size_t)l * 49152, tbqkv + l * 384, 128, 384, 0, qkv_bf);
    attn_kernel<<<BNODES, 256, 0, stream>>>(qkv_bf, maskf, attn_bf);
    gemm_ln<<<NROWS / 64, 256, 0, stream>>>(
        attn_bf, wo_bf + (size_t)l * 16384, tbo + l * 128, 128, 0,
        xbuf, tln1g + l * 128, tln1b + l * 128, nullptr, nullptr, xbuf, xbf);
    float* oF = (l == 4) ? (float*)d_out : xbuf;
    __hip_bfloat16* oB = (l == 4) ? nullptr : xbf;
    ffn_kernel<<<NROWS / 32, 256, 0, stream>>>(
        xbf, w1_bf + (size_t)l * 65536, w2_bf + (size_t)l * 65536,
        tb1 + l * 512, tb2 + l * 128, xbuf,
        tln2g + l * 128, tln2b + l * 128, oF, oB);
  }
}